// Round 10
// baseline (373.009 us; speedup 1.0000x reference)
//
#include <hip/hip_runtime.h>
#include <hip/hip_bf16.h>
#include <math.h>

#define N_NODES 32768
#define N_EDGES 262144
#define EPS_C 0.24253562503633297f   // 1/sqrt(17)
#define NSPEC 10

typedef __attribute__((ext_vector_type(8))) short short8;   // 8 bf16
typedef __attribute__((ext_vector_type(4))) float f32x4;    // 4 fp32 acc

#define MFMA16(a, b, c) __builtin_amdgcn_mfma_f32_16x16x32_bf16(a, b, c, 0, 0, 0)

__device__ __forceinline__ short2 cvt2(float a, float b) {
    union { __hip_bfloat162 h; short2 s; } u;
    u.h = __float22bfloat162_rn(make_float2(a, b));
    return u.s;
}
__device__ __forceinline__ short8 cvt8(float4 a, float4 b) {
    short2 p0 = cvt2(a.x, a.y), p1 = cvt2(a.z, a.w);
    short2 p2 = cvt2(b.x, b.y), p3 = cvt2(b.z, b.w);
    short8 r;
    r[0] = p0.x; r[1] = p0.y; r[2] = p1.x; r[3] = p1.y;
    r[4] = p2.x; r[5] = p2.y; r[6] = p3.x; r[7] = p3.y;
    return r;
}
__device__ __forceinline__ short8 loadArow(const float* rowp, int h, int q) {
    const float* p = rowp + h * 32 + q * 8;
    return cvt8(*(const float4*)p, *(const float4*)(p + 4));
}
__device__ __forceinline__ short8 loadB(const short* P, int t, int h, int l) {
    return *(const short8*)(P + (((t * 2 + h) * 64 + l) << 3));
}

// ---------------------------------------------------------------------------
// Edge precompute into fused 64B records: edata[e*16] = {y0,y1,y2,0, rbf[8], pad}
// ---------------------------------------------------------------------------
__global__ __launch_bounds__(256) void edge_pre_kernel(
    const float* __restrict__ vectors, float* __restrict__ edata)
{
    int e = blockIdx.x * 256 + threadIdx.x;
    float x = vectors[e * 3 + 0], y = vectors[e * 3 + 1], z = vectors[e * 3 + 2];
    float r2 = x * x + y * y + z * z + 1e-12f;
    float r = sqrtf(r2);
    float inv = 1.0f / r;
    float* d = edata + (size_t)e * 16;
    *(float4*)d = make_float4(x * inv, y * inv, z * inv, 0.0f);
    float rc = fmaxf(r, 1e-6f);
    float r6 = r2 * r2 * r2;
    float r7 = r6 * r;
    float r8 = r6 * r2;
    float env = (r < 1.0f) ? (1.0f - 28.0f * r6 + 48.0f * r7 - 21.0f * r8) : 0.0f;
    float sc = 1.41421356237309515f * env / rc;
#pragma unroll
    for (int j = 0; j < 8; ++j)
        d[4 + j] = sc * sinf((float)(j + 1) * 3.14159265358979323846f * rc);
    d[12] = 0.f; d[13] = 0.f; d[14] = 0.f; d[15] = 0.f;
}

// ---------------------------------------------------------------------------
// Species counting sort — contention-free, deterministic (ballot/popcount).
// ---------------------------------------------------------------------------
__global__ __launch_bounds__(256) void sort1_kernel(
    const int* __restrict__ species, int* __restrict__ counts_blk,
    int* __restrict__ lrank_arr)
{
    __shared__ int wcnt[4][16];
    int n = blockIdx.x * 256 + threadIdx.x;
    int sp = species[n];
    int lane = threadIdx.x & 63, wv = threadIdx.x >> 6;
    unsigned long long ltmask = (1ull << lane) - 1;
    int lrank_w = 0;
#pragma unroll
    for (int z = 0; z < NSPEC; ++z) {
        unsigned long long m = __ballot(sp == z);
        if (sp == z) lrank_w = __popcll(m & ltmask);
        if (lane == 0) wcnt[wv][z] = __popcll(m);
    }
    __syncthreads();
    int off = 0;
    for (int w = 0; w < wv; ++w) off += wcnt[w][sp];
    lrank_arr[n] = lrank_w + off;
    if (threadIdx.x < NSPEC)
        counts_blk[blockIdx.x * NSPEC + threadIdx.x] =
            wcnt[0][threadIdx.x] + wcnt[1][threadIdx.x] +
            wcnt[2][threadIdx.x] + wcnt[3][threadIdx.x];
}

__global__ __launch_bounds__(64) void sort2_kernel(
    const int* __restrict__ counts_blk, int* __restrict__ off_blk)
{
    __shared__ int total[NSPEC], base[NSPEC];
    int z = threadIdx.x;
    if (z < NSPEC) {
        int t = 0;
        for (int b = 0; b < 128; ++b) t += counts_blk[b * NSPEC + z];
        total[z] = t;
    }
    __syncthreads();
    if (z == 0) {
        int run = 0;
        for (int q = 0; q < NSPEC; ++q) { base[q] = run; run += total[q]; }
    }
    __syncthreads();
    if (z < NSPEC) {
        int run = base[z];
        for (int b = 0; b < 128; ++b) {
            off_blk[b * NSPEC + z] = run;
            run += counts_blk[b * NSPEC + z];
        }
    }
}

__global__ __launch_bounds__(256) void sort3_kernel(
    const int* __restrict__ species, const int* __restrict__ lrank_arr,
    const int* __restrict__ off_blk,
    int* __restrict__ sidx, int* __restrict__ rank, int* __restrict__ spec_srt)
{
    int n = blockIdx.x * 256 + threadIdx.x;
    int sp = species[n];
    int slot = off_blk[blockIdx.x * NSPEC + sp] + lrank_arr[n];
    sidx[slot] = n;
    rank[n] = slot;
    spec_srt[slot] = sp;
}

// ---------------------------------------------------------------------------
// Receiver CSR in SORTED space
// ---------------------------------------------------------------------------
__global__ __launch_bounds__(256) void hist_kernel(
    const int* __restrict__ receivers, const int* __restrict__ rank,
    int* __restrict__ counts)
{
    int e = blockIdx.x * 256 + threadIdx.x;
    atomicAdd(&counts[rank[receivers[e]]], 1);
}

__global__ __launch_bounds__(1024) void scan_kernel(
    const int* __restrict__ counts, int* __restrict__ row_start, int* __restrict__ cursor)
{
    __shared__ int wave_tot[16];
    int tid = threadIdx.x;
    int c[32];
    int sum = 0;
#pragma unroll
    for (int i = 0; i < 32; ++i) { c[i] = counts[tid * 32 + i]; sum += c[i]; }
    int lane = tid & 63, wv = tid >> 6;
    int x = sum;
#pragma unroll
    for (int off = 1; off < 64; off <<= 1) {
        int y = __shfl_up(x, off);
        if (lane >= off) x += y;
    }
    if (lane == 63) wave_tot[wv] = x;
    __syncthreads();
    if (wv == 0 && lane < 16) {
        int t = wave_tot[lane];
#pragma unroll
        for (int off = 1; off < 16; off <<= 1) {
            int y = __shfl_up(t, off);
            if (lane >= off) t += y;
        }
        wave_tot[lane] = t;
    }
    __syncthreads();
    int excl = x - sum + (wv ? wave_tot[wv - 1] : 0);
    int run = excl;
#pragma unroll
    for (int i = 0; i < 32; ++i) {
        row_start[tid * 32 + i] = run;
        cursor[tid * 32 + i] = run;
        run += c[i];
    }
    if (tid == 1023) row_start[32768] = run;
}

__global__ __launch_bounds__(256) void scatter_kernel(
    const int* __restrict__ receivers, const int* __restrict__ rank,
    int* __restrict__ cursor, int* __restrict__ edge_ids)
{
    int e = blockIdx.x * 256 + threadIdx.x;
    int slot = atomicAdd(&cursor[rank[receivers[e]]], 1);
    edge_ids[slot] = e;
}

// per-row insertion sort in LDS (stride-33 scratch, bank-clean); rows > 32
// edges (P~1e-11) fall back to global
__global__ __launch_bounds__(256) void rowsort_kernel(
    const int* __restrict__ row_start, int* __restrict__ edge_ids)
{
    __shared__ int buf[256 * 33];
    int i = blockIdx.x * 256 + threadIdx.x;
    int beg = row_start[i], end = row_start[i + 1];
    int len = end - beg;
    int* b = buf + threadIdx.x * 33;
    if (len <= 32) {
        for (int j = 0; j < len; ++j) b[j] = edge_ids[beg + j];
        for (int a = 1; a < len; ++a) {
            int key = b[a];
            int c = a - 1;
            while (c >= 0 && b[c] > key) { b[c + 1] = b[c]; --c; }
            b[c + 1] = key;
        }
        for (int j = 0; j < len; ++j) edge_ids[beg + j] = b[j];
    } else {
        for (int a = beg + 1; a < end; ++a) {
            int key = edge_ids[a];
            int c = a - 1;
            while (c >= beg && edge_ids[c] > key) { edge_ids[c + 1] = edge_ids[c]; --c; }
            edge_ids[c + 1] = key;
        }
    }
}

// fused (eid, sender_rank) stream per CSR slot
__global__ __launch_bounds__(256) void sr_kernel(
    const int* __restrict__ senders, const int* __restrict__ edge_ids,
    const int* __restrict__ rank, int2* __restrict__ esr)
{
    int p = blockIdx.x * 256 + threadIdx.x;
    int eid = edge_ids[p];
    esr[p] = make_int2(eid, rank[senders[eid]]);
}

// ---------------------------------------------------------------------------
// Node init (sorted layout)
// ---------------------------------------------------------------------------
__global__ __launch_bounds__(256) void init_s_kernel(
    const float* __restrict__ embed_s, const int* __restrict__ spec_srt,
    float* __restrict__ s)
{
    int idx = blockIdx.x * 256 + threadIdx.x;
    s[idx] = embed_s[spec_srt[idx >> 6] * 64 + (idx & 63)];
}

// ---------------------------------------------------------------------------
// Weight pre-pack: 28 64x64 fp32 matrices -> bf16 B-fragment order.
// ---------------------------------------------------------------------------
__global__ __launch_bounds__(256) void pack_kernel(
    const float* __restrict__ Wls, const float* __restrict__ Wlv,
    const float* __restrict__ Wps, const float* __restrict__ Wpv,
    const float* __restrict__ skip_s, const float* __restrict__ skip_v,
    short* __restrict__ packW)
{
    int idx = blockIdx.x * 256 + threadIdx.x;   // 28*4096 = 114688
    if (idx >= 28 * 4096) return;
    int m = idx >> 12, e = idx & 4095;
    int t = e >> 10, h = (e >> 9) & 1, l = (e >> 3) & 63, j = e & 7;
    int fi = h * 32 + ((l >> 4) << 3) + j;
    int fo = t * 16 + (l & 15);
    const float* src;
    if      (m < 2)  src = Wls    + m * 4096;
    else if (m < 4)  src = Wlv    + (m - 2) * 4096;
    else if (m < 6)  src = Wps    + (m - 4) * 4096;
    else if (m < 8)  src = Wpv    + (m - 6) * 4096;
    else if (m < 18) src = skip_s + (m - 8) * 4096;
    else             src = skip_v + (m - 18) * 4096;
    packW[idx] = cvt2(src[fi * 64 + fo], 0.f).x;
}

// ---------------------------------------------------------------------------
// Gather: per-edge accumulate helper (independent load chain per call site)
// ---------------------------------------------------------------------------
template<int VZERO>
__device__ __forceinline__ void edge_acc(
    int eid, int sr, int f,
    const float* __restrict__ edata,
    const float* __restrict__ s_in, const float* __restrict__ v_in,
    const float wr[5][8], float* acc)
{
    const float* d = edata + (size_t)eid * 16;
    float4 yv = *(const float4*)d;
    float4 r0 = *(const float4*)(d + 4);
    float4 r1 = *(const float4*)(d + 8);
    float ss = s_in[(size_t)sr * 64 + f];
    float rb[8] = {r0.x, r0.y, r0.z, r0.w, r1.x, r1.y, r1.z, r1.w};
    float w0 = 0.f, w1 = 0.f, w2 = 0.f, w3 = 0.f, w4 = 0.f;
#pragma unroll
    for (int j = 0; j < 8; ++j) {
        w0 = fmaf(rb[j], wr[0][j], w0);
        if (!VZERO) w1 = fmaf(rb[j], wr[1][j], w1);
        w2 = fmaf(rb[j], wr[2][j], w2);
        if (!VZERO) w3 = fmaf(rb[j], wr[3][j], w3);
        if (!VZERO) w4 = fmaf(rb[j], wr[4][j], w4);
    }
    if (VZERO) {
        acc[0] += w0 * ss;
        float ws2 = w2 * ss;
        acc[1] += ws2 * yv.x; acc[2] += ws2 * yv.y; acc[3] += ws2 * yv.z;
    } else {
        float vs0 = v_in[((size_t)sr * 3 + 0) * 64 + f];
        float vs1 = v_in[((size_t)sr * 3 + 1) * 64 + f];
        float vs2 = v_in[((size_t)sr * 3 + 2) * 64 + f];
        float dot = vs0 * yv.x + vs1 * yv.y + vs2 * yv.z;
        acc[0] += w0 * ss + w1 * dot;
        float c0 = vs1 * yv.z - vs2 * yv.y;
        float c1 = vs2 * yv.x - vs0 * yv.z;
        float c2 = vs0 * yv.y - vs1 * yv.x;
        float ws2 = w2 * ss;
        acc[1] += ws2 * yv.x + w3 * vs0 + w4 * c0;
        acc[2] += ws2 * yv.y + w3 * vs1 + w4 * c1;
        acc[3] += ws2 * yv.z + w3 * vs2 + w4 * c2;
    }
}

// ---------------------------------------------------------------------------
// Gather kernel: wave owns 4 rows, processed as 2 interleaved pairs (2
// independent load->compute chains per loop iteration). Index stream (esr)
// prefetched 1-ahead. Radial weights in VGPRs; no LDS, no atomics.
// ---------------------------------------------------------------------------
template<int VZERO>
__global__ __launch_bounds__(256) void gather_kernel(
    const float* __restrict__ edata, const int2* __restrict__ esr,
    const int* __restrict__ row_start,
    const float* __restrict__ s_in, const float* __restrict__ v_in,
    const float* __restrict__ Wr_i,
    float* __restrict__ agg_s, float* __restrict__ agg_v)
{
    const int wid = threadIdx.x >> 6;
    const int f = threadIdx.x & 63;
    const int base = (blockIdx.x * 4 + wid) * 4;

    float wr[5][8];
#pragma unroll
    for (int j = 0; j < 8; ++j)
#pragma unroll
        for (int p = 0; p < 5; ++p)
            wr[p][j] = (VZERO && (p == 1 || p == 3 || p == 4))
                       ? 0.f : Wr_i[j * 320 + p * 64 + f];

#pragma unroll
    for (int pr = 0; pr < 2; ++pr) {
        int iA = base + pr * 2;
        int iB = iA + 1;
        int pA = row_start[iA], endA = row_start[iA + 1];
        int pB = row_start[iB], endB = row_start[iB + 1];
        float accA[4] = {0.f, 0.f, 0.f, 0.f};
        float accB[4] = {0.f, 0.f, 0.f, 0.f};
        int lenA = endA - pA, lenB = endB - pB;
        int nI = lenA < lenB ? lenA : lenB;
        if (nI > 0) {
            int2 ia = esr[pA];
            int2 ib = esr[pB];
            for (int k = 0; k < nI; ++k) {
                int kn = k + 1;
                int2 ia_n = (kn < lenA) ? esr[pA + kn] : ia;
                int2 ib_n = (kn < lenB) ? esr[pB + kn] : ib;
                edge_acc<VZERO>(ia.x, ia.y, f, edata, s_in, v_in, wr, accA);
                edge_acc<VZERO>(ib.x, ib.y, f, edata, s_in, v_in, wr, accB);
                ia = ia_n; ib = ib_n;
            }
        }
        for (int p = pA + nI; p < endA; ++p) {
            int2 ix = esr[p];
            edge_acc<VZERO>(ix.x, ix.y, f, edata, s_in, v_in, wr, accA);
        }
        for (int p = pB + nI; p < endB; ++p) {
            int2 ix = esr[p];
            edge_acc<VZERO>(ix.x, ix.y, f, edata, s_in, v_in, wr, accB);
        }
        agg_s[(size_t)iA * 64 + f] = accA[0];
        agg_v[((size_t)iA * 3 + 0) * 64 + f] = accA[1];
        agg_v[((size_t)iA * 3 + 1) * 64 + f] = accA[2];
        agg_v[((size_t)iA * 3 + 2) * 64 + f] = accA[3];
        agg_s[(size_t)iB * 64 + f] = accB[0];
        agg_v[((size_t)iB * 3 + 0) * 64 + f] = accB[1];
        agg_v[((size_t)iB * 3 + 1) * 64 + f] = accB[2];
        agg_v[((size_t)iB * 3 + 2) * 64 + f] = accB[3];
    }
}

// ---------------------------------------------------------------------------
// MFMA node kernel (unchanged): wave = 16 sorted nodes.
// ---------------------------------------------------------------------------
__global__ __launch_bounds__(256) void node_mfma_kernel(
    const float* __restrict__ agg_s, const float* __restrict__ agg_v,
    float* s, float* v,
    const short* __restrict__ packW, int it,
    const float* __restrict__ pw_i,
    const int* __restrict__ spec_srt,
    int has_skip)
{
    const int l = threadIdx.x & 63;
    const int wid = threadIdx.x >> 6;
    const int cl = l & 15;
    const int q = l >> 4;
    const int i16 = (blockIdx.x * 4 + wid) * 16;
    __shared__ float xls_all[4][16 * 65];
    float* xls = xls_all[wid];

    const short* pWls = packW + (size_t)(0 + it) * 4096;
    const short* pWlv = packW + (size_t)(2 + it) * 4096;
    const short* pWps = packW + (size_t)(4 + it) * 4096;
    const short* pWpv = packW + (size_t)(6 + it) * 4096;
    const short* pSkS = packW + (size_t)8 * 4096;
    const short* pSkV = packW + (size_t)18 * 4096;
    const short8 z8 = {0, 0, 0, 0, 0, 0, 0, 0};

    const float* ars = agg_s + (size_t)(i16 + cl) * 64;
    short8 As[2] = { loadArow(ars, 0, q), loadArow(ars, 1, q) };
    short8 Av[3][2];
#pragma unroll
    for (int k = 0; k < 3; ++k) {
        const float* r = agg_v + ((size_t)(i16 + cl) * 3 + k) * 64;
        Av[k][0] = loadArow(r, 0, q);
        Av[k][1] = loadArow(r, 1, q);
    }

    f32x4 sD[4];
#pragma unroll
    for (int t = 0; t < 4; ++t) {
        f32x4 acc = {0.f, 0.f, 0.f, 0.f};
        acc = MFMA16(As[0], loadB(pWls, t, 0, l), acc);
        acc = MFMA16(As[1], loadB(pWls, t, 1, l), acc);
        sD[t] = acc;
    }

    f32x4 vD[3][4];
#pragma unroll
    for (int k = 0; k < 3; ++k)
#pragma unroll
        for (int t = 0; t < 4; ++t) vD[k][t] = (f32x4){0.f, 0.f, 0.f, 0.f};
#pragma unroll
    for (int t = 0; t < 4; ++t)
#pragma unroll
        for (int h = 0; h < 2; ++h) {
            short8 b = loadB(pWlv, t, h, l);
#pragma unroll
            for (int k = 0; k < 3; ++k) vD[k][t] = MFMA16(Av[k][h], b, vD[k][t]);
        }

    int z0 = spec_srt[i16], z1 = spec_srt[i16 + 15];
    float psD[4][4], pvsD[4][4];
    if (z0 == z1) {
        const float* pb = pw_i + z0 * 576 + cl;
        float pc[9][4];
#pragma unroll
        for (int c = 0; c < 9; ++c)
#pragma unroll
            for (int t = 0; t < 4; ++t) pc[c][t] = pb[c * 64 + t * 16];
#pragma unroll
        for (int t = 0; t < 4; ++t)
#pragma unroll
            for (int r = 0; r < 4; ++r) {
                float x = sD[t][r] * EPS_C;
                float w0 = vD[0][t][r] * EPS_C;
                float w1 = vD[1][t][r] * EPS_C;
                float w2 = vD[2][t][r] * EPS_C;
                vD[0][t][r] = w0; vD[1][t][r] = w1; vD[2][t][r] = w2;
                float vv = w0 * w0 + w1 * w1 + w2 * w2;
                float x2 = x * x;
                psD[t][r] = pc[0][t] * x + pc[1][t] * x2 + pc[2][t] * vv
                          + pc[3][t] * x2 * x + pc[4][t] * x * vv;
                pvsD[t][r] = pc[5][t] + pc[6][t] * x + pc[7][t] * x2 + pc[8][t] * vv;
            }
    } else {
#pragma unroll
        for (int r = 0; r < 4; ++r) {
            int z = spec_srt[i16 + q * 4 + r];
            const float* pb = pw_i + z * 576 + cl;
#pragma unroll
            for (int t = 0; t < 4; ++t) {
                float p0 = pb[t*16], p1 = pb[64+t*16], p2 = pb[128+t*16];
                float p3 = pb[192+t*16], p4 = pb[256+t*16], p5 = pb[320+t*16];
                float p6 = pb[384+t*16], p7 = pb[448+t*16], p8 = pb[512+t*16];
                float x = sD[t][r] * EPS_C;
                float w0 = vD[0][t][r] * EPS_C;
                float w1 = vD[1][t][r] * EPS_C;
                float w2 = vD[2][t][r] * EPS_C;
                vD[0][t][r] = w0; vD[1][t][r] = w1; vD[2][t][r] = w2;
                float vv = w0 * w0 + w1 * w1 + w2 * w2;
                float x2 = x * x;
                psD[t][r] = p0 * x + p1 * x2 + p2 * vv + p3 * x2 * x + p4 * x * vv;
                pvsD[t][r] = p5 + p6 * x + p7 * x2 + p8 * vv;
            }
        }
    }

#pragma unroll
    for (int t = 0; t < 4; ++t)
#pragma unroll
        for (int r = 0; r < 4; ++r)
            xls[(q * 4 + r) * 65 + t * 16 + cl] = psD[t][r];
    short8 psA[2];
#pragma unroll
    for (int h = 0; h < 2; ++h) {
        const float* rp = xls + cl * 65 + h * 32 + q * 8;
        float t0 = rp[0], t1 = rp[1], t2 = rp[2], t3 = rp[3];
        float t4 = rp[4], t5 = rp[5], t6 = rp[6], t7 = rp[7];
        psA[h] = cvt8(make_float4(t0, t1, t2, t3), make_float4(t4, t5, t6, t7));
    }

    f32x4 snD[4];
#pragma unroll
    for (int t = 0; t < 4; ++t) {
        f32x4 acc = {0.f, 0.f, 0.f, 0.f};
        acc = MFMA16(psA[0], loadB(pWps, t, 0, l), acc);
        acc = MFMA16(psA[1], loadB(pWps, t, 1, l), acc);
        snD[t] = acc;
    }
    if (has_skip) {
        const float* srow = s + (size_t)(i16 + cl) * 64;
        short8 Ai0 = loadArow(srow, 0, q), Ai1 = loadArow(srow, 1, q);
        int myz = spec_srt[i16 + cl];
        for (int z = z0; z <= z1; ++z) {
            bool keep = (myz == z);
            short8 m0 = keep ? Ai0 : z8;
            short8 m1 = keep ? Ai1 : z8;
            const short* pz = pSkS + (size_t)z * 4096;
#pragma unroll
            for (int t = 0; t < 4; ++t) {
                snD[t] = MFMA16(m0, loadB(pz, t, 0, l), snD[t]);
                snD[t] = MFMA16(m1, loadB(pz, t, 1, l), snD[t]);
            }
        }
    }
#pragma unroll
    for (int t = 0; t < 4; ++t)
#pragma unroll
        for (int r = 0; r < 4; ++r)
            s[(size_t)(i16 + q * 4 + r) * 64 + t * 16 + cl] = snD[t][r];

    short8 pvA[3][2];
#pragma unroll
    for (int k = 0; k < 3; ++k) {
#pragma unroll
        for (int t = 0; t < 4; ++t)
#pragma unroll
            for (int r = 0; r < 4; ++r)
                xls[(q * 4 + r) * 65 + t * 16 + cl] = pvsD[t][r] * vD[k][t][r];
#pragma unroll
        for (int h = 0; h < 2; ++h) {
            const float* rp = xls + cl * 65 + h * 32 + q * 8;
            float t0 = rp[0], t1 = rp[1], t2 = rp[2], t3 = rp[3];
            float t4 = rp[4], t5 = rp[5], t6 = rp[6], t7 = rp[7];
            pvA[k][h] = cvt8(make_float4(t0, t1, t2, t3), make_float4(t4, t5, t6, t7));
        }
    }

    f32x4 vnD[3][4];
#pragma unroll
    for (int k = 0; k < 3; ++k)
#pragma unroll
        for (int t = 0; t < 4; ++t) vnD[k][t] = (f32x4){0.f, 0.f, 0.f, 0.f};
#pragma unroll
    for (int t = 0; t < 4; ++t)
#pragma unroll
        for (int h = 0; h < 2; ++h) {
            short8 b = loadB(pWpv, t, h, l);
#pragma unroll
            for (int k = 0; k < 3; ++k) vnD[k][t] = MFMA16(pvA[k][h], b, vnD[k][t]);
        }
    if (has_skip) {
        short8 Aiv[3][2];
#pragma unroll
        for (int k = 0; k < 3; ++k) {
            const float* r = v + ((size_t)(i16 + cl) * 3 + k) * 64;
            Aiv[k][0] = loadArow(r, 0, q);
            Aiv[k][1] = loadArow(r, 1, q);
        }
        int myz = spec_srt[i16 + cl];
        for (int z = z0; z <= z1; ++z) {
            bool keep = (myz == z);
            const short* pz = pSkV + (size_t)z * 4096;
#pragma unroll
            for (int t = 0; t < 4; ++t)
#pragma unroll
                for (int h = 0; h < 2; ++h) {
                    short8 b = loadB(pz, t, h, l);
#pragma unroll
                    for (int k = 0; k < 3; ++k) {
                        short8 a = keep ? Aiv[k][h] : z8;
                        vnD[k][t] = MFMA16(a, b, vnD[k][t]);
                    }
                }
        }
    }
#pragma unroll
    for (int k = 0; k < 3; ++k)
#pragma unroll
        for (int t = 0; t < 4; ++t)
#pragma unroll
            for (int r = 0; r < 4; ++r)
                v[((size_t)(i16 + q * 4 + r) * 3 + k) * 64 + t * 16 + cl] = vnD[k][t][r];
}

// ---------------------------------------------------------------------------
// Readouts (sorted s -> out[sidx])
// ---------------------------------------------------------------------------
__global__ __launch_bounds__(256) void read0_kernel(
    const float* __restrict__ s, const float* __restrict__ Wread0,
    const int* __restrict__ sidx, float* __restrict__ out)
{
    const int wid = threadIdx.x >> 6;
    const int f = threadIdx.x & 63;
    const int i4 = (blockIdx.x * 4 + wid) * 4;
    float w0 = Wread0[f];
#pragma unroll
    for (int t = 0; t < 4; ++t) {
        float a = s[(size_t)(i4 + t) * 64 + f] * w0;
        for (int off = 32; off; off >>= 1) a += __shfl_down(a, off);
        if (f == 0) out[(size_t)sidx[i4 + t] * 2 + 0] = a;
    }
}

__global__ __launch_bounds__(256) void read1_kernel(
    const float* __restrict__ s, const float* __restrict__ Wr1a,
    const float* __restrict__ Wr1b, const int* __restrict__ sidx,
    float* __restrict__ out)
{
    const int wid = threadIdx.x >> 6;
    const int f = threadIdx.x & 63;
    const int i4 = (blockIdx.x * 4 + wid) * 4;
    int hh = f & 15;
    int t0 = f >> 4;
    float a = 0.f;
    const float* sp = s + (size_t)(i4 + t0) * 64;
#pragma unroll 8
    for (int g = 0; g < 64; ++g)
        a = fmaf(sp[g], Wr1a[g * 16 + hh], a);
    float r0 = (a / (1.f + expf(-a))) * Wr1b[hh];
    for (int off = 8; off; off >>= 1) r0 += __shfl_down(r0, off);
    if (hh == 0) out[(size_t)sidx[i4 + t0] * 2 + 1] = r0;
}

// ---------------------------------------------------------------------------
extern "C" void kernel_launch(void* const* d_in, const int* in_sizes, int n_in,
                              void* d_out, int out_size, void* d_ws, size_t ws_size,
                              hipStream_t stream)
{
    const float* vectors = (const float*)d_in[0];
    const float* embed_s = (const float*)d_in[1];
    const float* Wr      = (const float*)d_in[2];   // [2,8,320]
    const float* Wls     = (const float*)d_in[3];   // [2,64,64]
    const float* Wlv     = (const float*)d_in[4];
    const float* skip_s  = (const float*)d_in[5];   // [10,64,64]
    const float* skip_v  = (const float*)d_in[6];
    const float* pw      = (const float*)d_in[7];   // [2,10,9,64]
    const float* Wps     = (const float*)d_in[8];
    const float* Wpv     = (const float*)d_in[9];
    const float* Wread0  = (const float*)d_in[10];  // [64,1]
    const float* Wr1a    = (const float*)d_in[11];  // [64,16]
    const float* Wr1b    = (const float*)d_in[12];  // [16,1]
    const int* senders   = (const int*)d_in[13];
    const int* receivers = (const int*)d_in[14];
    const int* species   = (const int*)d_in[15];
    float* out = (float*)d_out;

    float* ws = (float*)d_ws;
    float* edata = ws; ws += (size_t)N_EDGES * 16;  // 16 MB (Y1+rbf fused)
    float* s     = ws; ws += (size_t)N_NODES * 64;  // 8 MB
    float* v     = ws; ws += (size_t)N_NODES * 192; // 24 MB
    float* agg_s = ws; ws += (size_t)N_NODES * 64;  // 8 MB
    float* agg_v = ws; ws += (size_t)N_NODES * 192; // 24 MB
    int* counts    = (int*)ws; ws += N_NODES;
    int* row_start = (int*)ws; ws += N_NODES + 4;
    int* cursor    = (int*)ws; ws += N_NODES;
    int* edge_ids  = (int*)ws; ws += N_EDGES;
    int2* esr      = (int2*)ws; ws += N_EDGES * 2;
    int* sidx      = (int*)ws; ws += N_NODES;
    int* rank      = (int*)ws; ws += N_NODES;
    int* spec_srt  = (int*)ws; ws += N_NODES;
    int* lrank_arr = (int*)ws; ws += N_NODES;
    int* counts_blk = (int*)ws; ws += 128 * NSPEC;
    int* off_blk    = (int*)ws; ws += 128 * NSPEC;
    short* packW   = (short*)ws;                    // 224 KB

    edge_pre_kernel<<<N_EDGES / 256, 256, 0, stream>>>(vectors, edata);

    // species counting sort (no atomics, deterministic)
    sort1_kernel<<<N_NODES / 256, 256, 0, stream>>>(species, counts_blk, lrank_arr);
    sort2_kernel<<<1, 64, 0, stream>>>(counts_blk, off_blk);
    sort3_kernel<<<N_NODES / 256, 256, 0, stream>>>(
        species, lrank_arr, off_blk, sidx, rank, spec_srt);

    // receiver CSR in sorted space + LDS row-sort + fused esr stream
    hipMemsetAsync(counts, 0, N_NODES * sizeof(int), stream);
    hist_kernel<<<N_EDGES / 256, 256, 0, stream>>>(receivers, rank, counts);
    scan_kernel<<<1, 1024, 0, stream>>>(counts, row_start, cursor);
    scatter_kernel<<<N_EDGES / 256, 256, 0, stream>>>(receivers, rank, cursor, edge_ids);
    rowsort_kernel<<<N_NODES / 256, 256, 0, stream>>>(row_start, edge_ids);
    sr_kernel<<<N_EDGES / 256, 256, 0, stream>>>(senders, edge_ids, rank, esr);

    init_s_kernel<<<N_NODES * 64 / 256, 256, 0, stream>>>(embed_s, spec_srt, s);
    pack_kernel<<<448, 256, 0, stream>>>(Wls, Wlv, Wps, Wpv, skip_s, skip_v, packW);

    // interaction 0
    gather_kernel<1><<<N_NODES / 16, 256, 0, stream>>>(
        edata, esr, row_start, s, v, Wr, agg_s, agg_v);
    node_mfma_kernel<<<N_NODES / 64, 256, 0, stream>>>(
        agg_s, agg_v, s, v, packW, 0, pw, spec_srt, 0);
    read0_kernel<<<N_NODES / 16, 256, 0, stream>>>(s, Wread0, sidx, out);

    // interaction 1
    gather_kernel<0><<<N_NODES / 16, 256, 0, stream>>>(
        edata, esr, row_start, s, v, Wr + 2560, agg_s, agg_v);
    node_mfma_kernel<<<N_NODES / 64, 256, 0, stream>>>(
        agg_s, agg_v, s, v, packW, 1, pw + 5760, spec_srt, 1);
    read1_kernel<<<N_NODES / 16, 256, 0, stream>>>(s, Wr1a, Wr1b, sidx, out);
}

// Round 11
// 356.498 us; speedup vs baseline: 1.0463x; 1.0463x over previous
//
#include <hip/hip_runtime.h>
#include <hip/hip_bf16.h>
#include <math.h>

#define N_NODES 32768
#define N_EDGES 262144
#define EPS_C 0.24253562503633297f   // 1/sqrt(17)
#define NSPEC 10

typedef __attribute__((ext_vector_type(8))) short short8;   // 8 bf16
typedef __attribute__((ext_vector_type(4))) float f32x4;    // 4 fp32 acc

#define MFMA16(a, b, c) __builtin_amdgcn_mfma_f32_16x16x32_bf16(a, b, c, 0, 0, 0)

__device__ __forceinline__ short2 cvt2(float a, float b) {
    union { __hip_bfloat162 h; short2 s; } u;
    u.h = __float22bfloat162_rn(make_float2(a, b));
    return u.s;
}
__device__ __forceinline__ short8 cvt8(float4 a, float4 b) {
    short2 p0 = cvt2(a.x, a.y), p1 = cvt2(a.z, a.w);
    short2 p2 = cvt2(b.x, b.y), p3 = cvt2(b.z, b.w);
    short8 r;
    r[0] = p0.x; r[1] = p0.y; r[2] = p1.x; r[3] = p1.y;
    r[4] = p2.x; r[5] = p2.y; r[6] = p3.x; r[7] = p3.y;
    return r;
}
__device__ __forceinline__ short8 loadArow(const float* rowp, int h, int q) {
    const float* p = rowp + h * 32 + q * 8;
    return cvt8(*(const float4*)p, *(const float4*)(p + 4));
}
__device__ __forceinline__ short8 loadB(const short* P, int t, int h, int l) {
    return *(const short8*)(P + (((t * 2 + h) * 64 + l) << 3));
}

// ---------------------------------------------------------------------------
// Species counting sort — contention-free, deterministic (ballot/popcount).
// ---------------------------------------------------------------------------
__global__ __launch_bounds__(256) void sort1_kernel(
    const int* __restrict__ species, int* __restrict__ counts_blk,
    int* __restrict__ lrank_arr)
{
    __shared__ int wcnt[4][16];
    int n = blockIdx.x * 256 + threadIdx.x;
    int sp = species[n];
    int lane = threadIdx.x & 63, wv = threadIdx.x >> 6;
    unsigned long long ltmask = (1ull << lane) - 1;
    int lrank_w = 0;
#pragma unroll
    for (int z = 0; z < NSPEC; ++z) {
        unsigned long long m = __ballot(sp == z);
        if (sp == z) lrank_w = __popcll(m & ltmask);
        if (lane == 0) wcnt[wv][z] = __popcll(m);
    }
    __syncthreads();
    int off = 0;
    for (int w = 0; w < wv; ++w) off += wcnt[w][sp];
    lrank_arr[n] = lrank_w + off;
    if (threadIdx.x < NSPEC)
        counts_blk[blockIdx.x * NSPEC + threadIdx.x] =
            wcnt[0][threadIdx.x] + wcnt[1][threadIdx.x] +
            wcnt[2][threadIdx.x] + wcnt[3][threadIdx.x];
}

__global__ __launch_bounds__(64) void sort2_kernel(
    const int* __restrict__ counts_blk, int* __restrict__ off_blk)
{
    __shared__ int total[NSPEC], base[NSPEC];
    int z = threadIdx.x;
    if (z < NSPEC) {
        int t = 0;
        for (int b = 0; b < 128; ++b) t += counts_blk[b * NSPEC + z];
        total[z] = t;
    }
    __syncthreads();
    if (z == 0) {
        int run = 0;
        for (int q = 0; q < NSPEC; ++q) { base[q] = run; run += total[q]; }
    }
    __syncthreads();
    if (z < NSPEC) {
        int run = base[z];
        for (int b = 0; b < 128; ++b) {
            off_blk[b * NSPEC + z] = run;
            run += counts_blk[b * NSPEC + z];
        }
    }
}

__global__ __launch_bounds__(256) void sort3_kernel(
    const int* __restrict__ species, const int* __restrict__ lrank_arr,
    const int* __restrict__ off_blk,
    int* __restrict__ sidx, int* __restrict__ rank, int* __restrict__ spec_srt)
{
    int n = blockIdx.x * 256 + threadIdx.x;
    int sp = species[n];
    int slot = off_blk[blockIdx.x * NSPEC + sp] + lrank_arr[n];
    sidx[slot] = n;
    rank[n] = slot;
    spec_srt[slot] = sp;
}

// ---------------------------------------------------------------------------
// Receiver CSR in SORTED space
// ---------------------------------------------------------------------------
__global__ __launch_bounds__(256) void hist_kernel(
    const int* __restrict__ receivers, const int* __restrict__ rank,
    int* __restrict__ counts)
{
    int e = blockIdx.x * 256 + threadIdx.x;
    atomicAdd(&counts[rank[receivers[e]]], 1);
}

__global__ __launch_bounds__(1024) void scan_kernel(
    const int* __restrict__ counts, int* __restrict__ row_start, int* __restrict__ cursor)
{
    __shared__ int wave_tot[16];
    int tid = threadIdx.x;
    int c[32];
    int sum = 0;
#pragma unroll
    for (int i = 0; i < 32; ++i) { c[i] = counts[tid * 32 + i]; sum += c[i]; }
    int lane = tid & 63, wv = tid >> 6;
    int x = sum;
#pragma unroll
    for (int off = 1; off < 64; off <<= 1) {
        int y = __shfl_up(x, off);
        if (lane >= off) x += y;
    }
    if (lane == 63) wave_tot[wv] = x;
    __syncthreads();
    if (wv == 0 && lane < 16) {
        int t = wave_tot[lane];
#pragma unroll
        for (int off = 1; off < 16; off <<= 1) {
            int y = __shfl_up(t, off);
            if (lane >= off) t += y;
        }
        wave_tot[lane] = t;
    }
    __syncthreads();
    int excl = x - sum + (wv ? wave_tot[wv - 1] : 0);
    int run = excl;
#pragma unroll
    for (int i = 0; i < 32; ++i) {
        row_start[tid * 32 + i] = run;
        cursor[tid * 32 + i] = run;
        run += c[i];
    }
    if (tid == 1023) row_start[32768] = run;
}

__global__ __launch_bounds__(256) void scatter_kernel(
    const int* __restrict__ receivers, const int* __restrict__ rank,
    int* __restrict__ cursor, int* __restrict__ edge_ids)
{
    int e = blockIdx.x * 256 + threadIdx.x;
    int slot = atomicAdd(&cursor[rank[receivers[e]]], 1);
    edge_ids[slot] = e;
}

// per-row insertion sort in LDS (deterministic edge order per row)
__global__ __launch_bounds__(256) void rowsort_kernel(
    const int* __restrict__ row_start, int* __restrict__ edge_ids)
{
    __shared__ int buf[256 * 33];
    int i = blockIdx.x * 256 + threadIdx.x;
    int beg = row_start[i], end = row_start[i + 1];
    int len = end - beg;
    int* b = buf + threadIdx.x * 33;
    if (len <= 32) {
        for (int j = 0; j < len; ++j) b[j] = edge_ids[beg + j];
        for (int a = 1; a < len; ++a) {
            int key = b[a];
            int c = a - 1;
            while (c >= 0 && b[c] > key) { b[c + 1] = b[c]; --c; }
            b[c + 1] = key;
        }
        for (int j = 0; j < len; ++j) edge_ids[beg + j] = b[j];
    } else {
        for (int a = beg + 1; a < end; ++a) {
            int key = edge_ids[a];
            int c = a - 1;
            while (c >= beg && edge_ids[c] > key) { edge_ids[c + 1] = edge_ids[c]; --c; }
            edge_ids[c + 1] = key;
        }
    }
}

// slot_of[e]: CSR slot of original edge e; srk[p]: sender rank per slot
__global__ __launch_bounds__(256) void slotof_kernel(
    const int* __restrict__ edge_ids, int* __restrict__ slot_of)
{
    int p = blockIdx.x * 256 + threadIdx.x;
    slot_of[edge_ids[p]] = p;
}
__global__ __launch_bounds__(256) void sr_kernel(
    const int* __restrict__ senders, const int* __restrict__ edge_ids,
    const int* __restrict__ rank, int* __restrict__ srk)
{
    int p = blockIdx.x * 256 + threadIdx.x;
    srk[p] = rank[senders[edge_ids[p]]];
}

// wave_row[w]: row containing slot 32w (largest r with row_start[r] <= 32w)
__global__ __launch_bounds__(256) void waverow_kernel(
    const int* __restrict__ row_start, int* __restrict__ wave_row)
{
    int w = blockIdx.x * 256 + threadIdx.x;   // 8192
    int target = w * 32;
    int lo = 0, hi = N_NODES - 1;
    while (lo < hi) {
        int mid = (lo + hi + 1) >> 1;
        if (row_start[mid] <= target) lo = mid; else hi = mid - 1;
    }
    wave_row[w] = lo;
}

// zero agg rows that are empty or cross a 32-slot wave boundary
__global__ __launch_bounds__(256) void zero_bnd_kernel(
    const int* __restrict__ row_start,
    float* __restrict__ agg_s, float* __restrict__ agg_v)
{
    const int wid = threadIdx.x >> 6;
    const int f = threadIdx.x & 63;
    const int base = (blockIdx.x * 4 + wid) * 4;
#pragma unroll
    for (int t = 0; t < 4; ++t) {
        int i = base + t;
        int beg = row_start[i], end = row_start[i + 1];
        bool need = (end == beg) || (end > (((beg >> 5) + 1) << 5));
        if (need) {
            agg_s[(size_t)i * 64 + f] = 0.f;
            agg_v[((size_t)i * 3 + 0) * 64 + f] = 0.f;
            agg_v[((size_t)i * 3 + 1) * 64 + f] = 0.f;
            agg_v[((size_t)i * 3 + 2) * 64 + f] = 0.f;
        }
    }
}

// ---------------------------------------------------------------------------
// Edge precompute, written directly in CSR-slot order (64B records):
// edata[slot_of[e]*16] = {y0,y1,y2,0, rbf[8], pad}
// ---------------------------------------------------------------------------
__global__ __launch_bounds__(256) void edge_pre_kernel(
    const float* __restrict__ vectors, const int* __restrict__ slot_of,
    float* __restrict__ edata)
{
    int e = blockIdx.x * 256 + threadIdx.x;
    float x = vectors[e * 3 + 0], y = vectors[e * 3 + 1], z = vectors[e * 3 + 2];
    float r2 = x * x + y * y + z * z + 1e-12f;
    float r = sqrtf(r2);
    float inv = 1.0f / r;
    float* d = edata + (size_t)slot_of[e] * 16;
    *(float4*)d = make_float4(x * inv, y * inv, z * inv, 0.0f);
    float rc = fmaxf(r, 1e-6f);
    float r6 = r2 * r2 * r2;
    float r7 = r6 * r;
    float r8 = r6 * r2;
    float env = (r < 1.0f) ? (1.0f - 28.0f * r6 + 48.0f * r7 - 21.0f * r8) : 0.0f;
    float sc = 1.41421356237309515f * env / rc;
#pragma unroll
    for (int j = 0; j < 8; ++j)
        d[4 + j] = sc * sinf((float)(j + 1) * 3.14159265358979323846f * rc);
    d[12] = 0.f; d[13] = 0.f; d[14] = 0.f; d[15] = 0.f;
}

// ---------------------------------------------------------------------------
// Node init (sorted layout)
// ---------------------------------------------------------------------------
__global__ __launch_bounds__(256) void init_s_kernel(
    const float* __restrict__ embed_s, const int* __restrict__ spec_srt,
    float* __restrict__ s)
{
    int idx = blockIdx.x * 256 + threadIdx.x;
    s[idx] = embed_s[spec_srt[idx >> 6] * 64 + (idx & 63)];
}

// ---------------------------------------------------------------------------
// Weight pre-pack: 28 64x64 fp32 matrices -> bf16 B-fragment order.
// ---------------------------------------------------------------------------
__global__ __launch_bounds__(256) void pack_kernel(
    const float* __restrict__ Wls, const float* __restrict__ Wlv,
    const float* __restrict__ Wps, const float* __restrict__ Wpv,
    const float* __restrict__ skip_s, const float* __restrict__ skip_v,
    short* __restrict__ packW)
{
    int idx = blockIdx.x * 256 + threadIdx.x;   // 28*4096 = 114688
    if (idx >= 28 * 4096) return;
    int m = idx >> 12, e = idx & 4095;
    int t = e >> 10, h = (e >> 9) & 1, l = (e >> 3) & 63, j = e & 7;
    int fi = h * 32 + ((l >> 4) << 3) + j;
    int fo = t * 16 + (l & 15);
    const float* src;
    if      (m < 2)  src = Wls    + m * 4096;
    else if (m < 4)  src = Wlv    + (m - 2) * 4096;
    else if (m < 6)  src = Wps    + (m - 4) * 4096;
    else if (m < 8)  src = Wpv    + (m - 6) * 4096;
    else if (m < 18) src = skip_s + (m - 8) * 4096;
    else             src = skip_v + (m - 18) * 4096;
    packW[idx] = cvt2(src[fi * 64 + fo], 0.f).x;
}

// ---------------------------------------------------------------------------
// Edge-balanced gather: wave w handles CSR slots [32w, 32w+32) exactly.
// edata/srk streams are sequential; s/v reads pipelined 1-ahead (R9 rotate).
// Rows fully inside the range: plain store. Boundary rows: unsafeAtomicAdd
// into pre-zeroed agg. Row-boundary logic is wave-uniform.
// ---------------------------------------------------------------------------
template<int VZERO>
__global__ __launch_bounds__(256) void gather_kernel(
    const float* __restrict__ edata, const int* __restrict__ srk,
    const int* __restrict__ row_start, const int* __restrict__ wave_row,
    const float* __restrict__ s_in, const float* __restrict__ v_in,
    const float* __restrict__ Wr_i,
    float* __restrict__ agg_s, float* __restrict__ agg_v)
{
    const int wid = threadIdx.x >> 6;
    const int f = threadIdx.x & 63;
    const int w = blockIdx.x * 4 + wid;
    const int p0 = w * 32, p1 = p0 + 32;

    float wr[5][8];
#pragma unroll
    for (int j = 0; j < 8; ++j)
#pragma unroll
        for (int p = 0; p < 5; ++p)
            wr[p][j] = (VZERO && (p == 1 || p == 3 || p == 4))
                       ? 0.f : Wr_i[j * 320 + p * 64 + f];

    int r = wave_row[w];
    int beg_r = row_start[r], end_r = row_start[r + 1];
    float a0 = 0.f, a1 = 0.f, a2 = 0.f, a3 = 0.f;

    int sr_c = srk[p0];
    float ssC = s_in[(size_t)sr_c * 64 + f];
    float v0C = 0.f, v1C = 0.f, v2C = 0.f;
    if (!VZERO) {
        v0C = v_in[((size_t)sr_c * 3 + 0) * 64 + f];
        v1C = v_in[((size_t)sr_c * 3 + 1) * 64 + f];
        v2C = v_in[((size_t)sr_c * 3 + 2) * 64 + f];
    }

    for (int p = p0; p < p1; ++p) {
        int sr_n = (p + 1 < p1) ? srk[p + 1] : sr_c;
        float ssN = s_in[(size_t)sr_n * 64 + f];
        float v0N = 0.f, v1N = 0.f, v2N = 0.f;
        if (!VZERO) {
            v0N = v_in[((size_t)sr_n * 3 + 0) * 64 + f];
            v1N = v_in[((size_t)sr_n * 3 + 1) * 64 + f];
            v2N = v_in[((size_t)sr_n * 3 + 2) * 64 + f];
        }
        const float* d = edata + (size_t)p * 16;
        float4 yv = *(const float4*)d;
        float4 q0 = *(const float4*)(d + 4);
        float4 q1 = *(const float4*)(d + 8);
        float rb[8] = {q0.x, q0.y, q0.z, q0.w, q1.x, q1.y, q1.z, q1.w};
        float w0 = 0.f, w1 = 0.f, w2 = 0.f, w3 = 0.f, w4 = 0.f;
#pragma unroll
        for (int j = 0; j < 8; ++j) {
            w0 = fmaf(rb[j], wr[0][j], w0);
            if (!VZERO) w1 = fmaf(rb[j], wr[1][j], w1);
            w2 = fmaf(rb[j], wr[2][j], w2);
            if (!VZERO) w3 = fmaf(rb[j], wr[3][j], w3);
            if (!VZERO) w4 = fmaf(rb[j], wr[4][j], w4);
        }
        if (VZERO) {
            a0 += w0 * ssC;
            float ws2 = w2 * ssC;
            a1 += ws2 * yv.x; a2 += ws2 * yv.y; a3 += ws2 * yv.z;
        } else {
            float dot = v0C * yv.x + v1C * yv.y + v2C * yv.z;
            a0 += w0 * ssC + w1 * dot;
            float c0 = v1C * yv.z - v2C * yv.y;
            float c1 = v2C * yv.x - v0C * yv.z;
            float c2 = v0C * yv.y - v1C * yv.x;
            float ws2 = w2 * ssC;
            a1 += ws2 * yv.x + w3 * v0C + w4 * c0;
            a2 += ws2 * yv.y + w3 * v1C + w4 * c1;
            a3 += ws2 * yv.z + w3 * v2C + w4 * c2;
        }
        // flush at row end or range end (wave-uniform)
        if (p + 1 == end_r || p + 1 == p1) {
            bool interior = (beg_r >= p0) && (end_r <= p1);
            if (interior) {
                agg_s[(size_t)r * 64 + f] = a0;
                agg_v[((size_t)r * 3 + 0) * 64 + f] = a1;
                agg_v[((size_t)r * 3 + 1) * 64 + f] = a2;
                agg_v[((size_t)r * 3 + 2) * 64 + f] = a3;
            } else {
                unsafeAtomicAdd(&agg_s[(size_t)r * 64 + f], a0);
                unsafeAtomicAdd(&agg_v[((size_t)r * 3 + 0) * 64 + f], a1);
                unsafeAtomicAdd(&agg_v[((size_t)r * 3 + 1) * 64 + f], a2);
                unsafeAtomicAdd(&agg_v[((size_t)r * 3 + 2) * 64 + f], a3);
            }
            a0 = a1 = a2 = a3 = 0.f;
            if (p + 1 == end_r && p + 1 < p1) {
                beg_r = end_r; ++r; end_r = row_start[r + 1];
                while (end_r == beg_r) { ++r; end_r = row_start[r + 1]; }
            }
        }
        ssC = ssN; v0C = v0N; v1C = v1N; v2C = v2N; sr_c = sr_n;
    }
}

// ---------------------------------------------------------------------------
// MFMA node kernel (unchanged): wave = 16 sorted nodes.
// ---------------------------------------------------------------------------
__global__ __launch_bounds__(256) void node_mfma_kernel(
    const float* __restrict__ agg_s, const float* __restrict__ agg_v,
    float* s, float* v,
    const short* __restrict__ packW, int it,
    const float* __restrict__ pw_i,
    const int* __restrict__ spec_srt,
    int has_skip)
{
    const int l = threadIdx.x & 63;
    const int wid = threadIdx.x >> 6;
    const int cl = l & 15;
    const int q = l >> 4;
    const int i16 = (blockIdx.x * 4 + wid) * 16;
    __shared__ float xls_all[4][16 * 65];
    float* xls = xls_all[wid];

    const short* pWls = packW + (size_t)(0 + it) * 4096;
    const short* pWlv = packW + (size_t)(2 + it) * 4096;
    const short* pWps = packW + (size_t)(4 + it) * 4096;
    const short* pWpv = packW + (size_t)(6 + it) * 4096;
    const short* pSkS = packW + (size_t)8 * 4096;
    const short* pSkV = packW + (size_t)18 * 4096;
    const short8 z8 = {0, 0, 0, 0, 0, 0, 0, 0};

    const float* ars = agg_s + (size_t)(i16 + cl) * 64;
    short8 As[2] = { loadArow(ars, 0, q), loadArow(ars, 1, q) };
    short8 Av[3][2];
#pragma unroll
    for (int k = 0; k < 3; ++k) {
        const float* r = agg_v + ((size_t)(i16 + cl) * 3 + k) * 64;
        Av[k][0] = loadArow(r, 0, q);
        Av[k][1] = loadArow(r, 1, q);
    }

    f32x4 sD[4];
#pragma unroll
    for (int t = 0; t < 4; ++t) {
        f32x4 acc = {0.f, 0.f, 0.f, 0.f};
        acc = MFMA16(As[0], loadB(pWls, t, 0, l), acc);
        acc = MFMA16(As[1], loadB(pWls, t, 1, l), acc);
        sD[t] = acc;
    }

    f32x4 vD[3][4];
#pragma unroll
    for (int k = 0; k < 3; ++k)
#pragma unroll
        for (int t = 0; t < 4; ++t) vD[k][t] = (f32x4){0.f, 0.f, 0.f, 0.f};
#pragma unroll
    for (int t = 0; t < 4; ++t)
#pragma unroll
        for (int h = 0; h < 2; ++h) {
            short8 b = loadB(pWlv, t, h, l);
#pragma unroll
            for (int k = 0; k < 3; ++k) vD[k][t] = MFMA16(Av[k][h], b, vD[k][t]);
        }

    int z0 = spec_srt[i16], z1 = spec_srt[i16 + 15];
    float psD[4][4], pvsD[4][4];
    if (z0 == z1) {
        const float* pb = pw_i + z0 * 576 + cl;
        float pc[9][4];
#pragma unroll
        for (int c = 0; c < 9; ++c)
#pragma unroll
            for (int t = 0; t < 4; ++t) pc[c][t] = pb[c * 64 + t * 16];
#pragma unroll
        for (int t = 0; t < 4; ++t)
#pragma unroll
            for (int r = 0; r < 4; ++r) {
                float x = sD[t][r] * EPS_C;
                float w0 = vD[0][t][r] * EPS_C;
                float w1 = vD[1][t][r] * EPS_C;
                float w2 = vD[2][t][r] * EPS_C;
                vD[0][t][r] = w0; vD[1][t][r] = w1; vD[2][t][r] = w2;
                float vv = w0 * w0 + w1 * w1 + w2 * w2;
                float x2 = x * x;
                psD[t][r] = pc[0][t] * x + pc[1][t] * x2 + pc[2][t] * vv
                          + pc[3][t] * x2 * x + pc[4][t] * x * vv;
                pvsD[t][r] = pc[5][t] + pc[6][t] * x + pc[7][t] * x2 + pc[8][t] * vv;
            }
    } else {
#pragma unroll
        for (int r = 0; r < 4; ++r) {
            int z = spec_srt[i16 + q * 4 + r];
            const float* pb = pw_i + z * 576 + cl;
#pragma unroll
            for (int t = 0; t < 4; ++t) {
                float p0 = pb[t*16], p1 = pb[64+t*16], p2 = pb[128+t*16];
                float p3 = pb[192+t*16], p4 = pb[256+t*16], p5 = pb[320+t*16];
                float p6 = pb[384+t*16], p7 = pb[448+t*16], p8 = pb[512+t*16];
                float x = sD[t][r] * EPS_C;
                float w0 = vD[0][t][r] * EPS_C;
                float w1 = vD[1][t][r] * EPS_C;
                float w2 = vD[2][t][r] * EPS_C;
                vD[0][t][r] = w0; vD[1][t][r] = w1; vD[2][t][r] = w2;
                float vv = w0 * w0 + w1 * w1 + w2 * w2;
                float x2 = x * x;
                psD[t][r] = p0 * x + p1 * x2 + p2 * vv + p3 * x2 * x + p4 * x * vv;
                pvsD[t][r] = p5 + p6 * x + p7 * x2 + p8 * vv;
            }
        }
    }

#pragma unroll
    for (int t = 0; t < 4; ++t)
#pragma unroll
        for (int r = 0; r < 4; ++r)
            xls[(q * 4 + r) * 65 + t * 16 + cl] = psD[t][r];
    short8 psA[2];
#pragma unroll
    for (int h = 0; h < 2; ++h) {
        const float* rp = xls + cl * 65 + h * 32 + q * 8;
        float t0 = rp[0], t1 = rp[1], t2 = rp[2], t3 = rp[3];
        float t4 = rp[4], t5 = rp[5], t6 = rp[6], t7 = rp[7];
        psA[h] = cvt8(make_float4(t0, t1, t2, t3), make_float4(t4, t5, t6, t7));
    }

    f32x4 snD[4];
#pragma unroll
    for (int t = 0; t < 4; ++t) {
        f32x4 acc = {0.f, 0.f, 0.f, 0.f};
        acc = MFMA16(psA[0], loadB(pWps, t, 0, l), acc);
        acc = MFMA16(psA[1], loadB(pWps, t, 1, l), acc);
        snD[t] = acc;
    }
    if (has_skip) {
        const float* srow = s + (size_t)(i16 + cl) * 64;
        short8 Ai0 = loadArow(srow, 0, q), Ai1 = loadArow(srow, 1, q);
        int myz = spec_srt[i16 + cl];
        for (int z = z0; z <= z1; ++z) {
            bool keep = (myz == z);
            short8 m0 = keep ? Ai0 : z8;
            short8 m1 = keep ? Ai1 : z8;
            const short* pz = pSkS + (size_t)z * 4096;
#pragma unroll
            for (int t = 0; t < 4; ++t) {
                snD[t] = MFMA16(m0, loadB(pz, t, 0, l), snD[t]);
                snD[t] = MFMA16(m1, loadB(pz, t, 1, l), snD[t]);
            }
        }
    }
#pragma unroll
    for (int t = 0; t < 4; ++t)
#pragma unroll
        for (int r = 0; r < 4; ++r)
            s[(size_t)(i16 + q * 4 + r) * 64 + t * 16 + cl] = snD[t][r];

    short8 pvA[3][2];
#pragma unroll
    for (int k = 0; k < 3; ++k) {
#pragma unroll
        for (int t = 0; t < 4; ++t)
#pragma unroll
            for (int r = 0; r < 4; ++r)
                xls[(q * 4 + r) * 65 + t * 16 + cl] = pvsD[t][r] * vD[k][t][r];
#pragma unroll
        for (int h = 0; h < 2; ++h) {
            const float* rp = xls + cl * 65 + h * 32 + q * 8;
            float t0 = rp[0], t1 = rp[1], t2 = rp[2], t3 = rp[3];
            float t4 = rp[4], t5 = rp[5], t6 = rp[6], t7 = rp[7];
            pvA[k][h] = cvt8(make_float4(t0, t1, t2, t3), make_float4(t4, t5, t6, t7));
        }
    }

    f32x4 vnD[3][4];
#pragma unroll
    for (int k = 0; k < 3; ++k)
#pragma unroll
        for (int t = 0; t < 4; ++t) vnD[k][t] = (f32x4){0.f, 0.f, 0.f, 0.f};
#pragma unroll
    for (int t = 0; t < 4; ++t)
#pragma unroll
        for (int h = 0; h < 2; ++h) {
            short8 b = loadB(pWpv, t, h, l);
#pragma unroll
            for (int k = 0; k < 3; ++k) vnD[k][t] = MFMA16(pvA[k][h], b, vnD[k][t]);
        }
    if (has_skip) {
        short8 Aiv[3][2];
#pragma unroll
        for (int k = 0; k < 3; ++k) {
            const float* r = v + ((size_t)(i16 + cl) * 3 + k) * 64;
            Aiv[k][0] = loadArow(r, 0, q);
            Aiv[k][1] = loadArow(r, 1, q);
        }
        int myz = spec_srt[i16 + cl];
        for (int z = z0; z <= z1; ++z) {
            bool keep = (myz == z);
            const short* pz = pSkV + (size_t)z * 4096;
#pragma unroll
            for (int t = 0; t < 4; ++t)
#pragma unroll
                for (int h = 0; h < 2; ++h) {
                    short8 b = loadB(pz, t, h, l);
#pragma unroll
                    for (int k = 0; k < 3; ++k) {
                        short8 a = keep ? Aiv[k][h] : z8;
                        vnD[k][t] = MFMA16(a, b, vnD[k][t]);
                    }
                }
        }
    }
#pragma unroll
    for (int k = 0; k < 3; ++k)
#pragma unroll
        for (int t = 0; t < 4; ++t)
#pragma unroll
            for (int r = 0; r < 4; ++r)
                v[((size_t)(i16 + q * 4 + r) * 3 + k) * 64 + t * 16 + cl] = vnD[k][t][r];
}

// ---------------------------------------------------------------------------
// Readouts (sorted s -> out[sidx])
// ---------------------------------------------------------------------------
__global__ __launch_bounds__(256) void read0_kernel(
    const float* __restrict__ s, const float* __restrict__ Wread0,
    const int* __restrict__ sidx, float* __restrict__ out)
{
    const int wid = threadIdx.x >> 6;
    const int f = threadIdx.x & 63;
    const int i4 = (blockIdx.x * 4 + wid) * 4;
    float w0 = Wread0[f];
#pragma unroll
    for (int t = 0; t < 4; ++t) {
        float a = s[(size_t)(i4 + t) * 64 + f] * w0;
        for (int off = 32; off; off >>= 1) a += __shfl_down(a, off);
        if (f == 0) out[(size_t)sidx[i4 + t] * 2 + 0] = a;
    }
}

__global__ __launch_bounds__(256) void read1_kernel(
    const float* __restrict__ s, const float* __restrict__ Wr1a,
    const float* __restrict__ Wr1b, const int* __restrict__ sidx,
    float* __restrict__ out)
{
    const int wid = threadIdx.x >> 6;
    const int f = threadIdx.x & 63;
    const int i4 = (blockIdx.x * 4 + wid) * 4;
    int hh = f & 15;
    int t0 = f >> 4;
    float a = 0.f;
    const float* sp = s + (size_t)(i4 + t0) * 64;
#pragma unroll 8
    for (int g = 0; g < 64; ++g)
        a = fmaf(sp[g], Wr1a[g * 16 + hh], a);
    float r0 = (a / (1.f + expf(-a))) * Wr1b[hh];
    for (int off = 8; off; off >>= 1) r0 += __shfl_down(r0, off);
    if (hh == 0) out[(size_t)sidx[i4 + t0] * 2 + 1] = r0;
}

// ---------------------------------------------------------------------------
extern "C" void kernel_launch(void* const* d_in, const int* in_sizes, int n_in,
                              void* d_out, int out_size, void* d_ws, size_t ws_size,
                              hipStream_t stream)
{
    const float* vectors = (const float*)d_in[0];
    const float* embed_s = (const float*)d_in[1];
    const float* Wr      = (const float*)d_in[2];   // [2,8,320]
    const float* Wls     = (const float*)d_in[3];   // [2,64,64]
    const float* Wlv     = (const float*)d_in[4];
    const float* skip_s  = (const float*)d_in[5];   // [10,64,64]
    const float* skip_v  = (const float*)d_in[6];
    const float* pw      = (const float*)d_in[7];   // [2,10,9,64]
    const float* Wps     = (const float*)d_in[8];
    const float* Wpv     = (const float*)d_in[9];
    const float* Wread0  = (const float*)d_in[10];  // [64,1]
    const float* Wr1a    = (const float*)d_in[11];  // [64,16]
    const float* Wr1b    = (const float*)d_in[12];  // [16,1]
    const int* senders   = (const int*)d_in[13];
    const int* receivers = (const int*)d_in[14];
    const int* species   = (const int*)d_in[15];
    float* out = (float*)d_out;

    float* ws = (float*)d_ws;
    float* edata = ws; ws += (size_t)N_EDGES * 16;  // 16 MB (slot-ordered)
    float* s     = ws; ws += (size_t)N_NODES * 64;  // 8 MB
    float* v     = ws; ws += (size_t)N_NODES * 192; // 24 MB
    float* agg_s = ws; ws += (size_t)N_NODES * 64;  // 8 MB
    float* agg_v = ws; ws += (size_t)N_NODES * 192; // 24 MB
    int* counts    = (int*)ws; ws += N_NODES;
    int* row_start = (int*)ws; ws += N_NODES + 4;
    int* cursor    = (int*)ws; ws += N_NODES;
    int* edge_ids  = (int*)ws; ws += N_EDGES;
    int* srk       = (int*)ws; ws += N_EDGES;
    int* slot_of   = (int*)ws; ws += N_EDGES;
    int* wave_row  = (int*)ws; ws += N_EDGES / 32;
    int* sidx      = (int*)ws; ws += N_NODES;
    int* rank      = (int*)ws; ws += N_NODES;
    int* spec_srt  = (int*)ws; ws += N_NODES;
    int* lrank_arr = (int*)ws; ws += N_NODES;
    int* counts_blk = (int*)ws; ws += 128 * NSPEC;
    int* off_blk    = (int*)ws; ws += 128 * NSPEC;
    short* packW   = (short*)ws;                    // 224 KB

    // species counting sort (no atomics, deterministic)
    sort1_kernel<<<N_NODES / 256, 256, 0, stream>>>(species, counts_blk, lrank_arr);
    sort2_kernel<<<1, 64, 0, stream>>>(counts_blk, off_blk);
    sort3_kernel<<<N_NODES / 256, 256, 0, stream>>>(
        species, lrank_arr, off_blk, sidx, rank, spec_srt);

    // receiver CSR in sorted space, deterministic row order
    hipMemsetAsync(counts, 0, N_NODES * sizeof(int), stream);
    hist_kernel<<<N_EDGES / 256, 256, 0, stream>>>(receivers, rank, counts);
    scan_kernel<<<1, 1024, 0, stream>>>(counts, row_start, cursor);
    scatter_kernel<<<N_EDGES / 256, 256, 0, stream>>>(receivers, rank, cursor, edge_ids);
    rowsort_kernel<<<N_NODES / 256, 256, 0, stream>>>(row_start, edge_ids);
    slotof_kernel<<<N_EDGES / 256, 256, 0, stream>>>(edge_ids, slot_of);
    sr_kernel<<<N_EDGES / 256, 256, 0, stream>>>(senders, edge_ids, rank, srk);
    waverow_kernel<<<N_EDGES / 32 / 256, 256, 0, stream>>>(row_start, wave_row);

    // edge features written directly in slot order
    edge_pre_kernel<<<N_EDGES / 256, 256, 0, stream>>>(vectors, slot_of, edata);

    init_s_kernel<<<N_NODES * 64 / 256, 256, 0, stream>>>(embed_s, spec_srt, s);
    pack_kernel<<<448, 256, 0, stream>>>(Wls, Wlv, Wps, Wpv, skip_s, skip_v, packW);

    // interaction 0
    zero_bnd_kernel<<<N_NODES / 16, 256, 0, stream>>>(row_start, agg_s, agg_v);
    gather_kernel<1><<<N_EDGES / 32 / 4, 256, 0, stream>>>(
        edata, srk, row_start, wave_row, s, v, Wr, agg_s, agg_v);
    node_mfma_kernel<<<N_NODES / 64, 256, 0, stream>>>(
        agg_s, agg_v, s, v, packW, 0, pw, spec_srt, 0);
    read0_kernel<<<N_NODES / 16, 256, 0, stream>>>(s, Wread0, sidx, out);

    // interaction 1
    zero_bnd_kernel<<<N_NODES / 16, 256, 0, stream>>>(row_start, agg_s, agg_v);
    gather_kernel<0><<<N_EDGES / 32 / 4, 256, 0, stream>>>(
        edata, srk, row_start, wave_row, s, v, Wr + 2560, agg_s, agg_v);
    node_mfma_kernel<<<N_NODES / 64, 256, 0, stream>>>(
        agg_s, agg_v, s, v, packW, 1, pw + 5760, spec_srt, 1);
    read1_kernel<<<N_NODES / 16, 256, 0, stream>>>(s, Wr1a, Wr1b, sidx, out);
}

// Round 12
// 348.747 us; speedup vs baseline: 1.0696x; 1.0222x over previous
//
#include <hip/hip_runtime.h>
#include <hip/hip_bf16.h>
#include <math.h>

#define N_NODES 32768
#define N_EDGES 262144
#define EPS_C 0.24253562503633297f   // 1/sqrt(17)
#define NSPEC 10

typedef __attribute__((ext_vector_type(8))) short short8;   // 8 bf16
typedef __attribute__((ext_vector_type(4))) float f32x4;    // 4 fp32 acc

#define MFMA16(a, b, c) __builtin_amdgcn_mfma_f32_16x16x32_bf16(a, b, c, 0, 0, 0)

__device__ __forceinline__ short2 cvt2(float a, float b) {
    union { __hip_bfloat162 h; short2 s; } u;
    u.h = __float22bfloat162_rn(make_float2(a, b));
    return u.s;
}
__device__ __forceinline__ short8 cvt8(float4 a, float4 b) {
    short2 p0 = cvt2(a.x, a.y), p1 = cvt2(a.z, a.w);
    short2 p2 = cvt2(b.x, b.y), p3 = cvt2(b.z, b.w);
    short8 r;
    r[0] = p0.x; r[1] = p0.y; r[2] = p1.x; r[3] = p1.y;
    r[4] = p2.x; r[5] = p2.y; r[6] = p3.x; r[7] = p3.y;
    return r;
}
__device__ __forceinline__ short8 loadArow(const float* rowp, int h, int q) {
    const float* p = rowp + h * 32 + q * 8;
    return cvt8(*(const float4*)p, *(const float4*)(p + 4));
}
__device__ __forceinline__ short8 loadB(const short* P, int t, int h, int l) {
    return *(const short8*)(P + (((t * 2 + h) * 64 + l) << 3));
}

// ---------------------------------------------------------------------------
// Species counting sort — contention-free, deterministic (ballot/popcount).
// ---------------------------------------------------------------------------
__global__ __launch_bounds__(256) void sort1_kernel(
    const int* __restrict__ species, int* __restrict__ counts_blk,
    int* __restrict__ lrank_arr)
{
    __shared__ int wcnt[4][16];
    int n = blockIdx.x * 256 + threadIdx.x;
    int sp = species[n];
    int lane = threadIdx.x & 63, wv = threadIdx.x >> 6;
    unsigned long long ltmask = (1ull << lane) - 1;
    int lrank_w = 0;
#pragma unroll
    for (int z = 0; z < NSPEC; ++z) {
        unsigned long long m = __ballot(sp == z);
        if (sp == z) lrank_w = __popcll(m & ltmask);
        if (lane == 0) wcnt[wv][z] = __popcll(m);
    }
    __syncthreads();
    int off = 0;
    for (int w = 0; w < wv; ++w) off += wcnt[w][sp];
    lrank_arr[n] = lrank_w + off;
    if (threadIdx.x < NSPEC)
        counts_blk[blockIdx.x * NSPEC + threadIdx.x] =
            wcnt[0][threadIdx.x] + wcnt[1][threadIdx.x] +
            wcnt[2][threadIdx.x] + wcnt[3][threadIdx.x];
}

__global__ __launch_bounds__(64) void sort2_kernel(
    const int* __restrict__ counts_blk, int* __restrict__ off_blk)
{
    __shared__ int total[NSPEC], base[NSPEC];
    int z = threadIdx.x;
    if (z < NSPEC) {
        int t = 0;
        for (int b = 0; b < 128; ++b) t += counts_blk[b * NSPEC + z];
        total[z] = t;
    }
    __syncthreads();
    if (z == 0) {
        int run = 0;
        for (int q = 0; q < NSPEC; ++q) { base[q] = run; run += total[q]; }
    }
    __syncthreads();
    if (z < NSPEC) {
        int run = base[z];
        for (int b = 0; b < 128; ++b) {
            off_blk[b * NSPEC + z] = run;
            run += counts_blk[b * NSPEC + z];
        }
    }
}

__global__ __launch_bounds__(256) void sort3_kernel(
    const int* __restrict__ species, const int* __restrict__ lrank_arr,
    const int* __restrict__ off_blk,
    int* __restrict__ sidx, int* __restrict__ rank, int* __restrict__ spec_srt)
{
    int n = blockIdx.x * 256 + threadIdx.x;
    int sp = species[n];
    int slot = off_blk[blockIdx.x * NSPEC + sp] + lrank_arr[n];
    sidx[slot] = n;
    rank[n] = slot;
    spec_srt[slot] = sp;
}

// ---------------------------------------------------------------------------
// Receiver CSR in SORTED space
// ---------------------------------------------------------------------------
__global__ __launch_bounds__(256) void hist_kernel(
    const int* __restrict__ receivers, const int* __restrict__ rank,
    int* __restrict__ counts)
{
    int e = blockIdx.x * 256 + threadIdx.x;
    atomicAdd(&counts[rank[receivers[e]]], 1);
}

__global__ __launch_bounds__(1024) void scan_kernel(
    const int* __restrict__ counts, int* __restrict__ row_start, int* __restrict__ cursor)
{
    __shared__ int wave_tot[16];
    int tid = threadIdx.x;
    int c[32];
    int sum = 0;
#pragma unroll
    for (int i = 0; i < 32; ++i) { c[i] = counts[tid * 32 + i]; sum += c[i]; }
    int lane = tid & 63, wv = tid >> 6;
    int x = sum;
#pragma unroll
    for (int off = 1; off < 64; off <<= 1) {
        int y = __shfl_up(x, off);
        if (lane >= off) x += y;
    }
    if (lane == 63) wave_tot[wv] = x;
    __syncthreads();
    if (wv == 0 && lane < 16) {
        int t = wave_tot[lane];
#pragma unroll
        for (int off = 1; off < 16; off <<= 1) {
            int y = __shfl_up(t, off);
            if (lane >= off) t += y;
        }
        wave_tot[lane] = t;
    }
    __syncthreads();
    int excl = x - sum + (wv ? wave_tot[wv - 1] : 0);
    int run = excl;
#pragma unroll
    for (int i = 0; i < 32; ++i) {
        row_start[tid * 32 + i] = run;
        cursor[tid * 32 + i] = run;
        run += c[i];
    }
    if (tid == 1023) row_start[32768] = run;
}

__global__ __launch_bounds__(256) void scatter_kernel(
    const int* __restrict__ receivers, const int* __restrict__ rank,
    int* __restrict__ cursor, int* __restrict__ edge_ids)
{
    int e = blockIdx.x * 256 + threadIdx.x;
    int slot = atomicAdd(&cursor[rank[receivers[e]]], 1);
    edge_ids[slot] = e;
}

// per-row insertion sort in LDS (deterministic edge order per row)
__global__ __launch_bounds__(256) void rowsort_kernel(
    const int* __restrict__ row_start, int* __restrict__ edge_ids)
{
    __shared__ int buf[256 * 33];
    int i = blockIdx.x * 256 + threadIdx.x;
    int beg = row_start[i], end = row_start[i + 1];
    int len = end - beg;
    int* b = buf + threadIdx.x * 33;
    if (len <= 32) {
        for (int j = 0; j < len; ++j) b[j] = edge_ids[beg + j];
        for (int a = 1; a < len; ++a) {
            int key = b[a];
            int c = a - 1;
            while (c >= 0 && b[c] > key) { b[c + 1] = b[c]; --c; }
            b[c + 1] = key;
        }
        for (int j = 0; j < len; ++j) edge_ids[beg + j] = b[j];
    } else {
        for (int a = beg + 1; a < end; ++a) {
            int key = edge_ids[a];
            int c = a - 1;
            while (c >= beg && edge_ids[c] > key) { edge_ids[c + 1] = edge_ids[c]; --c; }
            edge_ids[c + 1] = key;
        }
    }
}

// srk[p]: sender rank per CSR slot
__global__ __launch_bounds__(256) void sr_kernel(
    const int* __restrict__ senders, const int* __restrict__ edge_ids,
    const int* __restrict__ rank, int* __restrict__ srk)
{
    int p = blockIdx.x * 256 + threadIdx.x;
    srk[p] = rank[senders[edge_ids[p]]];
}

// grp_row[g]: row containing slot 16g (largest r with row_start[r] <= 16g)
__global__ __launch_bounds__(256) void grprow_kernel(
    const int* __restrict__ row_start, int* __restrict__ grp_row)
{
    int g = blockIdx.x * 256 + threadIdx.x;   // 16384
    int target = g * 16;
    int lo = 0, hi = N_NODES - 1;
    while (lo < hi) {
        int mid = (lo + hi + 1) >> 1;
        if (row_start[mid] <= target) lo = mid; else hi = mid - 1;
    }
    grp_row[g] = lo;
}

// zero agg rows that are empty or cross a 16-slot chain boundary
__global__ __launch_bounds__(256) void zero_bnd_kernel(
    const int* __restrict__ row_start,
    float* __restrict__ agg_s, float* __restrict__ agg_v)
{
    const int wid = threadIdx.x >> 6;
    const int f = threadIdx.x & 63;
    const int base = (blockIdx.x * 4 + wid) * 4;
#pragma unroll
    for (int t = 0; t < 4; ++t) {
        int i = base + t;
        int beg = row_start[i], end = row_start[i + 1];
        bool need = (end == beg) || (end > (((beg >> 4) + 1) << 4));
        if (need) {
            agg_s[(size_t)i * 64 + f] = 0.f;
            agg_v[((size_t)i * 3 + 0) * 64 + f] = 0.f;
            agg_v[((size_t)i * 3 + 1) * 64 + f] = 0.f;
            agg_v[((size_t)i * 3 + 2) * 64 + f] = 0.f;
        }
    }
}

// ---------------------------------------------------------------------------
// Edge precompute in slot order (sequential 64B writes, gathered 12B reads):
// edata[p*16] = {y0,y1,y2,0, rbf[8], pad}   for p-th CSR slot
// ---------------------------------------------------------------------------
__global__ __launch_bounds__(256) void edge_pre_kernel(
    const float* __restrict__ vectors, const int* __restrict__ edge_ids,
    float* __restrict__ edata)
{
    int p = blockIdx.x * 256 + threadIdx.x;
    int e = edge_ids[p];
    float x = vectors[e * 3 + 0], y = vectors[e * 3 + 1], z = vectors[e * 3 + 2];
    float r2 = x * x + y * y + z * z + 1e-12f;
    float r = sqrtf(r2);
    float inv = 1.0f / r;
    float* d = edata + (size_t)p * 16;
    *(float4*)d = make_float4(x * inv, y * inv, z * inv, 0.0f);
    float rc = fmaxf(r, 1e-6f);
    float r6 = r2 * r2 * r2;
    float r7 = r6 * r;
    float r8 = r6 * r2;
    float env = (r < 1.0f) ? (1.0f - 28.0f * r6 + 48.0f * r7 - 21.0f * r8) : 0.0f;
    float sc = 1.41421356237309515f * env / rc;
#pragma unroll
    for (int j = 0; j < 8; ++j)
        d[4 + j] = sc * sinf((float)(j + 1) * 3.14159265358979323846f * rc);
    d[12] = 0.f; d[13] = 0.f; d[14] = 0.f; d[15] = 0.f;
}

// ---------------------------------------------------------------------------
// Node init (sorted layout)
// ---------------------------------------------------------------------------
__global__ __launch_bounds__(256) void init_s_kernel(
    const float* __restrict__ embed_s, const int* __restrict__ spec_srt,
    float* __restrict__ s)
{
    int idx = blockIdx.x * 256 + threadIdx.x;
    s[idx] = embed_s[spec_srt[idx >> 6] * 64 + (idx & 63)];
}

// ---------------------------------------------------------------------------
// Weight pre-pack: 28 64x64 fp32 matrices -> bf16 B-fragment order.
// ---------------------------------------------------------------------------
__global__ __launch_bounds__(256) void pack_kernel(
    const float* __restrict__ Wls, const float* __restrict__ Wlv,
    const float* __restrict__ Wps, const float* __restrict__ Wpv,
    const float* __restrict__ skip_s, const float* __restrict__ skip_v,
    short* __restrict__ packW)
{
    int idx = blockIdx.x * 256 + threadIdx.x;   // 28*4096 = 114688
    if (idx >= 28 * 4096) return;
    int m = idx >> 12, e = idx & 4095;
    int t = e >> 10, h = (e >> 9) & 1, l = (e >> 3) & 63, j = e & 7;
    int fi = h * 32 + ((l >> 4) << 3) + j;
    int fo = t * 16 + (l & 15);
    const float* src;
    if      (m < 2)  src = Wls    + m * 4096;
    else if (m < 4)  src = Wlv    + (m - 2) * 4096;
    else if (m < 6)  src = Wps    + (m - 4) * 4096;
    else if (m < 8)  src = Wpv    + (m - 6) * 4096;
    else if (m < 18) src = skip_s + (m - 8) * 4096;
    else             src = skip_v + (m - 18) * 4096;
    packW[idx] = cvt2(src[fi * 64 + fo], 0.f).x;
}

// ---------------------------------------------------------------------------
// Dual-chain edge-balanced gather: wave w owns slots [32w,32w+32) as TWO
// independent 16-slot chains (A,B), each software-pipelined (indices 2-ahead,
// values 1-ahead). Doubles in-flight random loads per wave. Rows fully inside
// a chain range: plain store; boundary rows: unsafeAtomicAdd (pre-zeroed).
// ---------------------------------------------------------------------------
template<int VZERO>
__global__ __launch_bounds__(256) void gather_kernel(
    const float* __restrict__ edata, const int* __restrict__ srk,
    const int* __restrict__ row_start, const int* __restrict__ grp_row,
    const float* __restrict__ s_in, const float* __restrict__ v_in,
    const float* __restrict__ Wr_i,
    float* __restrict__ agg_s, float* __restrict__ agg_v)
{
    const int wid = threadIdx.x >> 6;
    const int f = threadIdx.x & 63;
    const int w = blockIdx.x * 4 + wid;
    const int pA0 = w * 32;
    const int pB0 = pA0 + 16;

    float wr[5][8];
#pragma unroll
    for (int j = 0; j < 8; ++j)
#pragma unroll
        for (int p = 0; p < 5; ++p)
            wr[p][j] = (VZERO && (p == 1 || p == 3 || p == 4))
                       ? 0.f : Wr_i[j * 320 + p * 64 + f];

    int rA = grp_row[2 * w], rB = grp_row[2 * w + 1];
    int begA = row_start[rA], endA = row_start[rA + 1];
    int begB = row_start[rB], endB = row_start[rB + 1];
    float aA0 = 0.f, aA1 = 0.f, aA2 = 0.f, aA3 = 0.f;
    float aB0 = 0.f, aB1 = 0.f, aB2 = 0.f, aB3 = 0.f;

    int srA_c = srk[pA0],     srB_c = srk[pB0];
    int srA_n = srk[pA0 + 1], srB_n = srk[pB0 + 1];
    float ssA = s_in[(size_t)srA_c * 64 + f];
    float ssB = s_in[(size_t)srB_c * 64 + f];
    float vA0 = 0.f, vA1 = 0.f, vA2 = 0.f, vB0 = 0.f, vB1 = 0.f, vB2 = 0.f;
    if (!VZERO) {
        vA0 = v_in[((size_t)srA_c * 3 + 0) * 64 + f];
        vA1 = v_in[((size_t)srA_c * 3 + 1) * 64 + f];
        vA2 = v_in[((size_t)srA_c * 3 + 2) * 64 + f];
        vB0 = v_in[((size_t)srB_c * 3 + 0) * 64 + f];
        vB1 = v_in[((size_t)srB_c * 3 + 1) * 64 + f];
        vB2 = v_in[((size_t)srB_c * 3 + 2) * 64 + f];
    }

    for (int k = 0; k < 16; ++k) {
        int pA = pA0 + k, pB = pB0 + k;
        // indices 2-ahead
        int srA_n2 = (k + 2 < 16) ? srk[pA + 2] : srA_n;
        int srB_n2 = (k + 2 < 16) ? srk[pB + 2] : srB_n;
        // values 1-ahead (independent chains)
        float ssA_n = s_in[(size_t)srA_n * 64 + f];
        float ssB_n = s_in[(size_t)srB_n * 64 + f];
        float vA0n = 0.f, vA1n = 0.f, vA2n = 0.f;
        float vB0n = 0.f, vB1n = 0.f, vB2n = 0.f;
        if (!VZERO) {
            vA0n = v_in[((size_t)srA_n * 3 + 0) * 64 + f];
            vA1n = v_in[((size_t)srA_n * 3 + 1) * 64 + f];
            vA2n = v_in[((size_t)srA_n * 3 + 2) * 64 + f];
            vB0n = v_in[((size_t)srB_n * 3 + 0) * 64 + f];
            vB1n = v_in[((size_t)srB_n * 3 + 1) * 64 + f];
            vB2n = v_in[((size_t)srB_n * 3 + 2) * 64 + f];
        }
        // current edge data (sequential, wave-uniform address)
        const float* dA = edata + (size_t)pA * 16;
        const float* dB = edata + (size_t)pB * 16;
        float4 yA = *(const float4*)dA;
        float4 qA0 = *(const float4*)(dA + 4);
        float4 qA1 = *(const float4*)(dA + 8);
        float4 yB = *(const float4*)dB;
        float4 qB0 = *(const float4*)(dB + 4);
        float4 qB1 = *(const float4*)(dB + 8);

        float rbA[8] = {qA0.x, qA0.y, qA0.z, qA0.w, qA1.x, qA1.y, qA1.z, qA1.w};
        float rbB[8] = {qB0.x, qB0.y, qB0.z, qB0.w, qB1.x, qB1.y, qB1.z, qB1.w};
        float wA0 = 0.f, wA1 = 0.f, wA2 = 0.f, wA3 = 0.f, wA4 = 0.f;
        float wB0 = 0.f, wB1 = 0.f, wB2 = 0.f, wB3 = 0.f, wB4 = 0.f;
#pragma unroll
        for (int j = 0; j < 8; ++j) {
            wA0 = fmaf(rbA[j], wr[0][j], wA0);  wB0 = fmaf(rbB[j], wr[0][j], wB0);
            if (!VZERO) { wA1 = fmaf(rbA[j], wr[1][j], wA1);  wB1 = fmaf(rbB[j], wr[1][j], wB1); }
            wA2 = fmaf(rbA[j], wr[2][j], wA2);  wB2 = fmaf(rbB[j], wr[2][j], wB2);
            if (!VZERO) { wA3 = fmaf(rbA[j], wr[3][j], wA3);  wB3 = fmaf(rbB[j], wr[3][j], wB3); }
            if (!VZERO) { wA4 = fmaf(rbA[j], wr[4][j], wA4);  wB4 = fmaf(rbB[j], wr[4][j], wB4); }
        }
        if (VZERO) {
            aA0 += wA0 * ssA;
            float wsA = wA2 * ssA;
            aA1 += wsA * yA.x; aA2 += wsA * yA.y; aA3 += wsA * yA.z;
            aB0 += wB0 * ssB;
            float wsB = wB2 * ssB;
            aB1 += wsB * yB.x; aB2 += wsB * yB.y; aB3 += wsB * yB.z;
        } else {
            float dotA = vA0 * yA.x + vA1 * yA.y + vA2 * yA.z;
            aA0 += wA0 * ssA + wA1 * dotA;
            float cA0 = vA1 * yA.z - vA2 * yA.y;
            float cA1 = vA2 * yA.x - vA0 * yA.z;
            float cA2 = vA0 * yA.y - vA1 * yA.x;
            float wsA = wA2 * ssA;
            aA1 += wsA * yA.x + wA3 * vA0 + wA4 * cA0;
            aA2 += wsA * yA.y + wA3 * vA1 + wA4 * cA1;
            aA3 += wsA * yA.z + wA3 * vA2 + wA4 * cA2;
            float dotB = vB0 * yB.x + vB1 * yB.y + vB2 * yB.z;
            aB0 += wB0 * ssB + wB1 * dotB;
            float cB0 = vB1 * yB.z - vB2 * yB.y;
            float cB1 = vB2 * yB.x - vB0 * yB.z;
            float cB2 = vB0 * yB.y - vB1 * yB.x;
            float wsB = wB2 * ssB;
            aB1 += wsB * yB.x + wB3 * vB0 + wB4 * cB0;
            aB2 += wsB * yB.y + wB3 * vB1 + wB4 * cB1;
            aB3 += wsB * yB.z + wB3 * vB2 + wB4 * cB2;
        }

        // flush chain A (wave-uniform)
        if (pA + 1 == endA || k == 15) {
            bool interior = (begA >= pA0) && (endA <= pA0 + 16);
            if (interior) {
                agg_s[(size_t)rA * 64 + f] = aA0;
                agg_v[((size_t)rA * 3 + 0) * 64 + f] = aA1;
                agg_v[((size_t)rA * 3 + 1) * 64 + f] = aA2;
                agg_v[((size_t)rA * 3 + 2) * 64 + f] = aA3;
            } else {
                unsafeAtomicAdd(&agg_s[(size_t)rA * 64 + f], aA0);
                unsafeAtomicAdd(&agg_v[((size_t)rA * 3 + 0) * 64 + f], aA1);
                unsafeAtomicAdd(&agg_v[((size_t)rA * 3 + 1) * 64 + f], aA2);
                unsafeAtomicAdd(&agg_v[((size_t)rA * 3 + 2) * 64 + f], aA3);
            }
            aA0 = aA1 = aA2 = aA3 = 0.f;
            if (pA + 1 == endA && k < 15) {
                begA = endA; ++rA; endA = row_start[rA + 1];
                while (endA == begA) { ++rA; endA = row_start[rA + 1]; }
            }
        }
        // flush chain B (wave-uniform)
        if (pB + 1 == endB || k == 15) {
            bool interior = (begB >= pB0) && (endB <= pB0 + 16);
            if (interior) {
                agg_s[(size_t)rB * 64 + f] = aB0;
                agg_v[((size_t)rB * 3 + 0) * 64 + f] = aB1;
                agg_v[((size_t)rB * 3 + 1) * 64 + f] = aB2;
                agg_v[((size_t)rB * 3 + 2) * 64 + f] = aB3;
            } else {
                unsafeAtomicAdd(&agg_s[(size_t)rB * 64 + f], aB0);
                unsafeAtomicAdd(&agg_v[((size_t)rB * 3 + 0) * 64 + f], aB1);
                unsafeAtomicAdd(&agg_v[((size_t)rB * 3 + 1) * 64 + f], aB2);
                unsafeAtomicAdd(&agg_v[((size_t)rB * 3 + 2) * 64 + f], aB3);
            }
            aB0 = aB1 = aB2 = aB3 = 0.f;
            if (pB + 1 == endB && k < 15) {
                begB = endB; ++rB; endB = row_start[rB + 1];
                while (endB == begB) { ++rB; endB = row_start[rB + 1]; }
            }
        }
        // rotate pipelines
        ssA = ssA_n; vA0 = vA0n; vA1 = vA1n; vA2 = vA2n;
        ssB = ssB_n; vB0 = vB0n; vB1 = vB1n; vB2 = vB2n;
        srA_c = srA_n; srA_n = srA_n2;
        srB_c = srB_n; srB_n = srB_n2;
    }
}

// ---------------------------------------------------------------------------
// MFMA node kernel (unchanged): wave = 16 sorted nodes.
// ---------------------------------------------------------------------------
__global__ __launch_bounds__(256) void node_mfma_kernel(
    const float* __restrict__ agg_s, const float* __restrict__ agg_v,
    float* s, float* v,
    const short* __restrict__ packW, int it,
    const float* __restrict__ pw_i,
    const int* __restrict__ spec_srt,
    int has_skip)
{
    const int l = threadIdx.x & 63;
    const int wid = threadIdx.x >> 6;
    const int cl = l & 15;
    const int q = l >> 4;
    const int i16 = (blockIdx.x * 4 + wid) * 16;
    __shared__ float xls_all[4][16 * 65];
    float* xls = xls_all[wid];

    const short* pWls = packW + (size_t)(0 + it) * 4096;
    const short* pWlv = packW + (size_t)(2 + it) * 4096;
    const short* pWps = packW + (size_t)(4 + it) * 4096;
    const short* pWpv = packW + (size_t)(6 + it) * 4096;
    const short* pSkS = packW + (size_t)8 * 4096;
    const short* pSkV = packW + (size_t)18 * 4096;
    const short8 z8 = {0, 0, 0, 0, 0, 0, 0, 0};

    const float* ars = agg_s + (size_t)(i16 + cl) * 64;
    short8 As[2] = { loadArow(ars, 0, q), loadArow(ars, 1, q) };
    short8 Av[3][2];
#pragma unroll
    for (int k = 0; k < 3; ++k) {
        const float* r = agg_v + ((size_t)(i16 + cl) * 3 + k) * 64;
        Av[k][0] = loadArow(r, 0, q);
        Av[k][1] = loadArow(r, 1, q);
    }

    f32x4 sD[4];
#pragma unroll
    for (int t = 0; t < 4; ++t) {
        f32x4 acc = {0.f, 0.f, 0.f, 0.f};
        acc = MFMA16(As[0], loadB(pWls, t, 0, l), acc);
        acc = MFMA16(As[1], loadB(pWls, t, 1, l), acc);
        sD[t] = acc;
    }

    f32x4 vD[3][4];
#pragma unroll
    for (int k = 0; k < 3; ++k)
#pragma unroll
        for (int t = 0; t < 4; ++t) vD[k][t] = (f32x4){0.f, 0.f, 0.f, 0.f};
#pragma unroll
    for (int t = 0; t < 4; ++t)
#pragma unroll
        for (int h = 0; h < 2; ++h) {
            short8 b = loadB(pWlv, t, h, l);
#pragma unroll
            for (int k = 0; k < 3; ++k) vD[k][t] = MFMA16(Av[k][h], b, vD[k][t]);
        }

    int z0 = spec_srt[i16], z1 = spec_srt[i16 + 15];
    float psD[4][4], pvsD[4][4];
    if (z0 == z1) {
        const float* pb = pw_i + z0 * 576 + cl;
        float pc[9][4];
#pragma unroll
        for (int c = 0; c < 9; ++c)
#pragma unroll
            for (int t = 0; t < 4; ++t) pc[c][t] = pb[c * 64 + t * 16];
#pragma unroll
        for (int t = 0; t < 4; ++t)
#pragma unroll
            for (int r = 0; r < 4; ++r) {
                float x = sD[t][r] * EPS_C;
                float w0 = vD[0][t][r] * EPS_C;
                float w1 = vD[1][t][r] * EPS_C;
                float w2 = vD[2][t][r] * EPS_C;
                vD[0][t][r] = w0; vD[1][t][r] = w1; vD[2][t][r] = w2;
                float vv = w0 * w0 + w1 * w1 + w2 * w2;
                float x2 = x * x;
                psD[t][r] = pc[0][t] * x + pc[1][t] * x2 + pc[2][t] * vv
                          + pc[3][t] * x2 * x + pc[4][t] * x * vv;
                pvsD[t][r] = pc[5][t] + pc[6][t] * x + pc[7][t] * x2 + pc[8][t] * vv;
            }
    } else {
#pragma unroll
        for (int r = 0; r < 4; ++r) {
            int z = spec_srt[i16 + q * 4 + r];
            const float* pb = pw_i + z * 576 + cl;
#pragma unroll
            for (int t = 0; t < 4; ++t) {
                float p0 = pb[t*16], p1 = pb[64+t*16], p2 = pb[128+t*16];
                float p3 = pb[192+t*16], p4 = pb[256+t*16], p5 = pb[320+t*16];
                float p6 = pb[384+t*16], p7 = pb[448+t*16], p8 = pb[512+t*16];
                float x = sD[t][r] * EPS_C;
                float w0 = vD[0][t][r] * EPS_C;
                float w1 = vD[1][t][r] * EPS_C;
                float w2 = vD[2][t][r] * EPS_C;
                vD[0][t][r] = w0; vD[1][t][r] = w1; vD[2][t][r] = w2;
                float vv = w0 * w0 + w1 * w1 + w2 * w2;
                float x2 = x * x;
                psD[t][r] = p0 * x + p1 * x2 + p2 * vv + p3 * x2 * x + p4 * x * vv;
                pvsD[t][r] = p5 + p6 * x + p7 * x2 + p8 * vv;
            }
        }
    }

#pragma unroll
    for (int t = 0; t < 4; ++t)
#pragma unroll
        for (int r = 0; r < 4; ++r)
            xls[(q * 4 + r) * 65 + t * 16 + cl] = psD[t][r];
    short8 psA[2];
#pragma unroll
    for (int h = 0; h < 2; ++h) {
        const float* rp = xls + cl * 65 + h * 32 + q * 8;
        float t0 = rp[0], t1 = rp[1], t2 = rp[2], t3 = rp[3];
        float t4 = rp[4], t5 = rp[5], t6 = rp[6], t7 = rp[7];
        psA[h] = cvt8(make_float4(t0, t1, t2, t3), make_float4(t4, t5, t6, t7));
    }

    f32x4 snD[4];
#pragma unroll
    for (int t = 0; t < 4; ++t) {
        f32x4 acc = {0.f, 0.f, 0.f, 0.f};
        acc = MFMA16(psA[0], loadB(pWps, t, 0, l), acc);
        acc = MFMA16(psA[1], loadB(pWps, t, 1, l), acc);
        snD[t] = acc;
    }
    if (has_skip) {
        const float* srow = s + (size_t)(i16 + cl) * 64;
        short8 Ai0 = loadArow(srow, 0, q), Ai1 = loadArow(srow, 1, q);
        int myz = spec_srt[i16 + cl];
        for (int z = z0; z <= z1; ++z) {
            bool keep = (myz == z);
            short8 m0 = keep ? Ai0 : z8;
            short8 m1 = keep ? Ai1 : z8;
            const short* pz = pSkS + (size_t)z * 4096;
#pragma unroll
            for (int t = 0; t < 4; ++t) {
                snD[t] = MFMA16(m0, loadB(pz, t, 0, l), snD[t]);
                snD[t] = MFMA16(m1, loadB(pz, t, 1, l), snD[t]);
            }
        }
    }
#pragma unroll
    for (int t = 0; t < 4; ++t)
#pragma unroll
        for (int r = 0; r < 4; ++r)
            s[(size_t)(i16 + q * 4 + r) * 64 + t * 16 + cl] = snD[t][r];

    short8 pvA[3][2];
#pragma unroll
    for (int k = 0; k < 3; ++k) {
#pragma unroll
        for (int t = 0; t < 4; ++t)
#pragma unroll
            for (int r = 0; r < 4; ++r)
                xls[(q * 4 + r) * 65 + t * 16 + cl] = pvsD[t][r] * vD[k][t][r];
#pragma unroll
        for (int h = 0; h < 2; ++h) {
            const float* rp = xls + cl * 65 + h * 32 + q * 8;
            float t0 = rp[0], t1 = rp[1], t2 = rp[2], t3 = rp[3];
            float t4 = rp[4], t5 = rp[5], t6 = rp[6], t7 = rp[7];
            pvA[k][h] = cvt8(make_float4(t0, t1, t2, t3), make_float4(t4, t5, t6, t7));
        }
    }

    f32x4 vnD[3][4];
#pragma unroll
    for (int k = 0; k < 3; ++k)
#pragma unroll
        for (int t = 0; t < 4; ++t) vnD[k][t] = (f32x4){0.f, 0.f, 0.f, 0.f};
#pragma unroll
    for (int t = 0; t < 4; ++t)
#pragma unroll
        for (int h = 0; h < 2; ++h) {
            short8 b = loadB(pWpv, t, h, l);
#pragma unroll
            for (int k = 0; k < 3; ++k) vnD[k][t] = MFMA16(pvA[k][h], b, vnD[k][t]);
        }
    if (has_skip) {
        short8 Aiv[3][2];
#pragma unroll
        for (int k = 0; k < 3; ++k) {
            const float* r = v + ((size_t)(i16 + cl) * 3 + k) * 64;
            Aiv[k][0] = loadArow(r, 0, q);
            Aiv[k][1] = loadArow(r, 1, q);
        }
        int myz = spec_srt[i16 + cl];
        for (int z = z0; z <= z1; ++z) {
            bool keep = (myz == z);
            const short* pz = pSkV + (size_t)z * 4096;
#pragma unroll
            for (int t = 0; t < 4; ++t)
#pragma unroll
                for (int h = 0; h < 2; ++h) {
                    short8 b = loadB(pz, t, h, l);
#pragma unroll
                    for (int k = 0; k < 3; ++k) {
                        short8 a = keep ? Aiv[k][h] : z8;
                        vnD[k][t] = MFMA16(a, b, vnD[k][t]);
                    }
                }
        }
    }
#pragma unroll
    for (int k = 0; k < 3; ++k)
#pragma unroll
        for (int t = 0; t < 4; ++t)
#pragma unroll
            for (int r = 0; r < 4; ++r)
                v[((size_t)(i16 + q * 4 + r) * 3 + k) * 64 + t * 16 + cl] = vnD[k][t][r];
}

// ---------------------------------------------------------------------------
// Readouts (sorted s -> out[sidx])
// ---------------------------------------------------------------------------
__global__ __launch_bounds__(256) void read0_kernel(
    const float* __restrict__ s, const float* __restrict__ Wread0,
    const int* __restrict__ sidx, float* __restrict__ out)
{
    const int wid = threadIdx.x >> 6;
    const int f = threadIdx.x & 63;
    const int i4 = (blockIdx.x * 4 + wid) * 4;
    float w0 = Wread0[f];
#pragma unroll
    for (int t = 0; t < 4; ++t) {
        float a = s[(size_t)(i4 + t) * 64 + f] * w0;
        for (int off = 32; off; off >>= 1) a += __shfl_down(a, off);
        if (f == 0) out[(size_t)sidx[i4 + t] * 2 + 0] = a;
    }
}

__global__ __launch_bounds__(256) void read1_kernel(
    const float* __restrict__ s, const float* __restrict__ Wr1a,
    const float* __restrict__ Wr1b, const int* __restrict__ sidx,
    float* __restrict__ out)
{
    const int wid = threadIdx.x >> 6;
    const int f = threadIdx.x & 63;
    const int i4 = (blockIdx.x * 4 + wid) * 4;
    int hh = f & 15;
    int t0 = f >> 4;
    float a = 0.f;
    const float* sp = s + (size_t)(i4 + t0) * 64;
#pragma unroll 8
    for (int g = 0; g < 64; ++g)
        a = fmaf(sp[g], Wr1a[g * 16 + hh], a);
    float r0 = (a / (1.f + expf(-a))) * Wr1b[hh];
    for (int off = 8; off; off >>= 1) r0 += __shfl_down(r0, off);
    if (hh == 0) out[(size_t)sidx[i4 + t0] * 2 + 1] = r0;
}

// ---------------------------------------------------------------------------
extern "C" void kernel_launch(void* const* d_in, const int* in_sizes, int n_in,
                              void* d_out, int out_size, void* d_ws, size_t ws_size,
                              hipStream_t stream)
{
    const float* vectors = (const float*)d_in[0];
    const float* embed_s = (const float*)d_in[1];
    const float* Wr      = (const float*)d_in[2];   // [2,8,320]
    const float* Wls     = (const float*)d_in[3];   // [2,64,64]
    const float* Wlv     = (const float*)d_in[4];
    const float* skip_s  = (const float*)d_in[5];   // [10,64,64]
    const float* skip_v  = (const float*)d_in[6];
    const float* pw      = (const float*)d_in[7];   // [2,10,9,64]
    const float* Wps     = (const float*)d_in[8];
    const float* Wpv     = (const float*)d_in[9];
    const float* Wread0  = (const float*)d_in[10];  // [64,1]
    const float* Wr1a    = (const float*)d_in[11];  // [64,16]
    const float* Wr1b    = (const float*)d_in[12];  // [16,1]
    const int* senders   = (const int*)d_in[13];
    const int* receivers = (const int*)d_in[14];
    const int* species   = (const int*)d_in[15];
    float* out = (float*)d_out;

    float* ws = (float*)d_ws;
    float* edata = ws; ws += (size_t)N_EDGES * 16;  // 16 MB (slot-ordered)
    float* s     = ws; ws += (size_t)N_NODES * 64;  // 8 MB
    float* v     = ws; ws += (size_t)N_NODES * 192; // 24 MB
    float* agg_s = ws; ws += (size_t)N_NODES * 64;  // 8 MB
    float* agg_v = ws; ws += (size_t)N_NODES * 192; // 24 MB
    int* counts    = (int*)ws; ws += N_NODES;
    int* row_start = (int*)ws; ws += N_NODES + 4;
    int* cursor    = (int*)ws; ws += N_NODES;
    int* edge_ids  = (int*)ws; ws += N_EDGES;
    int* srk       = (int*)ws; ws += N_EDGES;
    int* grp_row   = (int*)ws; ws += N_EDGES / 16;
    int* sidx      = (int*)ws; ws += N_NODES;
    int* rank      = (int*)ws; ws += N_NODES;
    int* spec_srt  = (int*)ws; ws += N_NODES;
    int* lrank_arr = (int*)ws; ws += N_NODES;
    int* counts_blk = (int*)ws; ws += 128 * NSPEC;
    int* off_blk    = (int*)ws; ws += 128 * NSPEC;
    short* packW   = (short*)ws;                    // 224 KB

    // species counting sort (no atomics, deterministic)
    sort1_kernel<<<N_NODES / 256, 256, 0, stream>>>(species, counts_blk, lrank_arr);
    sort2_kernel<<<1, 64, 0, stream>>>(counts_blk, off_blk);
    sort3_kernel<<<N_NODES / 256, 256, 0, stream>>>(
        species, lrank_arr, off_blk, sidx, rank, spec_srt);

    // receiver CSR in sorted space, deterministic row order
    hipMemsetAsync(counts, 0, N_NODES * sizeof(int), stream);
    hist_kernel<<<N_EDGES / 256, 256, 0, stream>>>(receivers, rank, counts);
    scan_kernel<<<1, 1024, 0, stream>>>(counts, row_start, cursor);
    scatter_kernel<<<N_EDGES / 256, 256, 0, stream>>>(receivers, rank, cursor, edge_ids);
    rowsort_kernel<<<N_NODES / 256, 256, 0, stream>>>(row_start, edge_ids);
    sr_kernel<<<N_EDGES / 256, 256, 0, stream>>>(senders, edge_ids, rank, srk);
    grprow_kernel<<<N_EDGES / 16 / 256, 256, 0, stream>>>(row_start, grp_row);

    // edge features in slot order (sequential writes)
    edge_pre_kernel<<<N_EDGES / 256, 256, 0, stream>>>(vectors, edge_ids, edata);

    init_s_kernel<<<N_NODES * 64 / 256, 256, 0, stream>>>(embed_s, spec_srt, s);
    pack_kernel<<<448, 256, 0, stream>>>(Wls, Wlv, Wps, Wpv, skip_s, skip_v, packW);

    // interaction 0
    zero_bnd_kernel<<<N_NODES / 16, 256, 0, stream>>>(row_start, agg_s, agg_v);
    gather_kernel<1><<<N_EDGES / 32 / 4, 256, 0, stream>>>(
        edata, srk, row_start, grp_row, s, v, Wr, agg_s, agg_v);
    node_mfma_kernel<<<N_NODES / 64, 256, 0, stream>>>(
        agg_s, agg_v, s, v, packW, 0, pw, spec_srt, 0);
    read0_kernel<<<N_NODES / 16, 256, 0, stream>>>(s, Wread0, sidx, out);

    // interaction 1
    zero_bnd_kernel<<<N_NODES / 16, 256, 0, stream>>>(row_start, agg_s, agg_v);
    gather_kernel<0><<<N_EDGES / 32 / 4, 256, 0, stream>>>(
        edata, srk, row_start, grp_row, s, v, Wr + 2560, agg_s, agg_v);
    node_mfma_kernel<<<N_NODES / 64, 256, 0, stream>>>(
        agg_s, agg_v, s, v, packW, 1, pw + 5760, spec_srt, 1);
    read1_kernel<<<N_NODES / 16, 256, 0, stream>>>(s, Wr1a, Wr1b, sidx, out);
}

// Round 13
// 340.433 us; speedup vs baseline: 1.0957x; 1.0244x over previous
//
#include <hip/hip_runtime.h>
#include <hip/hip_bf16.h>
#include <math.h>

#define N_NODES 32768
#define N_EDGES 262144
#define EPS_C 0.24253562503633297f   // 1/sqrt(17)
#define NSPEC 10

typedef __attribute__((ext_vector_type(8))) short short8;   // 8 bf16
typedef __attribute__((ext_vector_type(4))) float f32x4;    // 4 fp32 acc

#define MFMA16(a, b, c) __builtin_amdgcn_mfma_f32_16x16x32_bf16(a, b, c, 0, 0, 0)

__device__ __forceinline__ short2 cvt2(float a, float b) {
    union { __hip_bfloat162 h; short2 s; } u;
    u.h = __float22bfloat162_rn(make_float2(a, b));
    return u.s;
}
__device__ __forceinline__ short8 cvt8(float4 a, float4 b) {
    short2 p0 = cvt2(a.x, a.y), p1 = cvt2(a.z, a.w);
    short2 p2 = cvt2(b.x, b.y), p3 = cvt2(b.z, b.w);
    short8 r;
    r[0] = p0.x; r[1] = p0.y; r[2] = p1.x; r[3] = p1.y;
    r[4] = p2.x; r[5] = p2.y; r[6] = p3.x; r[7] = p3.y;
    return r;
}
__device__ __forceinline__ short8 loadArow(const float* rowp, int h, int q) {
    const float* p = rowp + h * 32 + q * 8;
    return cvt8(*(const float4*)p, *(const float4*)(p + 4));
}
__device__ __forceinline__ short8 loadB(const short* P, int t, int h, int l) {
    return *(const short8*)(P + (((t * 2 + h) * 64 + l) << 3));
}

// ---------------------------------------------------------------------------
// Species counting sort — contention-free, deterministic (ballot/popcount).
// ---------------------------------------------------------------------------
__global__ __launch_bounds__(256) void sort1_kernel(
    const int* __restrict__ species, int* __restrict__ counts_blk,
    int* __restrict__ lrank_arr)
{
    __shared__ int wcnt[4][16];
    int n = blockIdx.x * 256 + threadIdx.x;
    int sp = species[n];
    int lane = threadIdx.x & 63, wv = threadIdx.x >> 6;
    unsigned long long ltmask = (1ull << lane) - 1;
    int lrank_w = 0;
#pragma unroll
    for (int z = 0; z < NSPEC; ++z) {
        unsigned long long m = __ballot(sp == z);
        if (sp == z) lrank_w = __popcll(m & ltmask);
        if (lane == 0) wcnt[wv][z] = __popcll(m);
    }
    __syncthreads();
    int off = 0;
    for (int w = 0; w < wv; ++w) off += wcnt[w][sp];
    lrank_arr[n] = lrank_w + off;
    if (threadIdx.x < NSPEC)
        counts_blk[blockIdx.x * NSPEC + threadIdx.x] =
            wcnt[0][threadIdx.x] + wcnt[1][threadIdx.x] +
            wcnt[2][threadIdx.x] + wcnt[3][threadIdx.x];
}

// parallel block-offset scan: wave z shuffle-scans its 128 block counts
__global__ __launch_bounds__(640) void sort2_kernel(
    const int* __restrict__ counts_blk, int* __restrict__ off_blk)
{
    __shared__ int totals[16];
    int wv = threadIdx.x >> 6;        // 0..9 == species z
    int lane = threadIdx.x & 63;
    int c0 = counts_blk[lane * NSPEC + wv];
    int c1 = counts_blk[(64 + lane) * NSPEC + wv];
    int s0 = c0;
#pragma unroll
    for (int off = 1; off < 64; off <<= 1) {
        int y = __shfl_up(s0, off);
        if (lane >= off) s0 += y;
    }
    int tot0 = __shfl(s0, 63);
    int s1 = c1;
#pragma unroll
    for (int off = 1; off < 64; off <<= 1) {
        int y = __shfl_up(s1, off);
        if (lane >= off) s1 += y;
    }
    s1 += tot0;
    if (lane == 63) totals[wv] = s1;
    __syncthreads();
    int base = 0;
    for (int q = 0; q < wv; ++q) base += totals[q];
    off_blk[lane * NSPEC + wv] = base + s0 - c0;
    off_blk[(64 + lane) * NSPEC + wv] = base + s1 - c1;
}

__global__ __launch_bounds__(256) void sort3_kernel(
    const int* __restrict__ species, const int* __restrict__ lrank_arr,
    const int* __restrict__ off_blk,
    int* __restrict__ sidx, int* __restrict__ rank, int* __restrict__ spec_srt)
{
    int n = blockIdx.x * 256 + threadIdx.x;
    int sp = species[n];
    int slot = off_blk[blockIdx.x * NSPEC + sp] + lrank_arr[n];
    sidx[slot] = n;
    rank[n] = slot;
    spec_srt[slot] = sp;
}

// ---------------------------------------------------------------------------
// Receiver CSR in SORTED space
// ---------------------------------------------------------------------------
__global__ __launch_bounds__(256) void hist_kernel(
    const int* __restrict__ receivers, const int* __restrict__ rank,
    int* __restrict__ counts)
{
    int e = blockIdx.x * 256 + threadIdx.x;
    atomicAdd(&counts[rank[receivers[e]]], 1);
}

__global__ __launch_bounds__(1024) void scan_kernel(
    const int* __restrict__ counts, int* __restrict__ row_start, int* __restrict__ cursor)
{
    __shared__ int wave_tot[16];
    int tid = threadIdx.x;
    int c[32];
    int sum = 0;
#pragma unroll
    for (int i = 0; i < 32; ++i) { c[i] = counts[tid * 32 + i]; sum += c[i]; }
    int lane = tid & 63, wv = tid >> 6;
    int x = sum;
#pragma unroll
    for (int off = 1; off < 64; off <<= 1) {
        int y = __shfl_up(x, off);
        if (lane >= off) x += y;
    }
    if (lane == 63) wave_tot[wv] = x;
    __syncthreads();
    if (wv == 0 && lane < 16) {
        int t = wave_tot[lane];
#pragma unroll
        for (int off = 1; off < 16; off <<= 1) {
            int y = __shfl_up(t, off);
            if (lane >= off) t += y;
        }
        wave_tot[lane] = t;
    }
    __syncthreads();
    int excl = x - sum + (wv ? wave_tot[wv - 1] : 0);
    int run = excl;
#pragma unroll
    for (int i = 0; i < 32; ++i) {
        row_start[tid * 32 + i] = run;
        cursor[tid * 32 + i] = run;
        run += c[i];
    }
    if (tid == 1023) row_start[32768] = run;
}

__global__ __launch_bounds__(256) void scatter_kernel(
    const int* __restrict__ receivers, const int* __restrict__ rank,
    int* __restrict__ cursor, int* __restrict__ edge_ids)
{
    int e = blockIdx.x * 256 + threadIdx.x;
    int slot = atomicAdd(&cursor[rank[receivers[e]]], 1);
    edge_ids[slot] = e;
}

// per-row insertion sort in LDS (deterministic edge order per row)
__global__ __launch_bounds__(256) void rowsort_kernel(
    const int* __restrict__ row_start, int* __restrict__ edge_ids)
{
    __shared__ int buf[256 * 33];
    int i = blockIdx.x * 256 + threadIdx.x;
    int beg = row_start[i], end = row_start[i + 1];
    int len = end - beg;
    int* b = buf + threadIdx.x * 33;
    if (len <= 32) {
        for (int j = 0; j < len; ++j) b[j] = edge_ids[beg + j];
        for (int a = 1; a < len; ++a) {
            int key = b[a];
            int c = a - 1;
            while (c >= 0 && b[c] > key) { b[c + 1] = b[c]; --c; }
            b[c + 1] = key;
        }
        for (int j = 0; j < len; ++j) edge_ids[beg + j] = b[j];
    } else {
        for (int a = beg + 1; a < end; ++a) {
            int key = edge_ids[a];
            int c = a - 1;
            while (c >= beg && edge_ids[c] > key) { edge_ids[c + 1] = edge_ids[c]; --c; }
            edge_ids[c + 1] = key;
        }
    }
}

// grp_row[g]: row containing slot 16g (largest r with row_start[r] <= 16g)
__global__ __launch_bounds__(256) void grprow_kernel(
    const int* __restrict__ row_start, int* __restrict__ grp_row)
{
    int g = blockIdx.x * 256 + threadIdx.x;   // 16384
    int target = g * 16;
    int lo = 0, hi = N_NODES - 1;
    while (lo < hi) {
        int mid = (lo + hi + 1) >> 1;
        if (row_start[mid] <= target) lo = mid; else hi = mid - 1;
    }
    grp_row[g] = lo;
}

// zero agg rows that are empty or cross a 16-slot chain boundary
__global__ __launch_bounds__(256) void zero_bnd_kernel(
    const int* __restrict__ row_start,
    float* __restrict__ agg_s, float* __restrict__ agg_v)
{
    const int wid = threadIdx.x >> 6;
    const int f = threadIdx.x & 63;
    const int base = (blockIdx.x * 4 + wid) * 4;
#pragma unroll
    for (int t = 0; t < 4; ++t) {
        int i = base + t;
        int beg = row_start[i], end = row_start[i + 1];
        bool need = (end == beg) || (end > (((beg >> 4) + 1) << 4));
        if (need) {
            agg_s[(size_t)i * 64 + f] = 0.f;
            agg_v[((size_t)i * 3 + 0) * 64 + f] = 0.f;
            agg_v[((size_t)i * 3 + 1) * 64 + f] = 0.f;
            agg_v[((size_t)i * 3 + 2) * 64 + f] = 0.f;
        }
    }
}

// ---------------------------------------------------------------------------
// Edge precompute in slot order + fused sender-rank stream:
// edata[p*16] = {y0,y1,y2,0, rbf[8], pad};  srk[p] = rank[senders[edge_ids[p]]]
// ---------------------------------------------------------------------------
__global__ __launch_bounds__(256) void edge_pre_kernel(
    const float* __restrict__ vectors, const int* __restrict__ edge_ids,
    const int* __restrict__ senders, const int* __restrict__ rank,
    float* __restrict__ edata, int* __restrict__ srk)
{
    int p = blockIdx.x * 256 + threadIdx.x;
    int e = edge_ids[p];
    srk[p] = rank[senders[e]];
    float x = vectors[e * 3 + 0], y = vectors[e * 3 + 1], z = vectors[e * 3 + 2];
    float r2 = x * x + y * y + z * z + 1e-12f;
    float r = sqrtf(r2);
    float inv = 1.0f / r;
    float* d = edata + (size_t)p * 16;
    *(float4*)d = make_float4(x * inv, y * inv, z * inv, 0.0f);
    float rc = fmaxf(r, 1e-6f);
    float r6 = r2 * r2 * r2;
    float r7 = r6 * r;
    float r8 = r6 * r2;
    float env = (r < 1.0f) ? (1.0f - 28.0f * r6 + 48.0f * r7 - 21.0f * r8) : 0.0f;
    float sc = 1.41421356237309515f * env / rc;
#pragma unroll
    for (int j = 0; j < 8; ++j)
        d[4 + j] = sc * sinf((float)(j + 1) * 3.14159265358979323846f * rc);
    d[12] = 0.f; d[13] = 0.f; d[14] = 0.f; d[15] = 0.f;
}

// ---------------------------------------------------------------------------
// Node init (sorted layout)
// ---------------------------------------------------------------------------
__global__ __launch_bounds__(256) void init_s_kernel(
    const float* __restrict__ embed_s, const int* __restrict__ spec_srt,
    float* __restrict__ s)
{
    int idx = blockIdx.x * 256 + threadIdx.x;
    s[idx] = embed_s[spec_srt[idx >> 6] * 64 + (idx & 63)];
}

// ---------------------------------------------------------------------------
// Weight pre-pack: 28 64x64 fp32 matrices -> bf16 B-fragment order.
// ---------------------------------------------------------------------------
__global__ __launch_bounds__(256) void pack_kernel(
    const float* __restrict__ Wls, const float* __restrict__ Wlv,
    const float* __restrict__ Wps, const float* __restrict__ Wpv,
    const float* __restrict__ skip_s, const float* __restrict__ skip_v,
    short* __restrict__ packW)
{
    int idx = blockIdx.x * 256 + threadIdx.x;   // 28*4096 = 114688
    if (idx >= 28 * 4096) return;
    int m = idx >> 12, e = idx & 4095;
    int t = e >> 10, h = (e >> 9) & 1, l = (e >> 3) & 63, j = e & 7;
    int fi = h * 32 + ((l >> 4) << 3) + j;
    int fo = t * 16 + (l & 15);
    const float* src;
    if      (m < 2)  src = Wls    + m * 4096;
    else if (m < 4)  src = Wlv    + (m - 2) * 4096;
    else if (m < 6)  src = Wps    + (m - 4) * 4096;
    else if (m < 8)  src = Wpv    + (m - 6) * 4096;
    else if (m < 18) src = skip_s + (m - 8) * 4096;
    else             src = skip_v + (m - 18) * 4096;
    packW[idx] = cvt2(src[fi * 64 + fo], 0.f).x;
}

// ---------------------------------------------------------------------------
// Dual-chain edge-balanced gather, FULLY UNROLLED (k=16): straight-line code
// lets the scheduler hoist edata/srk loads across iterations (no aliasing
// with agg stores). Manual 1-ahead s/v value pipeline kept.
// ---------------------------------------------------------------------------
template<int VZERO>
__global__ __launch_bounds__(256) void gather_kernel(
    const float* __restrict__ edata, const int* __restrict__ srk,
    const int* __restrict__ row_start, const int* __restrict__ grp_row,
    const float* __restrict__ s_in, const float* __restrict__ v_in,
    const float* __restrict__ Wr_i,
    float* __restrict__ agg_s, float* __restrict__ agg_v)
{
    const int wid = threadIdx.x >> 6;
    const int f = threadIdx.x & 63;
    const int w = blockIdx.x * 4 + wid;
    const int pA0 = w * 32;
    const int pB0 = pA0 + 16;

    float wr[5][8];
#pragma unroll
    for (int j = 0; j < 8; ++j)
#pragma unroll
        for (int p = 0; p < 5; ++p)
            wr[p][j] = (VZERO && (p == 1 || p == 3 || p == 4))
                       ? 0.f : Wr_i[j * 320 + p * 64 + f];

    int rA = grp_row[2 * w], rB = grp_row[2 * w + 1];
    int begA = row_start[rA], endA = row_start[rA + 1];
    int begB = row_start[rB], endB = row_start[rB + 1];
    float aA0 = 0.f, aA1 = 0.f, aA2 = 0.f, aA3 = 0.f;
    float aB0 = 0.f, aB1 = 0.f, aB2 = 0.f, aB3 = 0.f;

    int srA_c = srk[pA0],     srB_c = srk[pB0];
    int srA_n = srk[pA0 + 1], srB_n = srk[pB0 + 1];
    float ssA = s_in[(size_t)srA_c * 64 + f];
    float ssB = s_in[(size_t)srB_c * 64 + f];
    float vA0 = 0.f, vA1 = 0.f, vA2 = 0.f, vB0 = 0.f, vB1 = 0.f, vB2 = 0.f;
    if (!VZERO) {
        vA0 = v_in[((size_t)srA_c * 3 + 0) * 64 + f];
        vA1 = v_in[((size_t)srA_c * 3 + 1) * 64 + f];
        vA2 = v_in[((size_t)srA_c * 3 + 2) * 64 + f];
        vB0 = v_in[((size_t)srB_c * 3 + 0) * 64 + f];
        vB1 = v_in[((size_t)srB_c * 3 + 1) * 64 + f];
        vB2 = v_in[((size_t)srB_c * 3 + 2) * 64 + f];
    }

#pragma unroll
    for (int k = 0; k < 16; ++k) {
        int pA = pA0 + k, pB = pB0 + k;
        // indices 2-ahead
        int srA_n2 = (k + 2 < 16) ? srk[pA + 2] : srA_n;
        int srB_n2 = (k + 2 < 16) ? srk[pB + 2] : srB_n;
        // values 1-ahead (independent chains)
        float ssA_n = s_in[(size_t)srA_n * 64 + f];
        float ssB_n = s_in[(size_t)srB_n * 64 + f];
        float vA0n = 0.f, vA1n = 0.f, vA2n = 0.f;
        float vB0n = 0.f, vB1n = 0.f, vB2n = 0.f;
        if (!VZERO) {
            vA0n = v_in[((size_t)srA_n * 3 + 0) * 64 + f];
            vA1n = v_in[((size_t)srA_n * 3 + 1) * 64 + f];
            vA2n = v_in[((size_t)srA_n * 3 + 2) * 64 + f];
            vB0n = v_in[((size_t)srB_n * 3 + 0) * 64 + f];
            vB1n = v_in[((size_t)srB_n * 3 + 1) * 64 + f];
            vB2n = v_in[((size_t)srB_n * 3 + 2) * 64 + f];
        }
        // current edge data (sequential; hoisted across iterations by unroll)
        const float* dA = edata + (size_t)pA * 16;
        const float* dB = edata + (size_t)pB * 16;
        float4 yA = *(const float4*)dA;
        float4 qA0 = *(const float4*)(dA + 4);
        float4 qA1 = *(const float4*)(dA + 8);
        float4 yB = *(const float4*)dB;
        float4 qB0 = *(const float4*)(dB + 4);
        float4 qB1 = *(const float4*)(dB + 8);

        float rbA[8] = {qA0.x, qA0.y, qA0.z, qA0.w, qA1.x, qA1.y, qA1.z, qA1.w};
        float rbB[8] = {qB0.x, qB0.y, qB0.z, qB0.w, qB1.x, qB1.y, qB1.z, qB1.w};
        float wA0 = 0.f, wA1 = 0.f, wA2 = 0.f, wA3 = 0.f, wA4 = 0.f;
        float wB0 = 0.f, wB1 = 0.f, wB2 = 0.f, wB3 = 0.f, wB4 = 0.f;
#pragma unroll
        for (int j = 0; j < 8; ++j) {
            wA0 = fmaf(rbA[j], wr[0][j], wA0);  wB0 = fmaf(rbB[j], wr[0][j], wB0);
            if (!VZERO) { wA1 = fmaf(rbA[j], wr[1][j], wA1);  wB1 = fmaf(rbB[j], wr[1][j], wB1); }
            wA2 = fmaf(rbA[j], wr[2][j], wA2);  wB2 = fmaf(rbB[j], wr[2][j], wB2);
            if (!VZERO) { wA3 = fmaf(rbA[j], wr[3][j], wA3);  wB3 = fmaf(rbB[j], wr[3][j], wB3); }
            if (!VZERO) { wA4 = fmaf(rbA[j], wr[4][j], wA4);  wB4 = fmaf(rbB[j], wr[4][j], wB4); }
        }
        if (VZERO) {
            aA0 += wA0 * ssA;
            float wsA = wA2 * ssA;
            aA1 += wsA * yA.x; aA2 += wsA * yA.y; aA3 += wsA * yA.z;
            aB0 += wB0 * ssB;
            float wsB = wB2 * ssB;
            aB1 += wsB * yB.x; aB2 += wsB * yB.y; aB3 += wsB * yB.z;
        } else {
            float dotA = vA0 * yA.x + vA1 * yA.y + vA2 * yA.z;
            aA0 += wA0 * ssA + wA1 * dotA;
            float cA0 = vA1 * yA.z - vA2 * yA.y;
            float cA1 = vA2 * yA.x - vA0 * yA.z;
            float cA2 = vA0 * yA.y - vA1 * yA.x;
            float wsA = wA2 * ssA;
            aA1 += wsA * yA.x + wA3 * vA0 + wA4 * cA0;
            aA2 += wsA * yA.y + wA3 * vA1 + wA4 * cA1;
            aA3 += wsA * yA.z + wA3 * vA2 + wA4 * cA2;
            float dotB = vB0 * yB.x + vB1 * yB.y + vB2 * yB.z;
            aB0 += wB0 * ssB + wB1 * dotB;
            float cB0 = vB1 * yB.z - vB2 * yB.y;
            float cB1 = vB2 * yB.x - vB0 * yB.z;
            float cB2 = vB0 * yB.y - vB1 * yB.x;
            float wsB = wB2 * ssB;
            aB1 += wsB * yB.x + wB3 * vB0 + wB4 * cB0;
            aB2 += wsB * yB.y + wB3 * vB1 + wB4 * cB1;
            aB3 += wsB * yB.z + wB3 * vB2 + wB4 * cB2;
        }

        // flush chain A (wave-uniform)
        if (pA + 1 == endA || k == 15) {
            bool interior = (begA >= pA0) && (endA <= pA0 + 16);
            if (interior) {
                agg_s[(size_t)rA * 64 + f] = aA0;
                agg_v[((size_t)rA * 3 + 0) * 64 + f] = aA1;
                agg_v[((size_t)rA * 3 + 1) * 64 + f] = aA2;
                agg_v[((size_t)rA * 3 + 2) * 64 + f] = aA3;
            } else {
                unsafeAtomicAdd(&agg_s[(size_t)rA * 64 + f], aA0);
                unsafeAtomicAdd(&agg_v[((size_t)rA * 3 + 0) * 64 + f], aA1);
                unsafeAtomicAdd(&agg_v[((size_t)rA * 3 + 1) * 64 + f], aA2);
                unsafeAtomicAdd(&agg_v[((size_t)rA * 3 + 2) * 64 + f], aA3);
            }
            aA0 = aA1 = aA2 = aA3 = 0.f;
            if (pA + 1 == endA && k < 15) {
                begA = endA; ++rA; endA = row_start[rA + 1];
                while (endA == begA) { ++rA; endA = row_start[rA + 1]; }
            }
        }
        // flush chain B (wave-uniform)
        if (pB + 1 == endB || k == 15) {
            bool interior = (begB >= pB0) && (endB <= pB0 + 16);
            if (interior) {
                agg_s[(size_t)rB * 64 + f] = aB0;
                agg_v[((size_t)rB * 3 + 0) * 64 + f] = aB1;
                agg_v[((size_t)rB * 3 + 1) * 64 + f] = aB2;
                agg_v[((size_t)rB * 3 + 2) * 64 + f] = aB3;
            } else {
                unsafeAtomicAdd(&agg_s[(size_t)rB * 64 + f], aB0);
                unsafeAtomicAdd(&agg_v[((size_t)rB * 3 + 0) * 64 + f], aB1);
                unsafeAtomicAdd(&agg_v[((size_t)rB * 3 + 1) * 64 + f], aB2);
                unsafeAtomicAdd(&agg_v[((size_t)rB * 3 + 2) * 64 + f], aB3);
            }
            aB0 = aB1 = aB2 = aB3 = 0.f;
            if (pB + 1 == endB && k < 15) {
                begB = endB; ++rB; endB = row_start[rB + 1];
                while (endB == begB) { ++rB; endB = row_start[rB + 1]; }
            }
        }
        // rotate pipelines
        ssA = ssA_n; vA0 = vA0n; vA1 = vA1n; vA2 = vA2n;
        ssB = ssB_n; vB0 = vB0n; vB1 = vB1n; vB2 = vB2n;
        srA_c = srA_n; srA_n = srA_n2;
        srB_c = srB_n; srB_n = srB_n2;
    }
}

// ---------------------------------------------------------------------------
// MFMA node kernel (unchanged): wave = 16 sorted nodes.
// ---------------------------------------------------------------------------
__global__ __launch_bounds__(256) void node_mfma_kernel(
    const float* __restrict__ agg_s, const float* __restrict__ agg_v,
    float* s, float* v,
    const short* __restrict__ packW, int it,
    const float* __restrict__ pw_i,
    const int* __restrict__ spec_srt,
    int has_skip)
{
    const int l = threadIdx.x & 63;
    const int wid = threadIdx.x >> 6;
    const int cl = l & 15;
    const int q = l >> 4;
    const int i16 = (blockIdx.x * 4 + wid) * 16;
    __shared__ float xls_all[4][16 * 65];
    float* xls = xls_all[wid];

    const short* pWls = packW + (size_t)(0 + it) * 4096;
    const short* pWlv = packW + (size_t)(2 + it) * 4096;
    const short* pWps = packW + (size_t)(4 + it) * 4096;
    const short* pWpv = packW + (size_t)(6 + it) * 4096;
    const short* pSkS = packW + (size_t)8 * 4096;
    const short* pSkV = packW + (size_t)18 * 4096;
    const short8 z8 = {0, 0, 0, 0, 0, 0, 0, 0};

    const float* ars = agg_s + (size_t)(i16 + cl) * 64;
    short8 As[2] = { loadArow(ars, 0, q), loadArow(ars, 1, q) };
    short8 Av[3][2];
#pragma unroll
    for (int k = 0; k < 3; ++k) {
        const float* r = agg_v + ((size_t)(i16 + cl) * 3 + k) * 64;
        Av[k][0] = loadArow(r, 0, q);
        Av[k][1] = loadArow(r, 1, q);
    }

    f32x4 sD[4];
#pragma unroll
    for (int t = 0; t < 4; ++t) {
        f32x4 acc = {0.f, 0.f, 0.f, 0.f};
        acc = MFMA16(As[0], loadB(pWls, t, 0, l), acc);
        acc = MFMA16(As[1], loadB(pWls, t, 1, l), acc);
        sD[t] = acc;
    }

    f32x4 vD[3][4];
#pragma unroll
    for (int k = 0; k < 3; ++k)
#pragma unroll
        for (int t = 0; t < 4; ++t) vD[k][t] = (f32x4){0.f, 0.f, 0.f, 0.f};
#pragma unroll
    for (int t = 0; t < 4; ++t)
#pragma unroll
        for (int h = 0; h < 2; ++h) {
            short8 b = loadB(pWlv, t, h, l);
#pragma unroll
            for (int k = 0; k < 3; ++k) vD[k][t] = MFMA16(Av[k][h], b, vD[k][t]);
        }

    int z0 = spec_srt[i16], z1 = spec_srt[i16 + 15];
    float psD[4][4], pvsD[4][4];
    if (z0 == z1) {
        const float* pb = pw_i + z0 * 576 + cl;
        float pc[9][4];
#pragma unroll
        for (int c = 0; c < 9; ++c)
#pragma unroll
            for (int t = 0; t < 4; ++t) pc[c][t] = pb[c * 64 + t * 16];
#pragma unroll
        for (int t = 0; t < 4; ++t)
#pragma unroll
            for (int r = 0; r < 4; ++r) {
                float x = sD[t][r] * EPS_C;
                float w0 = vD[0][t][r] * EPS_C;
                float w1 = vD[1][t][r] * EPS_C;
                float w2 = vD[2][t][r] * EPS_C;
                vD[0][t][r] = w0; vD[1][t][r] = w1; vD[2][t][r] = w2;
                float vv = w0 * w0 + w1 * w1 + w2 * w2;
                float x2 = x * x;
                psD[t][r] = pc[0][t] * x + pc[1][t] * x2 + pc[2][t] * vv
                          + pc[3][t] * x2 * x + pc[4][t] * x * vv;
                pvsD[t][r] = pc[5][t] + pc[6][t] * x + pc[7][t] * x2 + pc[8][t] * vv;
            }
    } else {
#pragma unroll
        for (int r = 0; r < 4; ++r) {
            int z = spec_srt[i16 + q * 4 + r];
            const float* pb = pw_i + z * 576 + cl;
#pragma unroll
            for (int t = 0; t < 4; ++t) {
                float p0 = pb[t*16], p1 = pb[64+t*16], p2 = pb[128+t*16];
                float p3 = pb[192+t*16], p4 = pb[256+t*16], p5 = pb[320+t*16];
                float p6 = pb[384+t*16], p7 = pb[448+t*16], p8 = pb[512+t*16];
                float x = sD[t][r] * EPS_C;
                float w0 = vD[0][t][r] * EPS_C;
                float w1 = vD[1][t][r] * EPS_C;
                float w2 = vD[2][t][r] * EPS_C;
                vD[0][t][r] = w0; vD[1][t][r] = w1; vD[2][t][r] = w2;
                float vv = w0 * w0 + w1 * w1 + w2 * w2;
                float x2 = x * x;
                psD[t][r] = p0 * x + p1 * x2 + p2 * vv + p3 * x2 * x + p4 * x * vv;
                pvsD[t][r] = p5 + p6 * x + p7 * x2 + p8 * vv;
            }
        }
    }

#pragma unroll
    for (int t = 0; t < 4; ++t)
#pragma unroll
        for (int r = 0; r < 4; ++r)
            xls[(q * 4 + r) * 65 + t * 16 + cl] = psD[t][r];
    short8 psA[2];
#pragma unroll
    for (int h = 0; h < 2; ++h) {
        const float* rp = xls + cl * 65 + h * 32 + q * 8;
        float t0 = rp[0], t1 = rp[1], t2 = rp[2], t3 = rp[3];
        float t4 = rp[4], t5 = rp[5], t6 = rp[6], t7 = rp[7];
        psA[h] = cvt8(make_float4(t0, t1, t2, t3), make_float4(t4, t5, t6, t7));
    }

    f32x4 snD[4];
#pragma unroll
    for (int t = 0; t < 4; ++t) {
        f32x4 acc = {0.f, 0.f, 0.f, 0.f};
        acc = MFMA16(psA[0], loadB(pWps, t, 0, l), acc);
        acc = MFMA16(psA[1], loadB(pWps, t, 1, l), acc);
        snD[t] = acc;
    }
    if (has_skip) {
        const float* srow = s + (size_t)(i16 + cl) * 64;
        short8 Ai0 = loadArow(srow, 0, q), Ai1 = loadArow(srow, 1, q);
        int myz = spec_srt[i16 + cl];
        for (int z = z0; z <= z1; ++z) {
            bool keep = (myz == z);
            short8 m0 = keep ? Ai0 : z8;
            short8 m1 = keep ? Ai1 : z8;
            const short* pz = pSkS + (size_t)z * 4096;
#pragma unroll
            for (int t = 0; t < 4; ++t) {
                snD[t] = MFMA16(m0, loadB(pz, t, 0, l), snD[t]);
                snD[t] = MFMA16(m1, loadB(pz, t, 1, l), snD[t]);
            }
        }
    }
#pragma unroll
    for (int t = 0; t < 4; ++t)
#pragma unroll
        for (int r = 0; r < 4; ++r)
            s[(size_t)(i16 + q * 4 + r) * 64 + t * 16 + cl] = snD[t][r];

    short8 pvA[3][2];
#pragma unroll
    for (int k = 0; k < 3; ++k) {
#pragma unroll
        for (int t = 0; t < 4; ++t)
#pragma unroll
            for (int r = 0; r < 4; ++r)
                xls[(q * 4 + r) * 65 + t * 16 + cl] = pvsD[t][r] * vD[k][t][r];
#pragma unroll
        for (int h = 0; h < 2; ++h) {
            const float* rp = xls + cl * 65 + h * 32 + q * 8;
            float t0 = rp[0], t1 = rp[1], t2 = rp[2], t3 = rp[3];
            float t4 = rp[4], t5 = rp[5], t6 = rp[6], t7 = rp[7];
            pvA[k][h] = cvt8(make_float4(t0, t1, t2, t3), make_float4(t4, t5, t6, t7));
        }
    }

    f32x4 vnD[3][4];
#pragma unroll
    for (int k = 0; k < 3; ++k)
#pragma unroll
        for (int t = 0; t < 4; ++t) vnD[k][t] = (f32x4){0.f, 0.f, 0.f, 0.f};
#pragma unroll
    for (int t = 0; t < 4; ++t)
#pragma unroll
        for (int h = 0; h < 2; ++h) {
            short8 b = loadB(pWpv, t, h, l);
#pragma unroll
            for (int k = 0; k < 3; ++k) vnD[k][t] = MFMA16(pvA[k][h], b, vnD[k][t]);
        }
    if (has_skip) {
        short8 Aiv[3][2];
#pragma unroll
        for (int k = 0; k < 3; ++k) {
            const float* r = v + ((size_t)(i16 + cl) * 3 + k) * 64;
            Aiv[k][0] = loadArow(r, 0, q);
            Aiv[k][1] = loadArow(r, 1, q);
        }
        int myz = spec_srt[i16 + cl];
        for (int z = z0; z <= z1; ++z) {
            bool keep = (myz == z);
            const short* pz = pSkV + (size_t)z * 4096;
#pragma unroll
            for (int t = 0; t < 4; ++t)
#pragma unroll
                for (int h = 0; h < 2; ++h) {
                    short8 b = loadB(pz, t, h, l);
#pragma unroll
                    for (int k = 0; k < 3; ++k) {
                        short8 a = keep ? Aiv[k][h] : z8;
                        vnD[k][t] = MFMA16(a, b, vnD[k][t]);
                    }
                }
        }
    }
#pragma unroll
    for (int k = 0; k < 3; ++k)
#pragma unroll
        for (int t = 0; t < 4; ++t)
#pragma unroll
            for (int r = 0; r < 4; ++r)
                v[((size_t)(i16 + q * 4 + r) * 3 + k) * 64 + t * 16 + cl] = vnD[k][t][r];
}

// ---------------------------------------------------------------------------
// Readouts (sorted s -> out[sidx])
// ---------------------------------------------------------------------------
__global__ __launch_bounds__(256) void read0_kernel(
    const float* __restrict__ s, const float* __restrict__ Wread0,
    const int* __restrict__ sidx, float* __restrict__ out)
{
    const int wid = threadIdx.x >> 6;
    const int f = threadIdx.x & 63;
    const int i4 = (blockIdx.x * 4 + wid) * 4;
    float w0 = Wread0[f];
#pragma unroll
    for (int t = 0; t < 4; ++t) {
        float a = s[(size_t)(i4 + t) * 64 + f] * w0;
        for (int off = 32; off; off >>= 1) a += __shfl_down(a, off);
        if (f == 0) out[(size_t)sidx[i4 + t] * 2 + 0] = a;
    }
}

__global__ __launch_bounds__(256) void read1_kernel(
    const float* __restrict__ s, const float* __restrict__ Wr1a,
    const float* __restrict__ Wr1b, const int* __restrict__ sidx,
    float* __restrict__ out)
{
    const int wid = threadIdx.x >> 6;
    const int f = threadIdx.x & 63;
    const int i4 = (blockIdx.x * 4 + wid) * 4;
    int hh = f & 15;
    int t0 = f >> 4;
    float a = 0.f;
    const float* sp = s + (size_t)(i4 + t0) * 64;
#pragma unroll 8
    for (int g = 0; g < 64; ++g)
        a = fmaf(sp[g], Wr1a[g * 16 + hh], a);
    float r0 = (a / (1.f + expf(-a))) * Wr1b[hh];
    for (int off = 8; off; off >>= 1) r0 += __shfl_down(r0, off);
    if (hh == 0) out[(size_t)sidx[i4 + t0] * 2 + 1] = r0;
}

// ---------------------------------------------------------------------------
extern "C" void kernel_launch(void* const* d_in, const int* in_sizes, int n_in,
                              void* d_out, int out_size, void* d_ws, size_t ws_size,
                              hipStream_t stream)
{
    const float* vectors = (const float*)d_in[0];
    const float* embed_s = (const float*)d_in[1];
    const float* Wr      = (const float*)d_in[2];   // [2,8,320]
    const float* Wls     = (const float*)d_in[3];   // [2,64,64]
    const float* Wlv     = (const float*)d_in[4];
    const float* skip_s  = (const float*)d_in[5];   // [10,64,64]
    const float* skip_v  = (const float*)d_in[6];
    const float* pw      = (const float*)d_in[7];   // [2,10,9,64]
    const float* Wps     = (const float*)d_in[8];
    const float* Wpv     = (const float*)d_in[9];
    const float* Wread0  = (const float*)d_in[10];  // [64,1]
    const float* Wr1a    = (const float*)d_in[11];  // [64,16]
    const float* Wr1b    = (const float*)d_in[12];  // [16,1]
    const int* senders   = (const int*)d_in[13];
    const int* receivers = (const int*)d_in[14];
    const int* species   = (const int*)d_in[15];
    float* out = (float*)d_out;

    float* ws = (float*)d_ws;
    float* edata = ws; ws += (size_t)N_EDGES * 16;  // 16 MB (slot-ordered)
    float* s     = ws; ws += (size_t)N_NODES * 64;  // 8 MB
    float* v     = ws; ws += (size_t)N_NODES * 192; // 24 MB
    float* agg_s = ws; ws += (size_t)N_NODES * 64;  // 8 MB
    float* agg_v = ws; ws += (size_t)N_NODES * 192; // 24 MB
    int* counts    = (int*)ws; ws += N_NODES;
    int* row_start = (int*)ws; ws += N_NODES + 4;
    int* cursor    = (int*)ws; ws += N_NODES;
    int* edge_ids  = (int*)ws; ws += N_EDGES;
    int* srk       = (int*)ws; ws += N_EDGES;
    int* grp_row   = (int*)ws; ws += N_EDGES / 16;
    int* sidx      = (int*)ws; ws += N_NODES;
    int* rank      = (int*)ws; ws += N_NODES;
    int* spec_srt  = (int*)ws; ws += N_NODES;
    int* lrank_arr = (int*)ws; ws += N_NODES;
    int* counts_blk = (int*)ws; ws += 128 * NSPEC;
    int* off_blk    = (int*)ws; ws += 128 * NSPEC;
    short* packW   = (short*)ws;                    // 224 KB

    // species counting sort (no atomics, deterministic)
    sort1_kernel<<<N_NODES / 256, 256, 0, stream>>>(species, counts_blk, lrank_arr);
    sort2_kernel<<<1, 640, 0, stream>>>(counts_blk, off_blk);
    sort3_kernel<<<N_NODES / 256, 256, 0, stream>>>(
        species, lrank_arr, off_blk, sidx, rank, spec_srt);

    // receiver CSR in sorted space, deterministic row order
    hipMemsetAsync(counts, 0, N_NODES * sizeof(int), stream);
    hist_kernel<<<N_EDGES / 256, 256, 0, stream>>>(receivers, rank, counts);
    scan_kernel<<<1, 1024, 0, stream>>>(counts, row_start, cursor);
    scatter_kernel<<<N_EDGES / 256, 256, 0, stream>>>(receivers, rank, cursor, edge_ids);
    rowsort_kernel<<<N_NODES / 256, 256, 0, stream>>>(row_start, edge_ids);
    grprow_kernel<<<N_EDGES / 16 / 256, 256, 0, stream>>>(row_start, grp_row);

    // edge features + sender ranks in slot order (one pass)
    edge_pre_kernel<<<N_EDGES / 256, 256, 0, stream>>>(
        vectors, edge_ids, senders, rank, edata, srk);

    init_s_kernel<<<N_NODES * 64 / 256, 256, 0, stream>>>(embed_s, spec_srt, s);
    pack_kernel<<<448, 256, 0, stream>>>(Wls, Wlv, Wps, Wpv, skip_s, skip_v, packW);

    // interaction 0
    zero_bnd_kernel<<<N_NODES / 16, 256, 0, stream>>>(row_start, agg_s, agg_v);
    gather_kernel<1><<<N_EDGES / 32 / 4, 256, 0, stream>>>(
        edata, srk, row_start, grp_row, s, v, Wr, agg_s, agg_v);
    node_mfma_kernel<<<N_NODES / 64, 256, 0, stream>>>(
        agg_s, agg_v, s, v, packW, 0, pw, spec_srt, 0);
    read0_kernel<<<N_NODES / 16, 256, 0, stream>>>(s, Wread0, sidx, out);

    // interaction 1
    zero_bnd_kernel<<<N_NODES / 16, 256, 0, stream>>>(row_start, agg_s, agg_v);
    gather_kernel<0><<<N_EDGES / 32 / 4, 256, 0, stream>>>(
        edata, srk, row_start, grp_row, s, v, Wr + 2560, agg_s, agg_v);
    node_mfma_kernel<<<N_NODES / 64, 256, 0, stream>>>(
        agg_s, agg_v, s, v, packW, 1, pw + 5760, spec_srt, 1);
    read1_kernel<<<N_NODES / 16, 256, 0, stream>>>(s, Wr1a, Wr1b, sidx, out);
}

// Round 14
// 338.887 us; speedup vs baseline: 1.1007x; 1.0046x over previous
//
#include <hip/hip_runtime.h>
#include <hip/hip_bf16.h>
#include <math.h>

#define N_NODES 32768
#define N_EDGES 262144
#define EPS_C 0.24253562503633297f   // 1/sqrt(17)
#define NSPEC 10

typedef __attribute__((ext_vector_type(8))) short short8;   // 8 bf16
typedef __attribute__((ext_vector_type(4))) float f32x4;    // 4 fp32 acc

#define MFMA16(a, b, c) __builtin_amdgcn_mfma_f32_16x16x32_bf16(a, b, c, 0, 0, 0)

__device__ __forceinline__ short2 cvt2(float a, float b) {
    union { __hip_bfloat162 h; short2 s; } u;
    u.h = __float22bfloat162_rn(make_float2(a, b));
    return u.s;
}
__device__ __forceinline__ short8 cvt8(float4 a, float4 b) {
    short2 p0 = cvt2(a.x, a.y), p1 = cvt2(a.z, a.w);
    short2 p2 = cvt2(b.x, b.y), p3 = cvt2(b.z, b.w);
    short8 r;
    r[0] = p0.x; r[1] = p0.y; r[2] = p1.x; r[3] = p1.y;
    r[4] = p2.x; r[5] = p2.y; r[6] = p3.x; r[7] = p3.y;
    return r;
}
__device__ __forceinline__ short8 loadArow(const float* rowp, int h, int q) {
    const float* p = rowp + h * 32 + q * 8;
    return cvt8(*(const float4*)p, *(const float4*)(p + 4));
}
__device__ __forceinline__ short8 loadB(const short* P, int t, int h, int l) {
    return *(const short8*)(P + (((t * 2 + h) * 64 + l) << 3));
}

// ---------------------------------------------------------------------------
// Species counting sort — contention-free, deterministic (ballot/popcount).
// ---------------------------------------------------------------------------
__global__ __launch_bounds__(256) void sort1_kernel(
    const int* __restrict__ species, int* __restrict__ counts_blk,
    int* __restrict__ lrank_arr)
{
    __shared__ int wcnt[4][16];
    int n = blockIdx.x * 256 + threadIdx.x;
    int sp = species[n];
    int lane = threadIdx.x & 63, wv = threadIdx.x >> 6;
    unsigned long long ltmask = (1ull << lane) - 1;
    int lrank_w = 0;
#pragma unroll
    for (int z = 0; z < NSPEC; ++z) {
        unsigned long long m = __ballot(sp == z);
        if (sp == z) lrank_w = __popcll(m & ltmask);
        if (lane == 0) wcnt[wv][z] = __popcll(m);
    }
    __syncthreads();
    int off = 0;
    for (int w = 0; w < wv; ++w) off += wcnt[w][sp];
    lrank_arr[n] = lrank_w + off;
    if (threadIdx.x < NSPEC)
        counts_blk[blockIdx.x * NSPEC + threadIdx.x] =
            wcnt[0][threadIdx.x] + wcnt[1][threadIdx.x] +
            wcnt[2][threadIdx.x] + wcnt[3][threadIdx.x];
}

// parallel block-offset scan: wave z shuffle-scans its 128 block counts
__global__ __launch_bounds__(640) void sort2_kernel(
    const int* __restrict__ counts_blk, int* __restrict__ off_blk)
{
    __shared__ int totals[16];
    int wv = threadIdx.x >> 6;        // 0..9 == species z
    int lane = threadIdx.x & 63;
    int c0 = counts_blk[lane * NSPEC + wv];
    int c1 = counts_blk[(64 + lane) * NSPEC + wv];
    int s0 = c0;
#pragma unroll
    for (int off = 1; off < 64; off <<= 1) {
        int y = __shfl_up(s0, off);
        if (lane >= off) s0 += y;
    }
    int tot0 = __shfl(s0, 63);
    int s1 = c1;
#pragma unroll
    for (int off = 1; off < 64; off <<= 1) {
        int y = __shfl_up(s1, off);
        if (lane >= off) s1 += y;
    }
    s1 += tot0;
    if (lane == 63) totals[wv] = s1;
    __syncthreads();
    int base = 0;
    for (int q = 0; q < wv; ++q) base += totals[q];
    off_blk[lane * NSPEC + wv] = base + s0 - c0;
    off_blk[(64 + lane) * NSPEC + wv] = base + s1 - c1;
}

__global__ __launch_bounds__(256) void sort3_kernel(
    const int* __restrict__ species, const int* __restrict__ lrank_arr,
    const int* __restrict__ off_blk,
    int* __restrict__ sidx, int* __restrict__ rank, int* __restrict__ spec_srt)
{
    int n = blockIdx.x * 256 + threadIdx.x;
    int sp = species[n];
    int slot = off_blk[blockIdx.x * NSPEC + sp] + lrank_arr[n];
    sidx[slot] = n;
    rank[n] = slot;
    spec_srt[slot] = sp;
}

// ---------------------------------------------------------------------------
// Receiver CSR in SORTED space
// ---------------------------------------------------------------------------
__global__ __launch_bounds__(256) void hist_kernel(
    const int* __restrict__ receivers, const int* __restrict__ rank,
    int* __restrict__ counts)
{
    int e = blockIdx.x * 256 + threadIdx.x;
    atomicAdd(&counts[rank[receivers[e]]], 1);
}

__global__ __launch_bounds__(1024) void scan_kernel(
    const int* __restrict__ counts, int* __restrict__ row_start, int* __restrict__ cursor)
{
    __shared__ int wave_tot[16];
    int tid = threadIdx.x;
    int c[32];
    int sum = 0;
#pragma unroll
    for (int i = 0; i < 32; ++i) { c[i] = counts[tid * 32 + i]; sum += c[i]; }
    int lane = tid & 63, wv = tid >> 6;
    int x = sum;
#pragma unroll
    for (int off = 1; off < 64; off <<= 1) {
        int y = __shfl_up(x, off);
        if (lane >= off) x += y;
    }
    if (lane == 63) wave_tot[wv] = x;
    __syncthreads();
    if (wv == 0 && lane < 16) {
        int t = wave_tot[lane];
#pragma unroll
        for (int off = 1; off < 16; off <<= 1) {
            int y = __shfl_up(t, off);
            if (lane >= off) t += y;
        }
        wave_tot[lane] = t;
    }
    __syncthreads();
    int excl = x - sum + (wv ? wave_tot[wv - 1] : 0);
    int run = excl;
#pragma unroll
    for (int i = 0; i < 32; ++i) {
        row_start[tid * 32 + i] = run;
        cursor[tid * 32 + i] = run;
        run += c[i];
    }
    if (tid == 1023) row_start[32768] = run;
}

__global__ __launch_bounds__(256) void scatter_kernel(
    const int* __restrict__ receivers, const int* __restrict__ rank,
    int* __restrict__ cursor, int* __restrict__ edge_ids)
{
    int e = blockIdx.x * 256 + threadIdx.x;
    int slot = atomicAdd(&cursor[rank[receivers[e]]], 1);
    edge_ids[slot] = e;
}

// per-row insertion sort in LDS (deterministic edge order per row)
__global__ __launch_bounds__(256) void rowsort_kernel(
    const int* __restrict__ row_start, int* __restrict__ edge_ids)
{
    __shared__ int buf[256 * 33];
    int i = blockIdx.x * 256 + threadIdx.x;
    int beg = row_start[i], end = row_start[i + 1];
    int len = end - beg;
    int* b = buf + threadIdx.x * 33;
    if (len <= 32) {
        for (int j = 0; j < len; ++j) b[j] = edge_ids[beg + j];
        for (int a = 1; a < len; ++a) {
            int key = b[a];
            int c = a - 1;
            while (c >= 0 && b[c] > key) { b[c + 1] = b[c]; --c; }
            b[c + 1] = key;
        }
        for (int j = 0; j < len; ++j) edge_ids[beg + j] = b[j];
    } else {
        for (int a = beg + 1; a < end; ++a) {
            int key = edge_ids[a];
            int c = a - 1;
            while (c >= beg && edge_ids[c] > key) { edge_ids[c + 1] = edge_ids[c]; --c; }
            edge_ids[c + 1] = key;
        }
    }
}

// grp_row[g]: row containing slot 16g (largest r with row_start[r] <= 16g)
__global__ __launch_bounds__(256) void grprow_kernel(
    const int* __restrict__ row_start, int* __restrict__ grp_row)
{
    int g = blockIdx.x * 256 + threadIdx.x;   // 16384
    int target = g * 16;
    int lo = 0, hi = N_NODES - 1;
    while (lo < hi) {
        int mid = (lo + hi + 1) >> 1;
        if (row_start[mid] <= target) lo = mid; else hi = mid - 1;
    }
    grp_row[g] = lo;
}

// zero agg rows that are empty or cross a 16-slot chain boundary
__global__ __launch_bounds__(256) void zero_bnd_kernel(
    const int* __restrict__ row_start,
    float* __restrict__ agg_s, float* __restrict__ agg_v)
{
    const int wid = threadIdx.x >> 6;
    const int f = threadIdx.x & 63;
    const int base = (blockIdx.x * 4 + wid) * 4;
#pragma unroll
    for (int t = 0; t < 4; ++t) {
        int i = base + t;
        int beg = row_start[i], end = row_start[i + 1];
        bool need = (end == beg) || (end > (((beg >> 4) + 1) << 4));
        if (need) {
            agg_s[(size_t)i * 64 + f] = 0.f;
            agg_v[((size_t)i * 3 + 0) * 64 + f] = 0.f;
            agg_v[((size_t)i * 3 + 1) * 64 + f] = 0.f;
            agg_v[((size_t)i * 3 + 2) * 64 + f] = 0.f;
        }
    }
}

// ---------------------------------------------------------------------------
// Edge precompute in slot order + fused sender-rank stream:
// edata[p*16] = {y0,y1,y2,0, rbf[8], pad};  srk[p] = rank[senders[edge_ids[p]]]
// ---------------------------------------------------------------------------
__global__ __launch_bounds__(256) void edge_pre_kernel(
    const float* __restrict__ vectors, const int* __restrict__ edge_ids,
    const int* __restrict__ senders, const int* __restrict__ rank,
    float* __restrict__ edata, int* __restrict__ srk)
{
    int p = blockIdx.x * 256 + threadIdx.x;
    int e = edge_ids[p];
    srk[p] = rank[senders[e]];
    float x = vectors[e * 3 + 0], y = vectors[e * 3 + 1], z = vectors[e * 3 + 2];
    float r2 = x * x + y * y + z * z + 1e-12f;
    float r = sqrtf(r2);
    float inv = 1.0f / r;
    float* d = edata + (size_t)p * 16;
    *(float4*)d = make_float4(x * inv, y * inv, z * inv, 0.0f);
    float rc = fmaxf(r, 1e-6f);
    float r6 = r2 * r2 * r2;
    float r7 = r6 * r;
    float r8 = r6 * r2;
    float env = (r < 1.0f) ? (1.0f - 28.0f * r6 + 48.0f * r7 - 21.0f * r8) : 0.0f;
    float sc = 1.41421356237309515f * env / rc;
#pragma unroll
    for (int j = 0; j < 8; ++j)
        d[4 + j] = sc * sinf((float)(j + 1) * 3.14159265358979323846f * rc);
    d[12] = 0.f; d[13] = 0.f; d[14] = 0.f; d[15] = 0.f;
}

// ---------------------------------------------------------------------------
// Node init (sorted layout)
// ---------------------------------------------------------------------------
__global__ __launch_bounds__(256) void init_s_kernel(
    const float* __restrict__ embed_s, const int* __restrict__ spec_srt,
    float* __restrict__ s)
{
    int idx = blockIdx.x * 256 + threadIdx.x;
    s[idx] = embed_s[spec_srt[idx >> 6] * 64 + (idx & 63)];
}

// ---------------------------------------------------------------------------
// Weight pre-pack: 28 64x64 fp32 matrices -> bf16 B-fragment order.
// ---------------------------------------------------------------------------
__global__ __launch_bounds__(256) void pack_kernel(
    const float* __restrict__ Wls, const float* __restrict__ Wlv,
    const float* __restrict__ Wps, const float* __restrict__ Wpv,
    const float* __restrict__ skip_s, const float* __restrict__ skip_v,
    short* __restrict__ packW)
{
    int idx = blockIdx.x * 256 + threadIdx.x;   // 28*4096 = 114688
    if (idx >= 28 * 4096) return;
    int m = idx >> 12, e = idx & 4095;
    int t = e >> 10, h = (e >> 9) & 1, l = (e >> 3) & 63, j = e & 7;
    int fi = h * 32 + ((l >> 4) << 3) + j;
    int fo = t * 16 + (l & 15);
    const float* src;
    if      (m < 2)  src = Wls    + m * 4096;
    else if (m < 4)  src = Wlv    + (m - 2) * 4096;
    else if (m < 6)  src = Wps    + (m - 4) * 4096;
    else if (m < 8)  src = Wpv    + (m - 6) * 4096;
    else if (m < 18) src = skip_s + (m - 8) * 4096;
    else             src = skip_v + (m - 18) * 4096;
    packW[idx] = cvt2(src[fi * 64 + fo], 0.f).x;
}

// ---------------------------------------------------------------------------
// Dual-chain edge-balanced gather (rolled loop — R12 form, measured best):
// wave w owns slots [32w,32w+32) as TWO independent 16-slot chains (A,B),
// each software-pipelined (indices 2-ahead, values 1-ahead). Rows fully
// inside a chain range: plain store; boundary rows: unsafeAtomicAdd.
// ---------------------------------------------------------------------------
template<int VZERO>
__global__ __launch_bounds__(256) void gather_kernel(
    const float* __restrict__ edata, const int* __restrict__ srk,
    const int* __restrict__ row_start, const int* __restrict__ grp_row,
    const float* __restrict__ s_in, const float* __restrict__ v_in,
    const float* __restrict__ Wr_i,
    float* __restrict__ agg_s, float* __restrict__ agg_v)
{
    const int wid = threadIdx.x >> 6;
    const int f = threadIdx.x & 63;
    const int w = blockIdx.x * 4 + wid;
    const int pA0 = w * 32;
    const int pB0 = pA0 + 16;

    float wr[5][8];
#pragma unroll
    for (int j = 0; j < 8; ++j)
#pragma unroll
        for (int p = 0; p < 5; ++p)
            wr[p][j] = (VZERO && (p == 1 || p == 3 || p == 4))
                       ? 0.f : Wr_i[j * 320 + p * 64 + f];

    int rA = grp_row[2 * w], rB = grp_row[2 * w + 1];
    int begA = row_start[rA], endA = row_start[rA + 1];
    int begB = row_start[rB], endB = row_start[rB + 1];
    float aA0 = 0.f, aA1 = 0.f, aA2 = 0.f, aA3 = 0.f;
    float aB0 = 0.f, aB1 = 0.f, aB2 = 0.f, aB3 = 0.f;

    int srA_c = srk[pA0],     srB_c = srk[pB0];
    int srA_n = srk[pA0 + 1], srB_n = srk[pB0 + 1];
    float ssA = s_in[(size_t)srA_c * 64 + f];
    float ssB = s_in[(size_t)srB_c * 64 + f];
    float vA0 = 0.f, vA1 = 0.f, vA2 = 0.f, vB0 = 0.f, vB1 = 0.f, vB2 = 0.f;
    if (!VZERO) {
        vA0 = v_in[((size_t)srA_c * 3 + 0) * 64 + f];
        vA1 = v_in[((size_t)srA_c * 3 + 1) * 64 + f];
        vA2 = v_in[((size_t)srA_c * 3 + 2) * 64 + f];
        vB0 = v_in[((size_t)srB_c * 3 + 0) * 64 + f];
        vB1 = v_in[((size_t)srB_c * 3 + 1) * 64 + f];
        vB2 = v_in[((size_t)srB_c * 3 + 2) * 64 + f];
    }

    for (int k = 0; k < 16; ++k) {
        int pA = pA0 + k, pB = pB0 + k;
        // indices 2-ahead
        int srA_n2 = (k + 2 < 16) ? srk[pA + 2] : srA_n;
        int srB_n2 = (k + 2 < 16) ? srk[pB + 2] : srB_n;
        // values 1-ahead (independent chains)
        float ssA_n = s_in[(size_t)srA_n * 64 + f];
        float ssB_n = s_in[(size_t)srB_n * 64 + f];
        float vA0n = 0.f, vA1n = 0.f, vA2n = 0.f;
        float vB0n = 0.f, vB1n = 0.f, vB2n = 0.f;
        if (!VZERO) {
            vA0n = v_in[((size_t)srA_n * 3 + 0) * 64 + f];
            vA1n = v_in[((size_t)srA_n * 3 + 1) * 64 + f];
            vA2n = v_in[((size_t)srA_n * 3 + 2) * 64 + f];
            vB0n = v_in[((size_t)srB_n * 3 + 0) * 64 + f];
            vB1n = v_in[((size_t)srB_n * 3 + 1) * 64 + f];
            vB2n = v_in[((size_t)srB_n * 3 + 2) * 64 + f];
        }
        // current edge data (sequential, wave-uniform address)
        const float* dA = edata + (size_t)pA * 16;
        const float* dB = edata + (size_t)pB * 16;
        float4 yA = *(const float4*)dA;
        float4 qA0 = *(const float4*)(dA + 4);
        float4 qA1 = *(const float4*)(dA + 8);
        float4 yB = *(const float4*)dB;
        float4 qB0 = *(const float4*)(dB + 4);
        float4 qB1 = *(const float4*)(dB + 8);

        float rbA[8] = {qA0.x, qA0.y, qA0.z, qA0.w, qA1.x, qA1.y, qA1.z, qA1.w};
        float rbB[8] = {qB0.x, qB0.y, qB0.z, qB0.w, qB1.x, qB1.y, qB1.z, qB1.w};
        float wA0 = 0.f, wA1 = 0.f, wA2 = 0.f, wA3 = 0.f, wA4 = 0.f;
        float wB0 = 0.f, wB1 = 0.f, wB2 = 0.f, wB3 = 0.f, wB4 = 0.f;
#pragma unroll
        for (int j = 0; j < 8; ++j) {
            wA0 = fmaf(rbA[j], wr[0][j], wA0);  wB0 = fmaf(rbB[j], wr[0][j], wB0);
            if (!VZERO) { wA1 = fmaf(rbA[j], wr[1][j], wA1);  wB1 = fmaf(rbB[j], wr[1][j], wB1); }
            wA2 = fmaf(rbA[j], wr[2][j], wA2);  wB2 = fmaf(rbB[j], wr[2][j], wB2);
            if (!VZERO) { wA3 = fmaf(rbA[j], wr[3][j], wA3);  wB3 = fmaf(rbB[j], wr[3][j], wB3); }
            if (!VZERO) { wA4 = fmaf(rbA[j], wr[4][j], wA4);  wB4 = fmaf(rbB[j], wr[4][j], wB4); }
        }
        if (VZERO) {
            aA0 += wA0 * ssA;
            float wsA = wA2 * ssA;
            aA1 += wsA * yA.x; aA2 += wsA * yA.y; aA3 += wsA * yA.z;
            aB0 += wB0 * ssB;
            float wsB = wB2 * ssB;
            aB1 += wsB * yB.x; aB2 += wsB * yB.y; aB3 += wsB * yB.z;
        } else {
            float dotA = vA0 * yA.x + vA1 * yA.y + vA2 * yA.z;
            aA0 += wA0 * ssA + wA1 * dotA;
            float cA0 = vA1 * yA.z - vA2 * yA.y;
            float cA1 = vA2 * yA.x - vA0 * yA.z;
            float cA2 = vA0 * yA.y - vA1 * yA.x;
            float wsA = wA2 * ssA;
            aA1 += wsA * yA.x + wA3 * vA0 + wA4 * cA0;
            aA2 += wsA * yA.y + wA3 * vA1 + wA4 * cA1;
            aA3 += wsA * yA.z + wA3 * vA2 + wA4 * cA2;
            float dotB = vB0 * yB.x + vB1 * yB.y + vB2 * yB.z;
            aB0 += wB0 * ssB + wB1 * dotB;
            float cB0 = vB1 * yB.z - vB2 * yB.y;
            float cB1 = vB2 * yB.x - vB0 * yB.z;
            float cB2 = vB0 * yB.y - vB1 * yB.x;
            float wsB = wB2 * ssB;
            aB1 += wsB * yB.x + wB3 * vB0 + wB4 * cB0;
            aB2 += wsB * yB.y + wB3 * vB1 + wB4 * cB1;
            aB3 += wsB * yB.z + wB3 * vB2 + wB4 * cB2;
        }

        // flush chain A (wave-uniform)
        if (pA + 1 == endA || k == 15) {
            bool interior = (begA >= pA0) && (endA <= pA0 + 16);
            if (interior) {
                agg_s[(size_t)rA * 64 + f] = aA0;
                agg_v[((size_t)rA * 3 + 0) * 64 + f] = aA1;
                agg_v[((size_t)rA * 3 + 1) * 64 + f] = aA2;
                agg_v[((size_t)rA * 3 + 2) * 64 + f] = aA3;
            } else {
                unsafeAtomicAdd(&agg_s[(size_t)rA * 64 + f], aA0);
                unsafeAtomicAdd(&agg_v[((size_t)rA * 3 + 0) * 64 + f], aA1);
                unsafeAtomicAdd(&agg_v[((size_t)rA * 3 + 1) * 64 + f], aA2);
                unsafeAtomicAdd(&agg_v[((size_t)rA * 3 + 2) * 64 + f], aA3);
            }
            aA0 = aA1 = aA2 = aA3 = 0.f;
            if (pA + 1 == endA && k < 15) {
                begA = endA; ++rA; endA = row_start[rA + 1];
                while (endA == begA) { ++rA; endA = row_start[rA + 1]; }
            }
        }
        // flush chain B (wave-uniform)
        if (pB + 1 == endB || k == 15) {
            bool interior = (begB >= pB0) && (endB <= pB0 + 16);
            if (interior) {
                agg_s[(size_t)rB * 64 + f] = aB0;
                agg_v[((size_t)rB * 3 + 0) * 64 + f] = aB1;
                agg_v[((size_t)rB * 3 + 1) * 64 + f] = aB2;
                agg_v[((size_t)rB * 3 + 2) * 64 + f] = aB3;
            } else {
                unsafeAtomicAdd(&agg_s[(size_t)rB * 64 + f], aB0);
                unsafeAtomicAdd(&agg_v[((size_t)rB * 3 + 0) * 64 + f], aB1);
                unsafeAtomicAdd(&agg_v[((size_t)rB * 3 + 1) * 64 + f], aB2);
                unsafeAtomicAdd(&agg_v[((size_t)rB * 3 + 2) * 64 + f], aB3);
            }
            aB0 = aB1 = aB2 = aB3 = 0.f;
            if (pB + 1 == endB && k < 15) {
                begB = endB; ++rB; endB = row_start[rB + 1];
                while (endB == begB) { ++rB; endB = row_start[rB + 1]; }
            }
        }
        // rotate pipelines
        ssA = ssA_n; vA0 = vA0n; vA1 = vA1n; vA2 = vA2n;
        ssB = ssB_n; vB0 = vB0n; vB1 = vB1n; vB2 = vB2n;
        srA_c = srA_n; srA_n = srA_n2;
        srB_c = srB_n; srB_n = srB_n2;
    }
}

// ---------------------------------------------------------------------------
// MFMA node kernel (unchanged): wave = 16 sorted nodes.
// ---------------------------------------------------------------------------
__global__ __launch_bounds__(256) void node_mfma_kernel(
    const float* __restrict__ agg_s, const float* __restrict__ agg_v,
    float* s, float* v,
    const short* __restrict__ packW, int it,
    const float* __restrict__ pw_i,
    const int* __restrict__ spec_srt,
    int has_skip)
{
    const int l = threadIdx.x & 63;
    const int wid = threadIdx.x >> 6;
    const int cl = l & 15;
    const int q = l >> 4;
    const int i16 = (blockIdx.x * 4 + wid) * 16;
    __shared__ float xls_all[4][16 * 65];
    float* xls = xls_all[wid];

    const short* pWls = packW + (size_t)(0 + it) * 4096;
    const short* pWlv = packW + (size_t)(2 + it) * 4096;
    const short* pWps = packW + (size_t)(4 + it) * 4096;
    const short* pWpv = packW + (size_t)(6 + it) * 4096;
    const short* pSkS = packW + (size_t)8 * 4096;
    const short* pSkV = packW + (size_t)18 * 4096;
    const short8 z8 = {0, 0, 0, 0, 0, 0, 0, 0};

    const float* ars = agg_s + (size_t)(i16 + cl) * 64;
    short8 As[2] = { loadArow(ars, 0, q), loadArow(ars, 1, q) };
    short8 Av[3][2];
#pragma unroll
    for (int k = 0; k < 3; ++k) {
        const float* r = agg_v + ((size_t)(i16 + cl) * 3 + k) * 64;
        Av[k][0] = loadArow(r, 0, q);
        Av[k][1] = loadArow(r, 1, q);
    }

    f32x4 sD[4];
#pragma unroll
    for (int t = 0; t < 4; ++t) {
        f32x4 acc = {0.f, 0.f, 0.f, 0.f};
        acc = MFMA16(As[0], loadB(pWls, t, 0, l), acc);
        acc = MFMA16(As[1], loadB(pWls, t, 1, l), acc);
        sD[t] = acc;
    }

    f32x4 vD[3][4];
#pragma unroll
    for (int k = 0; k < 3; ++k)
#pragma unroll
        for (int t = 0; t < 4; ++t) vD[k][t] = (f32x4){0.f, 0.f, 0.f, 0.f};
#pragma unroll
    for (int t = 0; t < 4; ++t)
#pragma unroll
        for (int h = 0; h < 2; ++h) {
            short8 b = loadB(pWlv, t, h, l);
#pragma unroll
            for (int k = 0; k < 3; ++k) vD[k][t] = MFMA16(Av[k][h], b, vD[k][t]);
        }

    int z0 = spec_srt[i16], z1 = spec_srt[i16 + 15];
    float psD[4][4], pvsD[4][4];
    if (z0 == z1) {
        const float* pb = pw_i + z0 * 576 + cl;
        float pc[9][4];
#pragma unroll
        for (int c = 0; c < 9; ++c)
#pragma unroll
            for (int t = 0; t < 4; ++t) pc[c][t] = pb[c * 64 + t * 16];
#pragma unroll
        for (int t = 0; t < 4; ++t)
#pragma unroll
            for (int r = 0; r < 4; ++r) {
                float x = sD[t][r] * EPS_C;
                float w0 = vD[0][t][r] * EPS_C;
                float w1 = vD[1][t][r] * EPS_C;
                float w2 = vD[2][t][r] * EPS_C;
                vD[0][t][r] = w0; vD[1][t][r] = w1; vD[2][t][r] = w2;
                float vv = w0 * w0 + w1 * w1 + w2 * w2;
                float x2 = x * x;
                psD[t][r] = pc[0][t] * x + pc[1][t] * x2 + pc[2][t] * vv
                          + pc[3][t] * x2 * x + pc[4][t] * x * vv;
                pvsD[t][r] = pc[5][t] + pc[6][t] * x + pc[7][t] * x2 + pc[8][t] * vv;
            }
    } else {
#pragma unroll
        for (int r = 0; r < 4; ++r) {
            int z = spec_srt[i16 + q * 4 + r];
            const float* pb = pw_i + z * 576 + cl;
#pragma unroll
            for (int t = 0; t < 4; ++t) {
                float p0 = pb[t*16], p1 = pb[64+t*16], p2 = pb[128+t*16];
                float p3 = pb[192+t*16], p4 = pb[256+t*16], p5 = pb[320+t*16];
                float p6 = pb[384+t*16], p7 = pb[448+t*16], p8 = pb[512+t*16];
                float x = sD[t][r] * EPS_C;
                float w0 = vD[0][t][r] * EPS_C;
                float w1 = vD[1][t][r] * EPS_C;
                float w2 = vD[2][t][r] * EPS_C;
                vD[0][t][r] = w0; vD[1][t][r] = w1; vD[2][t][r] = w2;
                float vv = w0 * w0 + w1 * w1 + w2 * w2;
                float x2 = x * x;
                psD[t][r] = p0 * x + p1 * x2 + p2 * vv + p3 * x2 * x + p4 * x * vv;
                pvsD[t][r] = p5 + p6 * x + p7 * x2 + p8 * vv;
            }
        }
    }

#pragma unroll
    for (int t = 0; t < 4; ++t)
#pragma unroll
        for (int r = 0; r < 4; ++r)
            xls[(q * 4 + r) * 65 + t * 16 + cl] = psD[t][r];
    short8 psA[2];
#pragma unroll
    for (int h = 0; h < 2; ++h) {
        const float* rp = xls + cl * 65 + h * 32 + q * 8;
        float t0 = rp[0], t1 = rp[1], t2 = rp[2], t3 = rp[3];
        float t4 = rp[4], t5 = rp[5], t6 = rp[6], t7 = rp[7];
        psA[h] = cvt8(make_float4(t0, t1, t2, t3), make_float4(t4, t5, t6, t7));
    }

    f32x4 snD[4];
#pragma unroll
    for (int t = 0; t < 4; ++t) {
        f32x4 acc = {0.f, 0.f, 0.f, 0.f};
        acc = MFMA16(psA[0], loadB(pWps, t, 0, l), acc);
        acc = MFMA16(psA[1], loadB(pWps, t, 1, l), acc);
        snD[t] = acc;
    }
    if (has_skip) {
        const float* srow = s + (size_t)(i16 + cl) * 64;
        short8 Ai0 = loadArow(srow, 0, q), Ai1 = loadArow(srow, 1, q);
        int myz = spec_srt[i16 + cl];
        for (int z = z0; z <= z1; ++z) {
            bool keep = (myz == z);
            short8 m0 = keep ? Ai0 : z8;
            short8 m1 = keep ? Ai1 : z8;
            const short* pz = pSkS + (size_t)z * 4096;
#pragma unroll
            for (int t = 0; t < 4; ++t) {
                snD[t] = MFMA16(m0, loadB(pz, t, 0, l), snD[t]);
                snD[t] = MFMA16(m1, loadB(pz, t, 1, l), snD[t]);
            }
        }
    }
#pragma unroll
    for (int t = 0; t < 4; ++t)
#pragma unroll
        for (int r = 0; r < 4; ++r)
            s[(size_t)(i16 + q * 4 + r) * 64 + t * 16 + cl] = snD[t][r];

    short8 pvA[3][2];
#pragma unroll
    for (int k = 0; k < 3; ++k) {
#pragma unroll
        for (int t = 0; t < 4; ++t)
#pragma unroll
            for (int r = 0; r < 4; ++r)
                xls[(q * 4 + r) * 65 + t * 16 + cl] = pvsD[t][r] * vD[k][t][r];
#pragma unroll
        for (int h = 0; h < 2; ++h) {
            const float* rp = xls + cl * 65 + h * 32 + q * 8;
            float t0 = rp[0], t1 = rp[1], t2 = rp[2], t3 = rp[3];
            float t4 = rp[4], t5 = rp[5], t6 = rp[6], t7 = rp[7];
            pvA[k][h] = cvt8(make_float4(t0, t1, t2, t3), make_float4(t4, t5, t6, t7));
        }
    }

    f32x4 vnD[3][4];
#pragma unroll
    for (int k = 0; k < 3; ++k)
#pragma unroll
        for (int t = 0; t < 4; ++t) vnD[k][t] = (f32x4){0.f, 0.f, 0.f, 0.f};
#pragma unroll
    for (int t = 0; t < 4; ++t)
#pragma unroll
        for (int h = 0; h < 2; ++h) {
            short8 b = loadB(pWpv, t, h, l);
#pragma unroll
            for (int k = 0; k < 3; ++k) vnD[k][t] = MFMA16(pvA[k][h], b, vnD[k][t]);
        }
    if (has_skip) {
        short8 Aiv[3][2];
#pragma unroll
        for (int k = 0; k < 3; ++k) {
            const float* r = v + ((size_t)(i16 + cl) * 3 + k) * 64;
            Aiv[k][0] = loadArow(r, 0, q);
            Aiv[k][1] = loadArow(r, 1, q);
        }
        int myz = spec_srt[i16 + cl];
        for (int z = z0; z <= z1; ++z) {
            bool keep = (myz == z);
            const short* pz = pSkV + (size_t)z * 4096;
#pragma unroll
            for (int t = 0; t < 4; ++t)
#pragma unroll
                for (int h = 0; h < 2; ++h) {
                    short8 b = loadB(pz, t, h, l);
#pragma unroll
                    for (int k = 0; k < 3; ++k) {
                        short8 a = keep ? Aiv[k][h] : z8;
                        vnD[k][t] = MFMA16(a, b, vnD[k][t]);
                    }
                }
        }
    }
#pragma unroll
    for (int k = 0; k < 3; ++k)
#pragma unroll
        for (int t = 0; t < 4; ++t)
#pragma unroll
            for (int r = 0; r < 4; ++r)
                v[((size_t)(i16 + q * 4 + r) * 3 + k) * 64 + t * 16 + cl] = vnD[k][t][r];
}

// ---------------------------------------------------------------------------
// Readouts (sorted s -> out[sidx])
// ---------------------------------------------------------------------------
__global__ __launch_bounds__(256) void read0_kernel(
    const float* __restrict__ s, const float* __restrict__ Wread0,
    const int* __restrict__ sidx, float* __restrict__ out)
{
    const int wid = threadIdx.x >> 6;
    const int f = threadIdx.x & 63;
    const int i4 = (blockIdx.x * 4 + wid) * 4;
    float w0 = Wread0[f];
#pragma unroll
    for (int t = 0; t < 4; ++t) {
        float a = s[(size_t)(i4 + t) * 64 + f] * w0;
        for (int off = 32; off; off >>= 1) a += __shfl_down(a, off);
        if (f == 0) out[(size_t)sidx[i4 + t] * 2 + 0] = a;
    }
}

__global__ __launch_bounds__(256) void read1_kernel(
    const float* __restrict__ s, const float* __restrict__ Wr1a,
    const float* __restrict__ Wr1b, const int* __restrict__ sidx,
    float* __restrict__ out)
{
    const int wid = threadIdx.x >> 6;
    const int f = threadIdx.x & 63;
    const int i4 = (blockIdx.x * 4 + wid) * 4;
    int hh = f & 15;
    int t0 = f >> 4;
    float a = 0.f;
    const float* sp = s + (size_t)(i4 + t0) * 64;
#pragma unroll 8
    for (int g = 0; g < 64; ++g)
        a = fmaf(sp[g], Wr1a[g * 16 + hh], a);
    float r0 = (a / (1.f + expf(-a))) * Wr1b[hh];
    for (int off = 8; off; off >>= 1) r0 += __shfl_down(r0, off);
    if (hh == 0) out[(size_t)sidx[i4 + t0] * 2 + 1] = r0;
}

// ---------------------------------------------------------------------------
extern "C" void kernel_launch(void* const* d_in, const int* in_sizes, int n_in,
                              void* d_out, int out_size, void* d_ws, size_t ws_size,
                              hipStream_t stream)
{
    const float* vectors = (const float*)d_in[0];
    const float* embed_s = (const float*)d_in[1];
    const float* Wr      = (const float*)d_in[2];   // [2,8,320]
    const float* Wls     = (const float*)d_in[3];   // [2,64,64]
    const float* Wlv     = (const float*)d_in[4];
    const float* skip_s  = (const float*)d_in[5];   // [10,64,64]
    const float* skip_v  = (const float*)d_in[6];
    const float* pw      = (const float*)d_in[7];   // [2,10,9,64]
    const float* Wps     = (const float*)d_in[8];
    const float* Wpv     = (const float*)d_in[9];
    const float* Wread0  = (const float*)d_in[10];  // [64,1]
    const float* Wr1a    = (const float*)d_in[11];  // [64,16]
    const float* Wr1b    = (const float*)d_in[12];  // [16,1]
    const int* senders   = (const int*)d_in[13];
    const int* receivers = (const int*)d_in[14];
    const int* species   = (const int*)d_in[15];
    float* out = (float*)d_out;

    float* ws = (float*)d_ws;
    float* edata = ws; ws += (size_t)N_EDGES * 16;  // 16 MB (slot-ordered)
    float* s     = ws; ws += (size_t)N_NODES * 64;  // 8 MB
    float* v     = ws; ws += (size_t)N_NODES * 192; // 24 MB
    float* agg_s = ws; ws += (size_t)N_NODES * 64;  // 8 MB
    float* agg_v = ws; ws += (size_t)N_NODES * 192; // 24 MB
    int* counts    = (int*)ws; ws += N_NODES;
    int* row_start = (int*)ws; ws += N_NODES + 4;
    int* cursor    = (int*)ws; ws += N_NODES;
    int* edge_ids  = (int*)ws; ws += N_EDGES;
    int* srk       = (int*)ws; ws += N_EDGES;
    int* grp_row   = (int*)ws; ws += N_EDGES / 16;
    int* sidx      = (int*)ws; ws += N_NODES;
    int* rank      = (int*)ws; ws += N_NODES;
    int* spec_srt  = (int*)ws; ws += N_NODES;
    int* lrank_arr = (int*)ws; ws += N_NODES;
    int* counts_blk = (int*)ws; ws += 128 * NSPEC;
    int* off_blk    = (int*)ws; ws += 128 * NSPEC;
    short* packW   = (short*)ws;                    // 224 KB

    // species counting sort (no atomics, deterministic)
    sort1_kernel<<<N_NODES / 256, 256, 0, stream>>>(species, counts_blk, lrank_arr);
    sort2_kernel<<<1, 640, 0, stream>>>(counts_blk, off_blk);
    sort3_kernel<<<N_NODES / 256, 256, 0, stream>>>(
        species, lrank_arr, off_blk, sidx, rank, spec_srt);

    // receiver CSR in sorted space, deterministic row order
    hipMemsetAsync(counts, 0, N_NODES * sizeof(int), stream);
    hist_kernel<<<N_EDGES / 256, 256, 0, stream>>>(receivers, rank, counts);
    scan_kernel<<<1, 1024, 0, stream>>>(counts, row_start, cursor);
    scatter_kernel<<<N_EDGES / 256, 256, 0, stream>>>(receivers, rank, cursor, edge_ids);
    rowsort_kernel<<<N_NODES / 256, 256, 0, stream>>>(row_start, edge_ids);
    grprow_kernel<<<N_EDGES / 16 / 256, 256, 0, stream>>>(row_start, grp_row);

    // edge features + sender ranks in slot order (one pass)
    edge_pre_kernel<<<N_EDGES / 256, 256, 0, stream>>>(
        vectors, edge_ids, senders, rank, edata, srk);

    init_s_kernel<<<N_NODES * 64 / 256, 256, 0, stream>>>(embed_s, spec_srt, s);
    pack_kernel<<<448, 256, 0, stream>>>(Wls, Wlv, Wps, Wpv, skip_s, skip_v, packW);

    // interaction 0
    zero_bnd_kernel<<<N_NODES / 16, 256, 0, stream>>>(row_start, agg_s, agg_v);
    gather_kernel<1><<<N_EDGES / 32 / 4, 256, 0, stream>>>(
        edata, srk, row_start, grp_row, s, v, Wr, agg_s, agg_v);
    node_mfma_kernel<<<N_NODES / 64, 256, 0, stream>>>(
        agg_s, agg_v, s, v, packW, 0, pw, spec_srt, 0);
    read0_kernel<<<N_NODES / 16, 256, 0, stream>>>(s, Wread0, sidx, out);

    // interaction 1
    zero_bnd_kernel<<<N_NODES / 16, 256, 0, stream>>>(row_start, agg_s, agg_v);
    gather_kernel<0><<<N_EDGES / 32 / 4, 256, 0, stream>>>(
        edata, srk, row_start, grp_row, s, v, Wr + 2560, agg_s, agg_v);
    node_mfma_kernel<<<N_NODES / 64, 256, 0, stream>>>(
        agg_s, agg_v, s, v, packW, 1, pw + 5760, spec_srt, 1);
    read1_kernel<<<N_NODES / 16, 256, 0, stream>>>(s, Wr1a, Wr1b, sidx, out);
}

// Round 15
// 327.996 us; speedup vs baseline: 1.1372x; 1.0332x over previous
//
#include <hip/hip_runtime.h>
#include <hip/hip_bf16.h>
#include <math.h>

#define N_NODES 32768
#define N_EDGES 262144
#define EPS_C 0.24253562503633297f   // 1/sqrt(17)
#define NSPEC 10

typedef __attribute__((ext_vector_type(8))) short short8;   // 8 bf16
typedef __attribute__((ext_vector_type(4))) float f32x4;    // 4 fp32 acc

#define MFMA16(a, b, c) __builtin_amdgcn_mfma_f32_16x16x32_bf16(a, b, c, 0, 0, 0)

__device__ __forceinline__ short2 cvt2(float a, float b) {
    union { __hip_bfloat162 h; short2 s; } u;
    u.h = __float22bfloat162_rn(make_float2(a, b));
    return u.s;
}
__device__ __forceinline__ short8 cvt8(float4 a, float4 b) {
    short2 p0 = cvt2(a.x, a.y), p1 = cvt2(a.z, a.w);
    short2 p2 = cvt2(b.x, b.y), p3 = cvt2(b.z, b.w);
    short8 r;
    r[0] = p0.x; r[1] = p0.y; r[2] = p1.x; r[3] = p1.y;
    r[4] = p2.x; r[5] = p2.y; r[6] = p3.x; r[7] = p3.y;
    return r;
}
__device__ __forceinline__ short8 loadArow(const float* rowp, int h, int q) {
    const float* p = rowp + h * 32 + q * 8;
    return cvt8(*(const float4*)p, *(const float4*)(p + 4));
}
__device__ __forceinline__ short8 loadB(const short* P, int t, int h, int l) {
    return *(const short8*)(P + (((t * 2 + h) * 64 + l) << 3));
}

// ---------------------------------------------------------------------------
// Species counting sort — contention-free, deterministic. sort1 also zeroes
// the receiver-CSR counts array (replaces the memset dispatch).
// ---------------------------------------------------------------------------
__global__ __launch_bounds__(256) void sort1_kernel(
    const int* __restrict__ species, int* __restrict__ counts_blk,
    int* __restrict__ lrank_arr, int* __restrict__ counts)
{
    __shared__ int wcnt[4][16];
    int n = blockIdx.x * 256 + threadIdx.x;
    counts[n] = 0;
    int sp = species[n];
    int lane = threadIdx.x & 63, wv = threadIdx.x >> 6;
    unsigned long long ltmask = (1ull << lane) - 1;
    int lrank_w = 0;
#pragma unroll
    for (int z = 0; z < NSPEC; ++z) {
        unsigned long long m = __ballot(sp == z);
        if (sp == z) lrank_w = __popcll(m & ltmask);
        if (lane == 0) wcnt[wv][z] = __popcll(m);
    }
    __syncthreads();
    int off = 0;
    for (int w = 0; w < wv; ++w) off += wcnt[w][sp];
    lrank_arr[n] = lrank_w + off;
    if (threadIdx.x < NSPEC)
        counts_blk[blockIdx.x * NSPEC + threadIdx.x] =
            wcnt[0][threadIdx.x] + wcnt[1][threadIdx.x] +
            wcnt[2][threadIdx.x] + wcnt[3][threadIdx.x];
}

// parallel block-offset scan: wave z shuffle-scans its 128 block counts
__global__ __launch_bounds__(640) void sort2_kernel(
    const int* __restrict__ counts_blk, int* __restrict__ off_blk)
{
    __shared__ int totals[16];
    int wv = threadIdx.x >> 6;        // 0..9 == species z
    int lane = threadIdx.x & 63;
    int c0 = counts_blk[lane * NSPEC + wv];
    int c1 = counts_blk[(64 + lane) * NSPEC + wv];
    int s0 = c0;
#pragma unroll
    for (int off = 1; off < 64; off <<= 1) {
        int y = __shfl_up(s0, off);
        if (lane >= off) s0 += y;
    }
    int tot0 = __shfl(s0, 63);
    int s1 = c1;
#pragma unroll
    for (int off = 1; off < 64; off <<= 1) {
        int y = __shfl_up(s1, off);
        if (lane >= off) s1 += y;
    }
    s1 += tot0;
    if (lane == 63) totals[wv] = s1;
    __syncthreads();
    int base = 0;
    for (int q = 0; q < wv; ++q) base += totals[q];
    off_blk[lane * NSPEC + wv] = base + s0 - c0;
    off_blk[(64 + lane) * NSPEC + wv] = base + s1 - c1;
}

__global__ __launch_bounds__(256) void sort3_kernel(
    const int* __restrict__ species, const int* __restrict__ lrank_arr,
    const int* __restrict__ off_blk,
    int* __restrict__ sidx, int* __restrict__ rank, int* __restrict__ spec_srt)
{
    int n = blockIdx.x * 256 + threadIdx.x;
    int sp = species[n];
    int slot = off_blk[blockIdx.x * NSPEC + sp] + lrank_arr[n];
    sidx[slot] = n;
    rank[n] = slot;
    spec_srt[slot] = sp;
}

// ---------------------------------------------------------------------------
// Receiver CSR in SORTED space
// ---------------------------------------------------------------------------
__global__ __launch_bounds__(256) void hist_kernel(
    const int* __restrict__ receivers, const int* __restrict__ rank,
    int* __restrict__ counts)
{
    int e = blockIdx.x * 256 + threadIdx.x;
    atomicAdd(&counts[rank[receivers[e]]], 1);
}

__global__ __launch_bounds__(1024) void scan_kernel(
    const int* __restrict__ counts, int* __restrict__ row_start, int* __restrict__ cursor)
{
    __shared__ int wave_tot[16];
    int tid = threadIdx.x;
    int c[32];
    int sum = 0;
#pragma unroll
    for (int i = 0; i < 32; ++i) { c[i] = counts[tid * 32 + i]; sum += c[i]; }
    int lane = tid & 63, wv = tid >> 6;
    int x = sum;
#pragma unroll
    for (int off = 1; off < 64; off <<= 1) {
        int y = __shfl_up(x, off);
        if (lane >= off) x += y;
    }
    if (lane == 63) wave_tot[wv] = x;
    __syncthreads();
    if (wv == 0 && lane < 16) {
        int t = wave_tot[lane];
#pragma unroll
        for (int off = 1; off < 16; off <<= 1) {
            int y = __shfl_up(t, off);
            if (lane >= off) t += y;
        }
        wave_tot[lane] = t;
    }
    __syncthreads();
    int excl = x - sum + (wv ? wave_tot[wv - 1] : 0);
    int run = excl;
#pragma unroll
    for (int i = 0; i < 32; ++i) {
        row_start[tid * 32 + i] = run;
        cursor[tid * 32 + i] = run;
        run += c[i];
    }
    if (tid == 1023) row_start[32768] = run;
}

__global__ __launch_bounds__(256) void scatter_kernel(
    const int* __restrict__ receivers, const int* __restrict__ rank,
    int* __restrict__ cursor, int* __restrict__ edge_ids)
{
    int e = blockIdx.x * 256 + threadIdx.x;
    int slot = atomicAdd(&cursor[rank[receivers[e]]], 1);
    edge_ids[slot] = e;
}

// per-row insertion sort in LDS + grp_row binary search (both need row_start)
__global__ __launch_bounds__(256) void rowsort_kernel(
    const int* __restrict__ row_start, int* __restrict__ edge_ids,
    int* __restrict__ grp_row)
{
    __shared__ int buf[256 * 33];
    int i = blockIdx.x * 256 + threadIdx.x;
    int beg = row_start[i], end = row_start[i + 1];
    int len = end - beg;
    int* b = buf + threadIdx.x * 33;
    if (len <= 32) {
        for (int j = 0; j < len; ++j) b[j] = edge_ids[beg + j];
        for (int a = 1; a < len; ++a) {
            int key = b[a];
            int c = a - 1;
            while (c >= 0 && b[c] > key) { b[c + 1] = b[c]; --c; }
            b[c + 1] = key;
        }
        for (int j = 0; j < len; ++j) edge_ids[beg + j] = b[j];
    } else {
        for (int a = beg + 1; a < end; ++a) {
            int key = edge_ids[a];
            int c = a - 1;
            while (c >= beg && edge_ids[c] > key) { edge_ids[c + 1] = edge_ids[c]; --c; }
            edge_ids[c + 1] = key;
        }
    }
    // grp_row[g]: row containing slot 16g
    if (i < N_EDGES / 16) {
        int target = i * 16;
        int lo = 0, hi = N_NODES - 1;
        while (lo < hi) {
            int mid = (lo + hi + 1) >> 1;
            if (row_start[mid] <= target) lo = mid; else hi = mid - 1;
        }
        grp_row[i] = lo;
    }
}

// ---------------------------------------------------------------------------
// Edge precompute in slot order + fused sender-rank stream
// ---------------------------------------------------------------------------
__global__ __launch_bounds__(256) void edge_pre_kernel(
    const float* __restrict__ vectors, const int* __restrict__ edge_ids,
    const int* __restrict__ senders, const int* __restrict__ rank,
    float* __restrict__ edata, int* __restrict__ srk)
{
    int p = blockIdx.x * 256 + threadIdx.x;
    int e = edge_ids[p];
    srk[p] = rank[senders[e]];
    float x = vectors[e * 3 + 0], y = vectors[e * 3 + 1], z = vectors[e * 3 + 2];
    float r2 = x * x + y * y + z * z + 1e-12f;
    float r = sqrtf(r2);
    float inv = 1.0f / r;
    float* d = edata + (size_t)p * 16;
    *(float4*)d = make_float4(x * inv, y * inv, z * inv, 0.0f);
    float rc = fmaxf(r, 1e-6f);
    float r6 = r2 * r2 * r2;
    float r7 = r6 * r;
    float r8 = r6 * r2;
    float env = (r < 1.0f) ? (1.0f - 28.0f * r6 + 48.0f * r7 - 21.0f * r8) : 0.0f;
    float sc = 1.41421356237309515f * env / rc;
#pragma unroll
    for (int j = 0; j < 8; ++j)
        d[4 + j] = sc * sinf((float)(j + 1) * 3.14159265358979323846f * rc);
    d[12] = 0.f; d[13] = 0.f; d[14] = 0.f; d[15] = 0.f;
}

// ---------------------------------------------------------------------------
// Merged prep: init_s (all 8192 blocks) + pack (blocks<448) + zero_bnd for
// interaction 0 (blocks<2048). All independent; needs spec_srt + row_start.
// ---------------------------------------------------------------------------
__global__ __launch_bounds__(256) void prep_kernel(
    const float* __restrict__ embed_s, const int* __restrict__ spec_srt,
    float* __restrict__ s,
    const float* __restrict__ Wls, const float* __restrict__ Wlv,
    const float* __restrict__ Wps, const float* __restrict__ Wpv,
    const float* __restrict__ skip_s, const float* __restrict__ skip_v,
    short* __restrict__ packW,
    const int* __restrict__ row_start,
    float* __restrict__ agg_s, float* __restrict__ agg_v)
{
    int idx = blockIdx.x * 256 + threadIdx.x;
    s[idx] = embed_s[spec_srt[idx >> 6] * 64 + (idx & 63)];

    if (blockIdx.x < 448) {
        int pidx = idx;
        if (pidx < 28 * 4096) {
            int m = pidx >> 12, e = pidx & 4095;
            int t = e >> 10, h = (e >> 9) & 1, l = (e >> 3) & 63, j = e & 7;
            int fi = h * 32 + ((l >> 4) << 3) + j;
            int fo = t * 16 + (l & 15);
            const float* src;
            if      (m < 2)  src = Wls    + m * 4096;
            else if (m < 4)  src = Wlv    + (m - 2) * 4096;
            else if (m < 6)  src = Wps    + (m - 4) * 4096;
            else if (m < 8)  src = Wpv    + (m - 6) * 4096;
            else if (m < 18) src = skip_s + (m - 8) * 4096;
            else             src = skip_v + (m - 18) * 4096;
            packW[pidx] = cvt2(src[fi * 64 + fo], 0.f).x;
        }
    }
    if (blockIdx.x < 2048) {
        const int wid = threadIdx.x >> 6;
        const int f = threadIdx.x & 63;
        const int base = (blockIdx.x * 4 + wid) * 4;
#pragma unroll
        for (int t = 0; t < 4; ++t) {
            int i = base + t;
            int beg = row_start[i], end = row_start[i + 1];
            bool need = (end == beg) || (end > (((beg >> 4) + 1) << 4));
            if (need) {
                agg_s[(size_t)i * 64 + f] = 0.f;
                agg_v[((size_t)i * 3 + 0) * 64 + f] = 0.f;
                agg_v[((size_t)i * 3 + 1) * 64 + f] = 0.f;
                agg_v[((size_t)i * 3 + 2) * 64 + f] = 0.f;
            }
        }
    }
}

// ---------------------------------------------------------------------------
// Dual-chain edge-balanced gather (rolled loop — measured best, unchanged).
// ---------------------------------------------------------------------------
template<int VZERO>
__global__ __launch_bounds__(256) void gather_kernel(
    const float* __restrict__ edata, const int* __restrict__ srk,
    const int* __restrict__ row_start, const int* __restrict__ grp_row,
    const float* __restrict__ s_in, const float* __restrict__ v_in,
    const float* __restrict__ Wr_i,
    float* __restrict__ agg_s, float* __restrict__ agg_v)
{
    const int wid = threadIdx.x >> 6;
    const int f = threadIdx.x & 63;
    const int w = blockIdx.x * 4 + wid;
    const int pA0 = w * 32;
    const int pB0 = pA0 + 16;

    float wr[5][8];
#pragma unroll
    for (int j = 0; j < 8; ++j)
#pragma unroll
        for (int p = 0; p < 5; ++p)
            wr[p][j] = (VZERO && (p == 1 || p == 3 || p == 4))
                       ? 0.f : Wr_i[j * 320 + p * 64 + f];

    int rA = grp_row[2 * w], rB = grp_row[2 * w + 1];
    int begA = row_start[rA], endA = row_start[rA + 1];
    int begB = row_start[rB], endB = row_start[rB + 1];
    float aA0 = 0.f, aA1 = 0.f, aA2 = 0.f, aA3 = 0.f;
    float aB0 = 0.f, aB1 = 0.f, aB2 = 0.f, aB3 = 0.f;

    int srA_c = srk[pA0],     srB_c = srk[pB0];
    int srA_n = srk[pA0 + 1], srB_n = srk[pB0 + 1];
    float ssA = s_in[(size_t)srA_c * 64 + f];
    float ssB = s_in[(size_t)srB_c * 64 + f];
    float vA0 = 0.f, vA1 = 0.f, vA2 = 0.f, vB0 = 0.f, vB1 = 0.f, vB2 = 0.f;
    if (!VZERO) {
        vA0 = v_in[((size_t)srA_c * 3 + 0) * 64 + f];
        vA1 = v_in[((size_t)srA_c * 3 + 1) * 64 + f];
        vA2 = v_in[((size_t)srA_c * 3 + 2) * 64 + f];
        vB0 = v_in[((size_t)srB_c * 3 + 0) * 64 + f];
        vB1 = v_in[((size_t)srB_c * 3 + 1) * 64 + f];
        vB2 = v_in[((size_t)srB_c * 3 + 2) * 64 + f];
    }

    for (int k = 0; k < 16; ++k) {
        int pA = pA0 + k, pB = pB0 + k;
        int srA_n2 = (k + 2 < 16) ? srk[pA + 2] : srA_n;
        int srB_n2 = (k + 2 < 16) ? srk[pB + 2] : srB_n;
        float ssA_n = s_in[(size_t)srA_n * 64 + f];
        float ssB_n = s_in[(size_t)srB_n * 64 + f];
        float vA0n = 0.f, vA1n = 0.f, vA2n = 0.f;
        float vB0n = 0.f, vB1n = 0.f, vB2n = 0.f;
        if (!VZERO) {
            vA0n = v_in[((size_t)srA_n * 3 + 0) * 64 + f];
            vA1n = v_in[((size_t)srA_n * 3 + 1) * 64 + f];
            vA2n = v_in[((size_t)srA_n * 3 + 2) * 64 + f];
            vB0n = v_in[((size_t)srB_n * 3 + 0) * 64 + f];
            vB1n = v_in[((size_t)srB_n * 3 + 1) * 64 + f];
            vB2n = v_in[((size_t)srB_n * 3 + 2) * 64 + f];
        }
        const float* dA = edata + (size_t)pA * 16;
        const float* dB = edata + (size_t)pB * 16;
        float4 yA = *(const float4*)dA;
        float4 qA0 = *(const float4*)(dA + 4);
        float4 qA1 = *(const float4*)(dA + 8);
        float4 yB = *(const float4*)dB;
        float4 qB0 = *(const float4*)(dB + 4);
        float4 qB1 = *(const float4*)(dB + 8);

        float rbA[8] = {qA0.x, qA0.y, qA0.z, qA0.w, qA1.x, qA1.y, qA1.z, qA1.w};
        float rbB[8] = {qB0.x, qB0.y, qB0.z, qB0.w, qB1.x, qB1.y, qB1.z, qB1.w};
        float wA0 = 0.f, wA1 = 0.f, wA2 = 0.f, wA3 = 0.f, wA4 = 0.f;
        float wB0 = 0.f, wB1 = 0.f, wB2 = 0.f, wB3 = 0.f, wB4 = 0.f;
#pragma unroll
        for (int j = 0; j < 8; ++j) {
            wA0 = fmaf(rbA[j], wr[0][j], wA0);  wB0 = fmaf(rbB[j], wr[0][j], wB0);
            if (!VZERO) { wA1 = fmaf(rbA[j], wr[1][j], wA1);  wB1 = fmaf(rbB[j], wr[1][j], wB1); }
            wA2 = fmaf(rbA[j], wr[2][j], wA2);  wB2 = fmaf(rbB[j], wr[2][j], wB2);
            if (!VZERO) { wA3 = fmaf(rbA[j], wr[3][j], wA3);  wB3 = fmaf(rbB[j], wr[3][j], wB3); }
            if (!VZERO) { wA4 = fmaf(rbA[j], wr[4][j], wA4);  wB4 = fmaf(rbB[j], wr[4][j], wB4); }
        }
        if (VZERO) {
            aA0 += wA0 * ssA;
            float wsA = wA2 * ssA;
            aA1 += wsA * yA.x; aA2 += wsA * yA.y; aA3 += wsA * yA.z;
            aB0 += wB0 * ssB;
            float wsB = wB2 * ssB;
            aB1 += wsB * yB.x; aB2 += wsB * yB.y; aB3 += wsB * yB.z;
        } else {
            float dotA = vA0 * yA.x + vA1 * yA.y + vA2 * yA.z;
            aA0 += wA0 * ssA + wA1 * dotA;
            float cA0 = vA1 * yA.z - vA2 * yA.y;
            float cA1 = vA2 * yA.x - vA0 * yA.z;
            float cA2 = vA0 * yA.y - vA1 * yA.x;
            float wsA = wA2 * ssA;
            aA1 += wsA * yA.x + wA3 * vA0 + wA4 * cA0;
            aA2 += wsA * yA.y + wA3 * vA1 + wA4 * cA1;
            aA3 += wsA * yA.z + wA3 * vA2 + wA4 * cA2;
            float dotB = vB0 * yB.x + vB1 * yB.y + vB2 * yB.z;
            aB0 += wB0 * ssB + wB1 * dotB;
            float cB0 = vB1 * yB.z - vB2 * yB.y;
            float cB1 = vB2 * yB.x - vB0 * yB.z;
            float cB2 = vB0 * yB.y - vB1 * yB.x;
            float wsB = wB2 * ssB;
            aB1 += wsB * yB.x + wB3 * vB0 + wB4 * cB0;
            aB2 += wsB * yB.y + wB3 * vB1 + wB4 * cB1;
            aB3 += wsB * yB.z + wB3 * vB2 + wB4 * cB2;
        }

        if (pA + 1 == endA || k == 15) {
            bool interior = (begA >= pA0) && (endA <= pA0 + 16);
            if (interior) {
                agg_s[(size_t)rA * 64 + f] = aA0;
                agg_v[((size_t)rA * 3 + 0) * 64 + f] = aA1;
                agg_v[((size_t)rA * 3 + 1) * 64 + f] = aA2;
                agg_v[((size_t)rA * 3 + 2) * 64 + f] = aA3;
            } else {
                unsafeAtomicAdd(&agg_s[(size_t)rA * 64 + f], aA0);
                unsafeAtomicAdd(&agg_v[((size_t)rA * 3 + 0) * 64 + f], aA1);
                unsafeAtomicAdd(&agg_v[((size_t)rA * 3 + 1) * 64 + f], aA2);
                unsafeAtomicAdd(&agg_v[((size_t)rA * 3 + 2) * 64 + f], aA3);
            }
            aA0 = aA1 = aA2 = aA3 = 0.f;
            if (pA + 1 == endA && k < 15) {
                begA = endA; ++rA; endA = row_start[rA + 1];
                while (endA == begA) { ++rA; endA = row_start[rA + 1]; }
            }
        }
        if (pB + 1 == endB || k == 15) {
            bool interior = (begB >= pB0) && (endB <= pB0 + 16);
            if (interior) {
                agg_s[(size_t)rB * 64 + f] = aB0;
                agg_v[((size_t)rB * 3 + 0) * 64 + f] = aB1;
                agg_v[((size_t)rB * 3 + 1) * 64 + f] = aB2;
                agg_v[((size_t)rB * 3 + 2) * 64 + f] = aB3;
            } else {
                unsafeAtomicAdd(&agg_s[(size_t)rB * 64 + f], aB0);
                unsafeAtomicAdd(&agg_v[((size_t)rB * 3 + 0) * 64 + f], aB1);
                unsafeAtomicAdd(&agg_v[((size_t)rB * 3 + 1) * 64 + f], aB2);
                unsafeAtomicAdd(&agg_v[((size_t)rB * 3 + 2) * 64 + f], aB3);
            }
            aB0 = aB1 = aB2 = aB3 = 0.f;
            if (pB + 1 == endB && k < 15) {
                begB = endB; ++rB; endB = row_start[rB + 1];
                while (endB == begB) { ++rB; endB = row_start[rB + 1]; }
            }
        }
        ssA = ssA_n; vA0 = vA0n; vA1 = vA1n; vA2 = vA2n;
        ssB = ssB_n; vB0 = vB0n; vB1 = vB1n; vB2 = vB2n;
        srA_c = srA_n; srA_n = srA_n2;
        srB_c = srB_n; srB_n = srB_n2;
    }
}

// ---------------------------------------------------------------------------
// MFMA node kernel with FUSED readout and (it==0) fused zeroing of its own
// agg rows for the next interaction. wave = 16 sorted nodes.
// ---------------------------------------------------------------------------
__global__ __launch_bounds__(256) void node_mfma_kernel(
    const float* __restrict__ agg_s, const float* __restrict__ agg_v,
    float* s, float* v,
    const short* __restrict__ packW, int it,
    const float* __restrict__ pw_i,
    const int* __restrict__ spec_srt,
    const int* __restrict__ row_start, const int* __restrict__ sidx,
    const float* __restrict__ Wread0, const float* __restrict__ Wr1a,
    const float* __restrict__ Wr1b,
    float* __restrict__ out,
    int has_skip)
{
    const int l = threadIdx.x & 63;
    const int wid = threadIdx.x >> 6;
    const int cl = l & 15;
    const int q = l >> 4;
    const int i16 = (blockIdx.x * 4 + wid) * 16;
    __shared__ float xls_all[4][16 * 65];
    float* xls = xls_all[wid];

    const short* pWls = packW + (size_t)(0 + it) * 4096;
    const short* pWlv = packW + (size_t)(2 + it) * 4096;
    const short* pWps = packW + (size_t)(4 + it) * 4096;
    const short* pWpv = packW + (size_t)(6 + it) * 4096;
    const short* pSkS = packW + (size_t)8 * 4096;
    const short* pSkV = packW + (size_t)18 * 4096;
    const short8 z8 = {0, 0, 0, 0, 0, 0, 0, 0};

    const float* ars = agg_s + (size_t)(i16 + cl) * 64;
    short8 As[2] = { loadArow(ars, 0, q), loadArow(ars, 1, q) };
    short8 Av[3][2];
#pragma unroll
    for (int k = 0; k < 3; ++k) {
        const float* r = agg_v + ((size_t)(i16 + cl) * 3 + k) * 64;
        Av[k][0] = loadArow(r, 0, q);
        Av[k][1] = loadArow(r, 1, q);
    }

    f32x4 sD[4];
#pragma unroll
    for (int t = 0; t < 4; ++t) {
        f32x4 acc = {0.f, 0.f, 0.f, 0.f};
        acc = MFMA16(As[0], loadB(pWls, t, 0, l), acc);
        acc = MFMA16(As[1], loadB(pWls, t, 1, l), acc);
        sD[t] = acc;
    }

    f32x4 vD[3][4];
#pragma unroll
    for (int k = 0; k < 3; ++k)
#pragma unroll
        for (int t = 0; t < 4; ++t) vD[k][t] = (f32x4){0.f, 0.f, 0.f, 0.f};
#pragma unroll
    for (int t = 0; t < 4; ++t)
#pragma unroll
        for (int h = 0; h < 2; ++h) {
            short8 b = loadB(pWlv, t, h, l);
#pragma unroll
            for (int k = 0; k < 3; ++k) vD[k][t] = MFMA16(Av[k][h], b, vD[k][t]);
        }

    int z0 = spec_srt[i16], z1 = spec_srt[i16 + 15];
    float psD[4][4], pvsD[4][4];
    if (z0 == z1) {
        const float* pb = pw_i + z0 * 576 + cl;
        float pc[9][4];
#pragma unroll
        for (int c = 0; c < 9; ++c)
#pragma unroll
            for (int t = 0; t < 4; ++t) pc[c][t] = pb[c * 64 + t * 16];
#pragma unroll
        for (int t = 0; t < 4; ++t)
#pragma unroll
            for (int r = 0; r < 4; ++r) {
                float x = sD[t][r] * EPS_C;
                float w0 = vD[0][t][r] * EPS_C;
                float w1 = vD[1][t][r] * EPS_C;
                float w2 = vD[2][t][r] * EPS_C;
                vD[0][t][r] = w0; vD[1][t][r] = w1; vD[2][t][r] = w2;
                float vv = w0 * w0 + w1 * w1 + w2 * w2;
                float x2 = x * x;
                psD[t][r] = pc[0][t] * x + pc[1][t] * x2 + pc[2][t] * vv
                          + pc[3][t] * x2 * x + pc[4][t] * x * vv;
                pvsD[t][r] = pc[5][t] + pc[6][t] * x + pc[7][t] * x2 + pc[8][t] * vv;
            }
    } else {
#pragma unroll
        for (int r = 0; r < 4; ++r) {
            int z = spec_srt[i16 + q * 4 + r];
            const float* pb = pw_i + z * 576 + cl;
#pragma unroll
            for (int t = 0; t < 4; ++t) {
                float p0 = pb[t*16], p1 = pb[64+t*16], p2 = pb[128+t*16];
                float p3 = pb[192+t*16], p4 = pb[256+t*16], p5 = pb[320+t*16];
                float p6 = pb[384+t*16], p7 = pb[448+t*16], p8 = pb[512+t*16];
                float x = sD[t][r] * EPS_C;
                float w0 = vD[0][t][r] * EPS_C;
                float w1 = vD[1][t][r] * EPS_C;
                float w2 = vD[2][t][r] * EPS_C;
                vD[0][t][r] = w0; vD[1][t][r] = w1; vD[2][t][r] = w2;
                float vv = w0 * w0 + w1 * w1 + w2 * w2;
                float x2 = x * x;
                psD[t][r] = p0 * x + p1 * x2 + p2 * vv + p3 * x2 * x + p4 * x * vv;
                pvsD[t][r] = p5 + p6 * x + p7 * x2 + p8 * vv;
            }
        }
    }

#pragma unroll
    for (int t = 0; t < 4; ++t)
#pragma unroll
        for (int r = 0; r < 4; ++r)
            xls[(q * 4 + r) * 65 + t * 16 + cl] = psD[t][r];
    short8 psA[2];
#pragma unroll
    for (int h = 0; h < 2; ++h) {
        const float* rp = xls + cl * 65 + h * 32 + q * 8;
        float t0 = rp[0], t1 = rp[1], t2 = rp[2], t3 = rp[3];
        float t4 = rp[4], t5 = rp[5], t6 = rp[6], t7 = rp[7];
        psA[h] = cvt8(make_float4(t0, t1, t2, t3), make_float4(t4, t5, t6, t7));
    }

    f32x4 snD[4];
#pragma unroll
    for (int t = 0; t < 4; ++t) {
        f32x4 acc = {0.f, 0.f, 0.f, 0.f};
        acc = MFMA16(psA[0], loadB(pWps, t, 0, l), acc);
        acc = MFMA16(psA[1], loadB(pWps, t, 1, l), acc);
        snD[t] = acc;
    }
    if (has_skip) {
        const float* srow = s + (size_t)(i16 + cl) * 64;
        short8 Ai0 = loadArow(srow, 0, q), Ai1 = loadArow(srow, 1, q);
        int myz = spec_srt[i16 + cl];
        for (int z = z0; z <= z1; ++z) {
            bool keep = (myz == z);
            short8 m0 = keep ? Ai0 : z8;
            short8 m1 = keep ? Ai1 : z8;
            const short* pz = pSkS + (size_t)z * 4096;
#pragma unroll
            for (int t = 0; t < 4; ++t) {
                snD[t] = MFMA16(m0, loadB(pz, t, 0, l), snD[t]);
                snD[t] = MFMA16(m1, loadB(pz, t, 1, l), snD[t]);
            }
        }
    }
#pragma unroll
    for (int t = 0; t < 4; ++t)
#pragma unroll
        for (int r = 0; r < 4; ++r)
            s[(size_t)(i16 + q * 4 + r) * 64 + t * 16 + cl] = snD[t][r];

    // ---- FUSED readout
    if (it == 0) {
        // linear readout: out[n,0] = sum_ch s_new[n,ch] * Wread0[ch]
        float w0c[4];
#pragma unroll
        for (int t = 0; t < 4; ++t) w0c[t] = Wread0[t * 16 + cl];
#pragma unroll
        for (int r = 0; r < 4; ++r) {
            float a = snD[0][r] * w0c[0] + snD[1][r] * w0c[1]
                    + snD[2][r] * w0c[2] + snD[3][r] * w0c[3];
            a += __shfl_down(a, 8);
            a += __shfl_down(a, 4);
            a += __shfl_down(a, 2);
            a += __shfl_down(a, 1);
            if (cl == 0) out[(size_t)sidx[i16 + q * 4 + r] * 2 + 0] = a;
        }
    } else {
        // nonlinear readout: silu(s_new @ Wr1a) @ Wr1b
        // stage s_new in wave-private LDS (xls free; rewritten by pv below)
#pragma unroll
        for (int t = 0; t < 4; ++t)
#pragma unroll
            for (int r = 0; r < 4; ++r)
                xls[(q * 4 + r) * 65 + t * 16 + cl] = snD[t][r];
        // lane l: hidden hh=cl, nodes q+4j (j=0..3)
        float acc4[4] = {0.f, 0.f, 0.f, 0.f};
        for (int g = 0; g < 64; ++g) {
            float wa = Wr1a[g * 16 + cl];
#pragma unroll
            for (int j = 0; j < 4; ++j)
                acc4[j] = fmaf(xls[(q + 4 * j) * 65 + g], wa, acc4[j]);
        }
        float wb = Wr1b[cl];
#pragma unroll
        for (int j = 0; j < 4; ++j) {
            float av = acc4[j];
            float rr = (av / (1.f + expf(-av))) * wb;
            rr += __shfl_down(rr, 8);
            rr += __shfl_down(rr, 4);
            rr += __shfl_down(rr, 2);
            rr += __shfl_down(rr, 1);
            if (cl == 0) out[(size_t)sidx[i16 + q + 4 * j] * 2 + 1] = rr;
        }
    }

    short8 pvA[3][2];
#pragma unroll
    for (int k = 0; k < 3; ++k) {
#pragma unroll
        for (int t = 0; t < 4; ++t)
#pragma unroll
            for (int r = 0; r < 4; ++r)
                xls[(q * 4 + r) * 65 + t * 16 + cl] = pvsD[t][r] * vD[k][t][r];
#pragma unroll
        for (int h = 0; h < 2; ++h) {
            const float* rp = xls + cl * 65 + h * 32 + q * 8;
            float t0 = rp[0], t1 = rp[1], t2 = rp[2], t3 = rp[3];
            float t4 = rp[4], t5 = rp[5], t6 = rp[6], t7 = rp[7];
            pvA[k][h] = cvt8(make_float4(t0, t1, t2, t3), make_float4(t4, t5, t6, t7));
        }
    }

    f32x4 vnD[3][4];
#pragma unroll
    for (int k = 0; k < 3; ++k)
#pragma unroll
        for (int t = 0; t < 4; ++t) vnD[k][t] = (f32x4){0.f, 0.f, 0.f, 0.f};
#pragma unroll
    for (int t = 0; t < 4; ++t)
#pragma unroll
        for (int h = 0; h < 2; ++h) {
            short8 b = loadB(pWpv, t, h, l);
#pragma unroll
            for (int k = 0; k < 3; ++k) vnD[k][t] = MFMA16(pvA[k][h], b, vnD[k][t]);
        }
    if (has_skip) {
        short8 Aiv[3][2];
#pragma unroll
        for (int k = 0; k < 3; ++k) {
            const float* r = v + ((size_t)(i16 + cl) * 3 + k) * 64;
            Aiv[k][0] = loadArow(r, 0, q);
            Aiv[k][1] = loadArow(r, 1, q);
        }
        int myz = spec_srt[i16 + cl];
        for (int z = z0; z <= z1; ++z) {
            bool keep = (myz == z);
            const short* pz = pSkV + (size_t)z * 4096;
#pragma unroll
            for (int t = 0; t < 4; ++t)
#pragma unroll
                for (int h = 0; h < 2; ++h) {
                    short8 b = loadB(pz, t, h, l);
#pragma unroll
                    for (int k = 0; k < 3; ++k) {
                        short8 a = keep ? Aiv[k][h] : z8;
                        vnD[k][t] = MFMA16(a, b, vnD[k][t]);
                    }
                }
        }
    }
#pragma unroll
    for (int k = 0; k < 3; ++k)
#pragma unroll
        for (int t = 0; t < 4; ++t)
#pragma unroll
            for (int r = 0; r < 4; ++r)
                v[((size_t)(i16 + q * 4 + r) * 3 + k) * 64 + t * 16 + cl] = vnD[k][t][r];

    // ---- it==0: zero this wave's own agg boundary rows for interaction 1.
    // Safe: this block already consumed agg rows i16..i16+15 above, and no
    // other block touches them; gather<0> runs in a later dispatch.
    if (it == 0) {
        for (int rr = 0; rr < 16; ++rr) {
            int i = i16 + rr;
            int beg = row_start[i], end = row_start[i + 1];
            bool need = (end == beg) || (end > (((beg >> 4) + 1) << 4));
            if (need) {
                float* as = (float*)agg_s;
                float* av = (float*)agg_v;
                as[(size_t)i * 64 + l] = 0.f;
                av[((size_t)i * 3 + 0) * 64 + l] = 0.f;
                av[((size_t)i * 3 + 1) * 64 + l] = 0.f;
                av[((size_t)i * 3 + 2) * 64 + l] = 0.f;
            }
        }
    }
}

// ---------------------------------------------------------------------------
extern "C" void kernel_launch(void* const* d_in, const int* in_sizes, int n_in,
                              void* d_out, int out_size, void* d_ws, size_t ws_size,
                              hipStream_t stream)
{
    const float* vectors = (const float*)d_in[0];
    const float* embed_s = (const float*)d_in[1];
    const float* Wr      = (const float*)d_in[2];   // [2,8,320]
    const float* Wls     = (const float*)d_in[3];   // [2,64,64]
    const float* Wlv     = (const float*)d_in[4];
    const float* skip_s  = (const float*)d_in[5];   // [10,64,64]
    const float* skip_v  = (const float*)d_in[6];
    const float* pw      = (const float*)d_in[7];   // [2,10,9,64]
    const float* Wps     = (const float*)d_in[8];
    const float* Wpv     = (const float*)d_in[9];
    const float* Wread0  = (const float*)d_in[10];  // [64,1]
    const float* Wr1a    = (const float*)d_in[11];  // [64,16]
    const float* Wr1b    = (const float*)d_in[12];  // [16,1]
    const int* senders   = (const int*)d_in[13];
    const int* receivers = (const int*)d_in[14];
    const int* species   = (const int*)d_in[15];
    float* out = (float*)d_out;

    float* ws = (float*)d_ws;
    float* edata = ws; ws += (size_t)N_EDGES * 16;  // 16 MB (slot-ordered)
    float* s     = ws; ws += (size_t)N_NODES * 64;  // 8 MB
    float* v     = ws; ws += (size_t)N_NODES * 192; // 24 MB
    float* agg_s = ws; ws += (size_t)N_NODES * 64;  // 8 MB
    float* agg_v = ws; ws += (size_t)N_NODES * 192; // 24 MB
    int* counts    = (int*)ws; ws += N_NODES;
    int* row_start = (int*)ws; ws += N_NODES + 4;
    int* cursor    = (int*)ws; ws += N_NODES;
    int* edge_ids  = (int*)ws; ws += N_EDGES;
    int* srk       = (int*)ws; ws += N_EDGES;
    int* grp_row   = (int*)ws; ws += N_EDGES / 16;
    int* sidx      = (int*)ws; ws += N_NODES;
    int* rank      = (int*)ws; ws += N_NODES;
    int* spec_srt  = (int*)ws; ws += N_NODES;
    int* lrank_arr = (int*)ws; ws += N_NODES;
    int* counts_blk = (int*)ws; ws += 128 * NSPEC;
    int* off_blk    = (int*)ws; ws += 128 * NSPEC;
    short* packW   = (short*)ws;                    // 224 KB

    // species counting sort (sort1 also zeroes CSR counts)
    sort1_kernel<<<N_NODES / 256, 256, 0, stream>>>(
        species, counts_blk, lrank_arr, counts);
    sort2_kernel<<<1, 640, 0, stream>>>(counts_blk, off_blk);
    sort3_kernel<<<N_NODES / 256, 256, 0, stream>>>(
        species, lrank_arr, off_blk, sidx, rank, spec_srt);

    // receiver CSR in sorted space, deterministic row order
    hist_kernel<<<N_EDGES / 256, 256, 0, stream>>>(receivers, rank, counts);
    scan_kernel<<<1, 1024, 0, stream>>>(counts, row_start, cursor);
    scatter_kernel<<<N_EDGES / 256, 256, 0, stream>>>(receivers, rank, cursor, edge_ids);
    rowsort_kernel<<<N_NODES / 256, 256, 0, stream>>>(row_start, edge_ids, grp_row);

    // edge features + sender ranks in slot order
    edge_pre_kernel<<<N_EDGES / 256, 256, 0, stream>>>(
        vectors, edge_ids, senders, rank, edata, srk);

    // merged prep: init_s + weight pack + zero boundary agg rows (i0)
    prep_kernel<<<N_NODES * 64 / 256, 256, 0, stream>>>(
        embed_s, spec_srt, s, Wls, Wlv, Wps, Wpv, skip_s, skip_v, packW,
        row_start, agg_s, agg_v);

    // interaction 0 (node fuses read0 + zeroing boundary rows for i1)
    gather_kernel<1><<<N_EDGES / 32 / 4, 256, 0, stream>>>(
        edata, srk, row_start, grp_row, s, v, Wr, agg_s, agg_v);
    node_mfma_kernel<<<N_NODES / 64, 256, 0, stream>>>(
        agg_s, agg_v, s, v, packW, 0, pw, spec_srt,
        row_start, sidx, Wread0, Wr1a, Wr1b, out, 0);

    // interaction 1 (node fuses read1)
    gather_kernel<0><<<N_EDGES / 32 / 4, 256, 0, stream>>>(
        edata, srk, row_start, grp_row, s, v, Wr + 2560, agg_s, agg_v);
    node_mfma_kernel<<<N_NODES / 64, 256, 0, stream>>>(
        agg_s, agg_v, s, v, packW, 1, pw + 5760, spec_srt,
        row_start, sidx, Wread0, Wr1a, Wr1b, out, 1);
}

// Round 16
// 302.548 us; speedup vs baseline: 1.2329x; 1.0841x over previous
//
#include <hip/hip_runtime.h>
#include <hip/hip_bf16.h>
#include <math.h>

#define N_NODES 32768
#define N_EDGES 262144
#define EPS_C 0.24253562503633297f   // 1/sqrt(17)
#define NSPEC 10

typedef __attribute__((ext_vector_type(8))) short short8;   // 8 bf16
typedef __attribute__((ext_vector_type(4))) float f32x4;    // 4 fp32 acc

#define MFMA16(a, b, c) __builtin_amdgcn_mfma_f32_16x16x32_bf16(a, b, c, 0, 0, 0)

__device__ __forceinline__ short2 cvt2(float a, float b) {
    union { __hip_bfloat162 h; short2 s; } u;
    u.h = __float22bfloat162_rn(make_float2(a, b));
    return u.s;
}
__device__ __forceinline__ short8 cvt8(float4 a, float4 b) {
    short2 p0 = cvt2(a.x, a.y), p1 = cvt2(a.z, a.w);
    short2 p2 = cvt2(b.x, b.y), p3 = cvt2(b.z, b.w);
    short8 r;
    r[0] = p0.x; r[1] = p0.y; r[2] = p1.x; r[3] = p1.y;
    r[4] = p2.x; r[5] = p2.y; r[6] = p3.x; r[7] = p3.y;
    return r;
}
__device__ __forceinline__ short8 loadArow(const float* rowp, int h, int q) {
    const float* p = rowp + h * 32 + q * 8;
    return cvt8(*(const float4*)p, *(const float4*)(p + 4));
}
__device__ __forceinline__ short8 loadB(const short* P, int t, int h, int l) {
    return *(const short8*)(P + (((t * 2 + h) * 64 + l) << 3));
}

// ---------------------------------------------------------------------------
// Species counting sort — contention-free, deterministic. sort1 also zeroes
// the receiver-CSR counts array.
// ---------------------------------------------------------------------------
__global__ __launch_bounds__(256) void sort1_kernel(
    const int* __restrict__ species, int* __restrict__ counts_blk,
    int* __restrict__ lrank_arr, int* __restrict__ counts)
{
    __shared__ int wcnt[4][16];
    int n = blockIdx.x * 256 + threadIdx.x;
    counts[n] = 0;
    int sp = species[n];
    int lane = threadIdx.x & 63, wv = threadIdx.x >> 6;
    unsigned long long ltmask = (1ull << lane) - 1;
    int lrank_w = 0;
#pragma unroll
    for (int z = 0; z < NSPEC; ++z) {
        unsigned long long m = __ballot(sp == z);
        if (sp == z) lrank_w = __popcll(m & ltmask);
        if (lane == 0) wcnt[wv][z] = __popcll(m);
    }
    __syncthreads();
    int off = 0;
    for (int w = 0; w < wv; ++w) off += wcnt[w][sp];
    lrank_arr[n] = lrank_w + off;
    if (threadIdx.x < NSPEC)
        counts_blk[blockIdx.x * NSPEC + threadIdx.x] =
            wcnt[0][threadIdx.x] + wcnt[1][threadIdx.x] +
            wcnt[2][threadIdx.x] + wcnt[3][threadIdx.x];
}

// parallel block-offset scan: wave z shuffle-scans its 128 block counts
__global__ __launch_bounds__(640) void sort2_kernel(
    const int* __restrict__ counts_blk, int* __restrict__ off_blk)
{
    __shared__ int totals[16];
    int wv = threadIdx.x >> 6;        // 0..9 == species z
    int lane = threadIdx.x & 63;
    int c0 = counts_blk[lane * NSPEC + wv];
    int c1 = counts_blk[(64 + lane) * NSPEC + wv];
    int s0 = c0;
#pragma unroll
    for (int off = 1; off < 64; off <<= 1) {
        int y = __shfl_up(s0, off);
        if (lane >= off) s0 += y;
    }
    int tot0 = __shfl(s0, 63);
    int s1 = c1;
#pragma unroll
    for (int off = 1; off < 64; off <<= 1) {
        int y = __shfl_up(s1, off);
        if (lane >= off) s1 += y;
    }
    s1 += tot0;
    if (lane == 63) totals[wv] = s1;
    __syncthreads();
    int base = 0;
    for (int q = 0; q < wv; ++q) base += totals[q];
    off_blk[lane * NSPEC + wv] = base + s0 - c0;
    off_blk[(64 + lane) * NSPEC + wv] = base + s1 - c1;
}

__global__ __launch_bounds__(256) void sort3_kernel(
    const int* __restrict__ species, const int* __restrict__ lrank_arr,
    const int* __restrict__ off_blk,
    int* __restrict__ sidx, int* __restrict__ rank, int* __restrict__ spec_srt)
{
    int n = blockIdx.x * 256 + threadIdx.x;
    int sp = species[n];
    int slot = off_blk[blockIdx.x * NSPEC + sp] + lrank_arr[n];
    sidx[slot] = n;
    rank[n] = slot;
    spec_srt[slot] = sp;
}

// ---------------------------------------------------------------------------
// Receiver CSR in SORTED space
// ---------------------------------------------------------------------------
__global__ __launch_bounds__(256) void hist_kernel(
    const int* __restrict__ receivers, const int* __restrict__ rank,
    int* __restrict__ counts)
{
    int e = blockIdx.x * 256 + threadIdx.x;
    atomicAdd(&counts[rank[receivers[e]]], 1);
}

__global__ __launch_bounds__(1024) void scan_kernel(
    const int* __restrict__ counts, int* __restrict__ row_start, int* __restrict__ cursor)
{
    __shared__ int wave_tot[16];
    int tid = threadIdx.x;
    int c[32];
    int sum = 0;
#pragma unroll
    for (int i = 0; i < 32; ++i) { c[i] = counts[tid * 32 + i]; sum += c[i]; }
    int lane = tid & 63, wv = tid >> 6;
    int x = sum;
#pragma unroll
    for (int off = 1; off < 64; off <<= 1) {
        int y = __shfl_up(x, off);
        if (lane >= off) x += y;
    }
    if (lane == 63) wave_tot[wv] = x;
    __syncthreads();
    if (wv == 0 && lane < 16) {
        int t = wave_tot[lane];
#pragma unroll
        for (int off = 1; off < 16; off <<= 1) {
            int y = __shfl_up(t, off);
            if (lane >= off) t += y;
        }
        wave_tot[lane] = t;
    }
    __syncthreads();
    int excl = x - sum + (wv ? wave_tot[wv - 1] : 0);
    int run = excl;
#pragma unroll
    for (int i = 0; i < 32; ++i) {
        row_start[tid * 32 + i] = run;
        cursor[tid * 32 + i] = run;
        run += c[i];
    }
    if (tid == 1023) row_start[32768] = run;
}

__global__ __launch_bounds__(256) void scatter_kernel(
    const int* __restrict__ receivers, const int* __restrict__ rank,
    int* __restrict__ cursor, int* __restrict__ edge_ids)
{
    int e = blockIdx.x * 256 + threadIdx.x;
    int slot = atomicAdd(&cursor[rank[receivers[e]]], 1);
    edge_ids[slot] = e;
}

// ---------------------------------------------------------------------------
// Edge precompute in slot order + fused sender-rank stream + grp_row search.
// (Row-internal edge order follows scatter's atomic order — consistent
// within a launch; only affects fp32 summation order, within error budget.)
// ---------------------------------------------------------------------------
__global__ __launch_bounds__(256) void edge_pre_kernel(
    const float* __restrict__ vectors, const int* __restrict__ edge_ids,
    const int* __restrict__ senders, const int* __restrict__ rank,
    const int* __restrict__ row_start,
    float* __restrict__ edata, int* __restrict__ srk, int* __restrict__ grp_row)
{
    int p = blockIdx.x * 256 + threadIdx.x;
    int e = edge_ids[p];
    srk[p] = rank[senders[e]];
    float x = vectors[e * 3 + 0], y = vectors[e * 3 + 1], z = vectors[e * 3 + 2];
    float r2 = x * x + y * y + z * z + 1e-12f;
    float r = sqrtf(r2);
    float inv = 1.0f / r;
    float* d = edata + (size_t)p * 16;
    *(float4*)d = make_float4(x * inv, y * inv, z * inv, 0.0f);
    float rc = fmaxf(r, 1e-6f);
    float r6 = r2 * r2 * r2;
    float r7 = r6 * r;
    float r8 = r6 * r2;
    float env = (r < 1.0f) ? (1.0f - 28.0f * r6 + 48.0f * r7 - 21.0f * r8) : 0.0f;
    float sc = 1.41421356237309515f * env / rc;
#pragma unroll
    for (int j = 0; j < 8; ++j)
        d[4 + j] = sc * sinf((float)(j + 1) * 3.14159265358979323846f * rc);
    d[12] = 0.f; d[13] = 0.f; d[14] = 0.f; d[15] = 0.f;

    // grp_row[g]: row containing slot 16g
    if (p < N_EDGES / 16) {
        int target = p * 16;
        int lo = 0, hi = N_NODES - 1;
        while (lo < hi) {
            int mid = (lo + hi + 1) >> 1;
            if (row_start[mid] <= target) lo = mid; else hi = mid - 1;
        }
        grp_row[p] = lo;
    }
}

// ---------------------------------------------------------------------------
// Merged prep: init_s (all 8192 blocks) + pack (blocks<448) + zero_bnd for
// interaction 0 (blocks<2048).
// ---------------------------------------------------------------------------
__global__ __launch_bounds__(256) void prep_kernel(
    const float* __restrict__ embed_s, const int* __restrict__ spec_srt,
    float* __restrict__ s,
    const float* __restrict__ Wls, const float* __restrict__ Wlv,
    const float* __restrict__ Wps, const float* __restrict__ Wpv,
    const float* __restrict__ skip_s, const float* __restrict__ skip_v,
    short* __restrict__ packW,
    const int* __restrict__ row_start,
    float* __restrict__ agg_s, float* __restrict__ agg_v)
{
    int idx = blockIdx.x * 256 + threadIdx.x;
    s[idx] = embed_s[spec_srt[idx >> 6] * 64 + (idx & 63)];

    if (blockIdx.x < 448) {
        int pidx = idx;
        if (pidx < 28 * 4096) {
            int m = pidx >> 12, e = pidx & 4095;
            int t = e >> 10, h = (e >> 9) & 1, l = (e >> 3) & 63, j = e & 7;
            int fi = h * 32 + ((l >> 4) << 3) + j;
            int fo = t * 16 + (l & 15);
            const float* src;
            if      (m < 2)  src = Wls    + m * 4096;
            else if (m < 4)  src = Wlv    + (m - 2) * 4096;
            else if (m < 6)  src = Wps    + (m - 4) * 4096;
            else if (m < 8)  src = Wpv    + (m - 6) * 4096;
            else if (m < 18) src = skip_s + (m - 8) * 4096;
            else             src = skip_v + (m - 18) * 4096;
            packW[pidx] = cvt2(src[fi * 64 + fo], 0.f).x;
        }
    }
    if (blockIdx.x < 2048) {
        const int wid = threadIdx.x >> 6;
        const int f = threadIdx.x & 63;
        const int base = (blockIdx.x * 4 + wid) * 4;
#pragma unroll
        for (int t = 0; t < 4; ++t) {
            int i = base + t;
            int beg = row_start[i], end = row_start[i + 1];
            bool need = (end == beg) || (end > (((beg >> 4) + 1) << 4));
            if (need) {
                agg_s[(size_t)i * 64 + f] = 0.f;
                agg_v[((size_t)i * 3 + 0) * 64 + f] = 0.f;
                agg_v[((size_t)i * 3 + 1) * 64 + f] = 0.f;
                agg_v[((size_t)i * 3 + 2) * 64 + f] = 0.f;
            }
        }
    }
}

// ---------------------------------------------------------------------------
// Dual-chain edge-balanced gather (rolled loop). ONE WAVE PER BLOCK
// (64-thread blocks, 8192 blocks) for finer CU packing — no LDS/barriers.
// ---------------------------------------------------------------------------
template<int VZERO>
__global__ __launch_bounds__(64) void gather_kernel(
    const float* __restrict__ edata, const int* __restrict__ srk,
    const int* __restrict__ row_start, const int* __restrict__ grp_row,
    const float* __restrict__ s_in, const float* __restrict__ v_in,
    const float* __restrict__ Wr_i,
    float* __restrict__ agg_s, float* __restrict__ agg_v)
{
    const int f = threadIdx.x & 63;
    const int w = blockIdx.x;
    const int pA0 = w * 32;
    const int pB0 = pA0 + 16;

    float wr[5][8];
#pragma unroll
    for (int j = 0; j < 8; ++j)
#pragma unroll
        for (int p = 0; p < 5; ++p)
            wr[p][j] = (VZERO && (p == 1 || p == 3 || p == 4))
                       ? 0.f : Wr_i[j * 320 + p * 64 + f];

    int rA = grp_row[2 * w], rB = grp_row[2 * w + 1];
    int begA = row_start[rA], endA = row_start[rA + 1];
    int begB = row_start[rB], endB = row_start[rB + 1];
    float aA0 = 0.f, aA1 = 0.f, aA2 = 0.f, aA3 = 0.f;
    float aB0 = 0.f, aB1 = 0.f, aB2 = 0.f, aB3 = 0.f;

    int srA_c = srk[pA0],     srB_c = srk[pB0];
    int srA_n = srk[pA0 + 1], srB_n = srk[pB0 + 1];
    float ssA = s_in[(size_t)srA_c * 64 + f];
    float ssB = s_in[(size_t)srB_c * 64 + f];
    float vA0 = 0.f, vA1 = 0.f, vA2 = 0.f, vB0 = 0.f, vB1 = 0.f, vB2 = 0.f;
    if (!VZERO) {
        vA0 = v_in[((size_t)srA_c * 3 + 0) * 64 + f];
        vA1 = v_in[((size_t)srA_c * 3 + 1) * 64 + f];
        vA2 = v_in[((size_t)srA_c * 3 + 2) * 64 + f];
        vB0 = v_in[((size_t)srB_c * 3 + 0) * 64 + f];
        vB1 = v_in[((size_t)srB_c * 3 + 1) * 64 + f];
        vB2 = v_in[((size_t)srB_c * 3 + 2) * 64 + f];
    }

    for (int k = 0; k < 16; ++k) {
        int pA = pA0 + k, pB = pB0 + k;
        int srA_n2 = (k + 2 < 16) ? srk[pA + 2] : srA_n;
        int srB_n2 = (k + 2 < 16) ? srk[pB + 2] : srB_n;
        float ssA_n = s_in[(size_t)srA_n * 64 + f];
        float ssB_n = s_in[(size_t)srB_n * 64 + f];
        float vA0n = 0.f, vA1n = 0.f, vA2n = 0.f;
        float vB0n = 0.f, vB1n = 0.f, vB2n = 0.f;
        if (!VZERO) {
            vA0n = v_in[((size_t)srA_n * 3 + 0) * 64 + f];
            vA1n = v_in[((size_t)srA_n * 3 + 1) * 64 + f];
            vA2n = v_in[((size_t)srA_n * 3 + 2) * 64 + f];
            vB0n = v_in[((size_t)srB_n * 3 + 0) * 64 + f];
            vB1n = v_in[((size_t)srB_n * 3 + 1) * 64 + f];
            vB2n = v_in[((size_t)srB_n * 3 + 2) * 64 + f];
        }
        const float* dA = edata + (size_t)pA * 16;
        const float* dB = edata + (size_t)pB * 16;
        float4 yA = *(const float4*)dA;
        float4 qA0 = *(const float4*)(dA + 4);
        float4 qA1 = *(const float4*)(dA + 8);
        float4 yB = *(const float4*)dB;
        float4 qB0 = *(const float4*)(dB + 4);
        float4 qB1 = *(const float4*)(dB + 8);

        float rbA[8] = {qA0.x, qA0.y, qA0.z, qA0.w, qA1.x, qA1.y, qA1.z, qA1.w};
        float rbB[8] = {qB0.x, qB0.y, qB0.z, qB0.w, qB1.x, qB1.y, qB1.z, qB1.w};
        float wA0 = 0.f, wA1 = 0.f, wA2 = 0.f, wA3 = 0.f, wA4 = 0.f;
        float wB0 = 0.f, wB1 = 0.f, wB2 = 0.f, wB3 = 0.f, wB4 = 0.f;
#pragma unroll
        for (int j = 0; j < 8; ++j) {
            wA0 = fmaf(rbA[j], wr[0][j], wA0);  wB0 = fmaf(rbB[j], wr[0][j], wB0);
            if (!VZERO) { wA1 = fmaf(rbA[j], wr[1][j], wA1);  wB1 = fmaf(rbB[j], wr[1][j], wB1); }
            wA2 = fmaf(rbA[j], wr[2][j], wA2);  wB2 = fmaf(rbB[j], wr[2][j], wB2);
            if (!VZERO) { wA3 = fmaf(rbA[j], wr[3][j], wA3);  wB3 = fmaf(rbB[j], wr[3][j], wB3); }
            if (!VZERO) { wA4 = fmaf(rbA[j], wr[4][j], wA4);  wB4 = fmaf(rbB[j], wr[4][j], wB4); }
        }
        if (VZERO) {
            aA0 += wA0 * ssA;
            float wsA = wA2 * ssA;
            aA1 += wsA * yA.x; aA2 += wsA * yA.y; aA3 += wsA * yA.z;
            aB0 += wB0 * ssB;
            float wsB = wB2 * ssB;
            aB1 += wsB * yB.x; aB2 += wsB * yB.y; aB3 += wsB * yB.z;
        } else {
            float dotA = vA0 * yA.x + vA1 * yA.y + vA2 * yA.z;
            aA0 += wA0 * ssA + wA1 * dotA;
            float cA0 = vA1 * yA.z - vA2 * yA.y;
            float cA1 = vA2 * yA.x - vA0 * yA.z;
            float cA2 = vA0 * yA.y - vA1 * yA.x;
            float wsA = wA2 * ssA;
            aA1 += wsA * yA.x + wA3 * vA0 + wA4 * cA0;
            aA2 += wsA * yA.y + wA3 * vA1 + wA4 * cA1;
            aA3 += wsA * yA.z + wA3 * vA2 + wA4 * cA2;
            float dotB = vB0 * yB.x + vB1 * yB.y + vB2 * yB.z;
            aB0 += wB0 * ssB + wB1 * dotB;
            float cB0 = vB1 * yB.z - vB2 * yB.y;
            float cB1 = vB2 * yB.x - vB0 * yB.z;
            float cB2 = vB0 * yB.y - vB1 * yB.x;
            float wsB = wB2 * ssB;
            aB1 += wsB * yB.x + wB3 * vB0 + wB4 * cB0;
            aB2 += wsB * yB.y + wB3 * vB1 + wB4 * cB1;
            aB3 += wsB * yB.z + wB3 * vB2 + wB4 * cB2;
        }

        if (pA + 1 == endA || k == 15) {
            bool interior = (begA >= pA0) && (endA <= pA0 + 16);
            if (interior) {
                agg_s[(size_t)rA * 64 + f] = aA0;
                agg_v[((size_t)rA * 3 + 0) * 64 + f] = aA1;
                agg_v[((size_t)rA * 3 + 1) * 64 + f] = aA2;
                agg_v[((size_t)rA * 3 + 2) * 64 + f] = aA3;
            } else {
                unsafeAtomicAdd(&agg_s[(size_t)rA * 64 + f], aA0);
                unsafeAtomicAdd(&agg_v[((size_t)rA * 3 + 0) * 64 + f], aA1);
                unsafeAtomicAdd(&agg_v[((size_t)rA * 3 + 1) * 64 + f], aA2);
                unsafeAtomicAdd(&agg_v[((size_t)rA * 3 + 2) * 64 + f], aA3);
            }
            aA0 = aA1 = aA2 = aA3 = 0.f;
            if (pA + 1 == endA && k < 15) {
                begA = endA; ++rA; endA = row_start[rA + 1];
                while (endA == begA) { ++rA; endA = row_start[rA + 1]; }
            }
        }
        if (pB + 1 == endB || k == 15) {
            bool interior = (begB >= pB0) && (endB <= pB0 + 16);
            if (interior) {
                agg_s[(size_t)rB * 64 + f] = aB0;
                agg_v[((size_t)rB * 3 + 0) * 64 + f] = aB1;
                agg_v[((size_t)rB * 3 + 1) * 64 + f] = aB2;
                agg_v[((size_t)rB * 3 + 2) * 64 + f] = aB3;
            } else {
                unsafeAtomicAdd(&agg_s[(size_t)rB * 64 + f], aB0);
                unsafeAtomicAdd(&agg_v[((size_t)rB * 3 + 0) * 64 + f], aB1);
                unsafeAtomicAdd(&agg_v[((size_t)rB * 3 + 1) * 64 + f], aB2);
                unsafeAtomicAdd(&agg_v[((size_t)rB * 3 + 2) * 64 + f], aB3);
            }
            aB0 = aB1 = aB2 = aB3 = 0.f;
            if (pB + 1 == endB && k < 15) {
                begB = endB; ++rB; endB = row_start[rB + 1];
                while (endB == begB) { ++rB; endB = row_start[rB + 1]; }
            }
        }
        ssA = ssA_n; vA0 = vA0n; vA1 = vA1n; vA2 = vA2n;
        ssB = ssB_n; vB0 = vB0n; vB1 = vB1n; vB2 = vB2n;
        srA_c = srA_n; srA_n = srA_n2;
        srB_c = srB_n; srB_n = srB_n2;
    }
}

// ---------------------------------------------------------------------------
// MFMA node kernel with fused readout and (it==0) fused zeroing of its own
// agg rows for the next interaction. wave = 16 sorted nodes.
// ---------------------------------------------------------------------------
__global__ __launch_bounds__(256) void node_mfma_kernel(
    const float* __restrict__ agg_s, const float* __restrict__ agg_v,
    float* s, float* v,
    const short* __restrict__ packW, int it,
    const float* __restrict__ pw_i,
    const int* __restrict__ spec_srt,
    const int* __restrict__ row_start, const int* __restrict__ sidx,
    const float* __restrict__ Wread0, const float* __restrict__ Wr1a,
    const float* __restrict__ Wr1b,
    float* __restrict__ out,
    int has_skip)
{
    const int l = threadIdx.x & 63;
    const int wid = threadIdx.x >> 6;
    const int cl = l & 15;
    const int q = l >> 4;
    const int i16 = (blockIdx.x * 4 + wid) * 16;
    __shared__ float xls_all[4][16 * 65];
    float* xls = xls_all[wid];

    const short* pWls = packW + (size_t)(0 + it) * 4096;
    const short* pWlv = packW + (size_t)(2 + it) * 4096;
    const short* pWps = packW + (size_t)(4 + it) * 4096;
    const short* pWpv = packW + (size_t)(6 + it) * 4096;
    const short* pSkS = packW + (size_t)8 * 4096;
    const short* pSkV = packW + (size_t)18 * 4096;
    const short8 z8 = {0, 0, 0, 0, 0, 0, 0, 0};

    const float* ars = agg_s + (size_t)(i16 + cl) * 64;
    short8 As[2] = { loadArow(ars, 0, q), loadArow(ars, 1, q) };
    short8 Av[3][2];
#pragma unroll
    for (int k = 0; k < 3; ++k) {
        const float* r = agg_v + ((size_t)(i16 + cl) * 3 + k) * 64;
        Av[k][0] = loadArow(r, 0, q);
        Av[k][1] = loadArow(r, 1, q);
    }

    f32x4 sD[4];
#pragma unroll
    for (int t = 0; t < 4; ++t) {
        f32x4 acc = {0.f, 0.f, 0.f, 0.f};
        acc = MFMA16(As[0], loadB(pWls, t, 0, l), acc);
        acc = MFMA16(As[1], loadB(pWls, t, 1, l), acc);
        sD[t] = acc;
    }

    f32x4 vD[3][4];
#pragma unroll
    for (int k = 0; k < 3; ++k)
#pragma unroll
        for (int t = 0; t < 4; ++t) vD[k][t] = (f32x4){0.f, 0.f, 0.f, 0.f};
#pragma unroll
    for (int t = 0; t < 4; ++t)
#pragma unroll
        for (int h = 0; h < 2; ++h) {
            short8 b = loadB(pWlv, t, h, l);
#pragma unroll
            for (int k = 0; k < 3; ++k) vD[k][t] = MFMA16(Av[k][h], b, vD[k][t]);
        }

    int z0 = spec_srt[i16], z1 = spec_srt[i16 + 15];
    float psD[4][4], pvsD[4][4];
    if (z0 == z1) {
        const float* pb = pw_i + z0 * 576 + cl;
        float pc[9][4];
#pragma unroll
        for (int c = 0; c < 9; ++c)
#pragma unroll
            for (int t = 0; t < 4; ++t) pc[c][t] = pb[c * 64 + t * 16];
#pragma unroll
        for (int t = 0; t < 4; ++t)
#pragma unroll
            for (int r = 0; r < 4; ++r) {
                float x = sD[t][r] * EPS_C;
                float w0 = vD[0][t][r] * EPS_C;
                float w1 = vD[1][t][r] * EPS_C;
                float w2 = vD[2][t][r] * EPS_C;
                vD[0][t][r] = w0; vD[1][t][r] = w1; vD[2][t][r] = w2;
                float vv = w0 * w0 + w1 * w1 + w2 * w2;
                float x2 = x * x;
                psD[t][r] = pc[0][t] * x + pc[1][t] * x2 + pc[2][t] * vv
                          + pc[3][t] * x2 * x + pc[4][t] * x * vv;
                pvsD[t][r] = pc[5][t] + pc[6][t] * x + pc[7][t] * x2 + pc[8][t] * vv;
            }
    } else {
#pragma unroll
        for (int r = 0; r < 4; ++r) {
            int z = spec_srt[i16 + q * 4 + r];
            const float* pb = pw_i + z * 576 + cl;
#pragma unroll
            for (int t = 0; t < 4; ++t) {
                float p0 = pb[t*16], p1 = pb[64+t*16], p2 = pb[128+t*16];
                float p3 = pb[192+t*16], p4 = pb[256+t*16], p5 = pb[320+t*16];
                float p6 = pb[384+t*16], p7 = pb[448+t*16], p8 = pb[512+t*16];
                float x = sD[t][r] * EPS_C;
                float w0 = vD[0][t][r] * EPS_C;
                float w1 = vD[1][t][r] * EPS_C;
                float w2 = vD[2][t][r] * EPS_C;
                vD[0][t][r] = w0; vD[1][t][r] = w1; vD[2][t][r] = w2;
                float vv = w0 * w0 + w1 * w1 + w2 * w2;
                float x2 = x * x;
                psD[t][r] = p0 * x + p1 * x2 + p2 * vv + p3 * x2 * x + p4 * x * vv;
                pvsD[t][r] = p5 + p6 * x + p7 * x2 + p8 * vv;
            }
        }
    }

#pragma unroll
    for (int t = 0; t < 4; ++t)
#pragma unroll
        for (int r = 0; r < 4; ++r)
            xls[(q * 4 + r) * 65 + t * 16 + cl] = psD[t][r];
    short8 psA[2];
#pragma unroll
    for (int h = 0; h < 2; ++h) {
        const float* rp = xls + cl * 65 + h * 32 + q * 8;
        float t0 = rp[0], t1 = rp[1], t2 = rp[2], t3 = rp[3];
        float t4 = rp[4], t5 = rp[5], t6 = rp[6], t7 = rp[7];
        psA[h] = cvt8(make_float4(t0, t1, t2, t3), make_float4(t4, t5, t6, t7));
    }

    f32x4 snD[4];
#pragma unroll
    for (int t = 0; t < 4; ++t) {
        f32x4 acc = {0.f, 0.f, 0.f, 0.f};
        acc = MFMA16(psA[0], loadB(pWps, t, 0, l), acc);
        acc = MFMA16(psA[1], loadB(pWps, t, 1, l), acc);
        snD[t] = acc;
    }
    if (has_skip) {
        const float* srow = s + (size_t)(i16 + cl) * 64;
        short8 Ai0 = loadArow(srow, 0, q), Ai1 = loadArow(srow, 1, q);
        int myz = spec_srt[i16 + cl];
        for (int z = z0; z <= z1; ++z) {
            bool keep = (myz == z);
            short8 m0 = keep ? Ai0 : z8;
            short8 m1 = keep ? Ai1 : z8;
            const short* pz = pSkS + (size_t)z * 4096;
#pragma unroll
            for (int t = 0; t < 4; ++t) {
                snD[t] = MFMA16(m0, loadB(pz, t, 0, l), snD[t]);
                snD[t] = MFMA16(m1, loadB(pz, t, 1, l), snD[t]);
            }
        }
    }
#pragma unroll
    for (int t = 0; t < 4; ++t)
#pragma unroll
        for (int r = 0; r < 4; ++r)
            s[(size_t)(i16 + q * 4 + r) * 64 + t * 16 + cl] = snD[t][r];

    // ---- fused readout
    if (it == 0) {
        float w0c[4];
#pragma unroll
        for (int t = 0; t < 4; ++t) w0c[t] = Wread0[t * 16 + cl];
#pragma unroll
        for (int r = 0; r < 4; ++r) {
            float a = snD[0][r] * w0c[0] + snD[1][r] * w0c[1]
                    + snD[2][r] * w0c[2] + snD[3][r] * w0c[3];
            a += __shfl_down(a, 8);
            a += __shfl_down(a, 4);
            a += __shfl_down(a, 2);
            a += __shfl_down(a, 1);
            if (cl == 0) out[(size_t)sidx[i16 + q * 4 + r] * 2 + 0] = a;
        }
    } else {
#pragma unroll
        for (int t = 0; t < 4; ++t)
#pragma unroll
            for (int r = 0; r < 4; ++r)
                xls[(q * 4 + r) * 65 + t * 16 + cl] = snD[t][r];
        float acc4[4] = {0.f, 0.f, 0.f, 0.f};
        for (int g = 0; g < 64; ++g) {
            float wa = Wr1a[g * 16 + cl];
#pragma unroll
            for (int j = 0; j < 4; ++j)
                acc4[j] = fmaf(xls[(q + 4 * j) * 65 + g], wa, acc4[j]);
        }
        float wb = Wr1b[cl];
#pragma unroll
        for (int j = 0; j < 4; ++j) {
            float av = acc4[j];
            float rr = (av / (1.f + expf(-av))) * wb;
            rr += __shfl_down(rr, 8);
            rr += __shfl_down(rr, 4);
            rr += __shfl_down(rr, 2);
            rr += __shfl_down(rr, 1);
            if (cl == 0) out[(size_t)sidx[i16 + q + 4 * j] * 2 + 1] = rr;
        }
    }

    short8 pvA[3][2];
#pragma unroll
    for (int k = 0; k < 3; ++k) {
#pragma unroll
        for (int t = 0; t < 4; ++t)
#pragma unroll
            for (int r = 0; r < 4; ++r)
                xls[(q * 4 + r) * 65 + t * 16 + cl] = pvsD[t][r] * vD[k][t][r];
#pragma unroll
        for (int h = 0; h < 2; ++h) {
            const float* rp = xls + cl * 65 + h * 32 + q * 8;
            float t0 = rp[0], t1 = rp[1], t2 = rp[2], t3 = rp[3];
            float t4 = rp[4], t5 = rp[5], t6 = rp[6], t7 = rp[7];
            pvA[k][h] = cvt8(make_float4(t0, t1, t2, t3), make_float4(t4, t5, t6, t7));
        }
    }

    f32x4 vnD[3][4];
#pragma unroll
    for (int k = 0; k < 3; ++k)
#pragma unroll
        for (int t = 0; t < 4; ++t) vnD[k][t] = (f32x4){0.f, 0.f, 0.f, 0.f};
#pragma unroll
    for (int t = 0; t < 4; ++t)
#pragma unroll
        for (int h = 0; h < 2; ++h) {
            short8 b = loadB(pWpv, t, h, l);
#pragma unroll
            for (int k = 0; k < 3; ++k) vnD[k][t] = MFMA16(pvA[k][h], b, vnD[k][t]);
        }
    if (has_skip) {
        short8 Aiv[3][2];
#pragma unroll
        for (int k = 0; k < 3; ++k) {
            const float* r = v + ((size_t)(i16 + cl) * 3 + k) * 64;
            Aiv[k][0] = loadArow(r, 0, q);
            Aiv[k][1] = loadArow(r, 1, q);
        }
        int myz = spec_srt[i16 + cl];
        for (int z = z0; z <= z1; ++z) {
            bool keep = (myz == z);
            const short* pz = pSkV + (size_t)z * 4096;
#pragma unroll
            for (int t = 0; t < 4; ++t)
#pragma unroll
                for (int h = 0; h < 2; ++h) {
                    short8 b = loadB(pz, t, h, l);
#pragma unroll
                    for (int k = 0; k < 3; ++k) {
                        short8 a = keep ? Aiv[k][h] : z8;
                        vnD[k][t] = MFMA16(a, b, vnD[k][t]);
                    }
                }
        }
    }
#pragma unroll
    for (int k = 0; k < 3; ++k)
#pragma unroll
        for (int t = 0; t < 4; ++t)
#pragma unroll
            for (int r = 0; r < 4; ++r)
                v[((size_t)(i16 + q * 4 + r) * 3 + k) * 64 + t * 16 + cl] = vnD[k][t][r];

    // ---- it==0: zero this wave's own agg boundary rows for interaction 1.
    if (it == 0) {
        for (int rr = 0; rr < 16; ++rr) {
            int i = i16 + rr;
            int beg = row_start[i], end = row_start[i + 1];
            bool need = (end == beg) || (end > (((beg >> 4) + 1) << 4));
            if (need) {
                float* as = (float*)agg_s;
                float* av = (float*)agg_v;
                as[(size_t)i * 64 + l] = 0.f;
                av[((size_t)i * 3 + 0) * 64 + l] = 0.f;
                av[((size_t)i * 3 + 1) * 64 + l] = 0.f;
                av[((size_t)i * 3 + 2) * 64 + l] = 0.f;
            }
        }
    }
}

// ---------------------------------------------------------------------------
extern "C" void kernel_launch(void* const* d_in, const int* in_sizes, int n_in,
                              void* d_out, int out_size, void* d_ws, size_t ws_size,
                              hipStream_t stream)
{
    const float* vectors = (const float*)d_in[0];
    const float* embed_s = (const float*)d_in[1];
    const float* Wr      = (const float*)d_in[2];   // [2,8,320]
    const float* Wls     = (const float*)d_in[3];   // [2,64,64]
    const float* Wlv     = (const float*)d_in[4];
    const float* skip_s  = (const float*)d_in[5];   // [10,64,64]
    const float* skip_v  = (const float*)d_in[6];
    const float* pw      = (const float*)d_in[7];   // [2,10,9,64]
    const float* Wps     = (const float*)d_in[8];
    const float* Wpv     = (const float*)d_in[9];
    const float* Wread0  = (const float*)d_in[10];  // [64,1]
    const float* Wr1a    = (const float*)d_in[11];  // [64,16]
    const float* Wr1b    = (const float*)d_in[12];  // [16,1]
    const int* senders   = (const int*)d_in[13];
    const int* receivers = (const int*)d_in[14];
    const int* species   = (const int*)d_in[15];
    float* out = (float*)d_out;

    float* ws = (float*)d_ws;
    float* edata = ws; ws += (size_t)N_EDGES * 16;  // 16 MB (slot-ordered)
    float* s     = ws; ws += (size_t)N_NODES * 64;  // 8 MB
    float* v     = ws; ws += (size_t)N_NODES * 192; // 24 MB
    float* agg_s = ws; ws += (size_t)N_NODES * 64;  // 8 MB
    float* agg_v = ws; ws += (size_t)N_NODES * 192; // 24 MB
    int* counts    = (int*)ws; ws += N_NODES;
    int* row_start = (int*)ws; ws += N_NODES + 4;
    int* cursor    = (int*)ws; ws += N_NODES;
    int* edge_ids  = (int*)ws; ws += N_EDGES;
    int* srk       = (int*)ws; ws += N_EDGES;
    int* grp_row   = (int*)ws; ws += N_EDGES / 16;
    int* sidx      = (int*)ws; ws += N_NODES;
    int* rank      = (int*)ws; ws += N_NODES;
    int* spec_srt  = (int*)ws; ws += N_NODES;
    int* lrank_arr = (int*)ws; ws += N_NODES;
    int* counts_blk = (int*)ws; ws += 128 * NSPEC;
    int* off_blk    = (int*)ws; ws += 128 * NSPEC;
    short* packW   = (short*)ws;                    // 224 KB

    // species counting sort (sort1 also zeroes CSR counts)
    sort1_kernel<<<N_NODES / 256, 256, 0, stream>>>(
        species, counts_blk, lrank_arr, counts);
    sort2_kernel<<<1, 640, 0, stream>>>(counts_blk, off_blk);
    sort3_kernel<<<N_NODES / 256, 256, 0, stream>>>(
        species, lrank_arr, off_blk, sidx, rank, spec_srt);

    // receiver CSR in sorted space
    hist_kernel<<<N_EDGES / 256, 256, 0, stream>>>(receivers, rank, counts);
    scan_kernel<<<1, 1024, 0, stream>>>(counts, row_start, cursor);
    scatter_kernel<<<N_EDGES / 256, 256, 0, stream>>>(receivers, rank, cursor, edge_ids);

    // edge features + sender ranks + grp_row (one pass, slot order)
    edge_pre_kernel<<<N_EDGES / 256, 256, 0, stream>>>(
        vectors, edge_ids, senders, rank, row_start, edata, srk, grp_row);

    // merged prep: init_s + weight pack + zero boundary agg rows (i0)
    prep_kernel<<<N_NODES * 64 / 256, 256, 0, stream>>>(
        embed_s, spec_srt, s, Wls, Wlv, Wps, Wpv, skip_s, skip_v, packW,
        row_start, agg_s, agg_v);

    // interaction 0 (node fuses read0 + zeroing boundary rows for i1)
    gather_kernel<1><<<N_EDGES / 32, 64, 0, stream>>>(
        edata, srk, row_start, grp_row, s, v, Wr, agg_s, agg_v);
    node_mfma_kernel<<<N_NODES / 64, 256, 0, stream>>>(
        agg_s, agg_v, s, v, packW, 0, pw, spec_srt,
        row_start, sidx, Wread0, Wr1a, Wr1b, out, 0);

    // interaction 1 (node fuses read1)
    gather_kernel<0><<<N_EDGES / 32, 64, 0, stream>>>(
        edata, srk, row_start, grp_row, s, v, Wr + 2560, agg_s, agg_v);
    node_mfma_kernel<<<N_NODES / 64, 256, 0, stream>>>(
        agg_s, agg_v, s, v, packW, 1, pw + 5760, spec_srt,
        row_start, sidx, Wread0, Wr1a, Wr1b, out, 1);
}

// Round 17
// 299.731 us; speedup vs baseline: 1.2445x; 1.0094x over previous
//
#include <hip/hip_runtime.h>
#include <hip/hip_bf16.h>
#include <math.h>

#define N_NODES 32768
#define N_EDGES 262144
#define EPS_C 0.24253562503633297f   // 1/sqrt(17)
#define NSPEC 10

typedef __attribute__((ext_vector_type(8))) short short8;   // 8 bf16
typedef __attribute__((ext_vector_type(4))) float f32x4;    // 4 fp32 acc

#define MFMA16(a, b, c) __builtin_amdgcn_mfma_f32_16x16x32_bf16(a, b, c, 0, 0, 0)

__device__ __forceinline__ short2 cvt2(float a, float b) {
    union { __hip_bfloat162 h; short2 s; } u;
    u.h = __float22bfloat162_rn(make_float2(a, b));
    return u.s;
}
__device__ __forceinline__ short8 cvt8(float4 a, float4 b) {
    short2 p0 = cvt2(a.x, a.y), p1 = cvt2(a.z, a.w);
    short2 p2 = cvt2(b.x, b.y), p3 = cvt2(b.z, b.w);
    short8 r;
    r[0] = p0.x; r[1] = p0.y; r[2] = p1.x; r[3] = p1.y;
    r[4] = p2.x; r[5] = p2.y; r[6] = p3.x; r[7] = p3.y;
    return r;
}
__device__ __forceinline__ short8 loadArow(const float* rowp, int h, int q) {
    const float* p = rowp + h * 32 + q * 8;
    return cvt8(*(const float4*)p, *(const float4*)(p + 4));
}
__device__ __forceinline__ short8 loadB(const short* P, int t, int h, int l) {
    return *(const short8*)(P + (((t * 2 + h) * 64 + l) << 3));
}

// ---------------------------------------------------------------------------
// Species counting sort — contention-free, deterministic. sort1 also zeroes
// the receiver-CSR counts array.
// ---------------------------------------------------------------------------
__global__ __launch_bounds__(256) void sort1_kernel(
    const int* __restrict__ species, int* __restrict__ counts_blk,
    int* __restrict__ lrank_arr, int* __restrict__ counts)
{
    __shared__ int wcnt[4][16];
    int n = blockIdx.x * 256 + threadIdx.x;
    counts[n] = 0;
    int sp = species[n];
    int lane = threadIdx.x & 63, wv = threadIdx.x >> 6;
    unsigned long long ltmask = (1ull << lane) - 1;
    int lrank_w = 0;
#pragma unroll
    for (int z = 0; z < NSPEC; ++z) {
        unsigned long long m = __ballot(sp == z);
        if (sp == z) lrank_w = __popcll(m & ltmask);
        if (lane == 0) wcnt[wv][z] = __popcll(m);
    }
    __syncthreads();
    int off = 0;
    for (int w = 0; w < wv; ++w) off += wcnt[w][sp];
    lrank_arr[n] = lrank_w + off;
    if (threadIdx.x < NSPEC)
        counts_blk[blockIdx.x * NSPEC + threadIdx.x] =
            wcnt[0][threadIdx.x] + wcnt[1][threadIdx.x] +
            wcnt[2][threadIdx.x] + wcnt[3][threadIdx.x];
}

// parallel block-offset scan: wave z shuffle-scans its 128 block counts
__global__ __launch_bounds__(640) void sort2_kernel(
    const int* __restrict__ counts_blk, int* __restrict__ off_blk)
{
    __shared__ int totals[16];
    int wv = threadIdx.x >> 6;        // 0..9 == species z
    int lane = threadIdx.x & 63;
    int c0 = counts_blk[lane * NSPEC + wv];
    int c1 = counts_blk[(64 + lane) * NSPEC + wv];
    int s0 = c0;
#pragma unroll
    for (int off = 1; off < 64; off <<= 1) {
        int y = __shfl_up(s0, off);
        if (lane >= off) s0 += y;
    }
    int tot0 = __shfl(s0, 63);
    int s1 = c1;
#pragma unroll
    for (int off = 1; off < 64; off <<= 1) {
        int y = __shfl_up(s1, off);
        if (lane >= off) s1 += y;
    }
    s1 += tot0;
    if (lane == 63) totals[wv] = s1;
    __syncthreads();
    int base = 0;
    for (int q = 0; q < wv; ++q) base += totals[q];
    off_blk[lane * NSPEC + wv] = base + s0 - c0;
    off_blk[(64 + lane) * NSPEC + wv] = base + s1 - c1;
}

__global__ __launch_bounds__(256) void sort3_kernel(
    const int* __restrict__ species, const int* __restrict__ lrank_arr,
    const int* __restrict__ off_blk,
    int* __restrict__ sidx, int* __restrict__ rank, int* __restrict__ spec_srt)
{
    int n = blockIdx.x * 256 + threadIdx.x;
    int sp = species[n];
    int slot = off_blk[blockIdx.x * NSPEC + sp] + lrank_arr[n];
    sidx[slot] = n;
    rank[n] = slot;
    spec_srt[slot] = sp;
}

// ---------------------------------------------------------------------------
// Receiver CSR in SORTED space
// ---------------------------------------------------------------------------
__global__ __launch_bounds__(256) void hist_kernel(
    const int* __restrict__ receivers, const int* __restrict__ rank,
    int* __restrict__ counts)
{
    int e = blockIdx.x * 256 + threadIdx.x;
    atomicAdd(&counts[rank[receivers[e]]], 1);
}

__global__ __launch_bounds__(1024) void scan_kernel(
    const int* __restrict__ counts, int* __restrict__ row_start, int* __restrict__ cursor)
{
    __shared__ int wave_tot[16];
    int tid = threadIdx.x;
    int c[32];
    int sum = 0;
#pragma unroll
    for (int i = 0; i < 32; ++i) { c[i] = counts[tid * 32 + i]; sum += c[i]; }
    int lane = tid & 63, wv = tid >> 6;
    int x = sum;
#pragma unroll
    for (int off = 1; off < 64; off <<= 1) {
        int y = __shfl_up(x, off);
        if (lane >= off) x += y;
    }
    if (lane == 63) wave_tot[wv] = x;
    __syncthreads();
    if (wv == 0 && lane < 16) {
        int t = wave_tot[lane];
#pragma unroll
        for (int off = 1; off < 16; off <<= 1) {
            int y = __shfl_up(t, off);
            if (lane >= off) t += y;
        }
        wave_tot[lane] = t;
    }
    __syncthreads();
    int excl = x - sum + (wv ? wave_tot[wv - 1] : 0);
    int run = excl;
#pragma unroll
    for (int i = 0; i < 32; ++i) {
        row_start[tid * 32 + i] = run;
        cursor[tid * 32 + i] = run;
        run += c[i];
    }
    if (tid == 1023) row_start[32768] = run;
}

__global__ __launch_bounds__(256) void scatter_kernel(
    const int* __restrict__ receivers, const int* __restrict__ rank,
    int* __restrict__ cursor, int* __restrict__ edge_ids)
{
    int e = blockIdx.x * 256 + threadIdx.x;
    int slot = atomicAdd(&cursor[rank[receivers[e]]], 1);
    edge_ids[slot] = e;
}

// ---------------------------------------------------------------------------
// Edge precompute in slot order + fused sender-rank/species stream + grp_row.
// srk[p] = rank | (species << 16)  (rank < 32768, species < 10)
// ---------------------------------------------------------------------------
__global__ __launch_bounds__(256) void edge_pre_kernel(
    const float* __restrict__ vectors, const int* __restrict__ edge_ids,
    const int* __restrict__ senders, const int* __restrict__ rank,
    const int* __restrict__ species, const int* __restrict__ row_start,
    float* __restrict__ edata, int* __restrict__ srk, int* __restrict__ grp_row)
{
    int p = blockIdx.x * 256 + threadIdx.x;
    int e = edge_ids[p];
    int snd = senders[e];
    srk[p] = rank[snd] | (species[snd] << 16);
    float x = vectors[e * 3 + 0], y = vectors[e * 3 + 1], z = vectors[e * 3 + 2];
    float r2 = x * x + y * y + z * z + 1e-12f;
    float r = sqrtf(r2);
    float inv = 1.0f / r;
    float* d = edata + (size_t)p * 16;
    *(float4*)d = make_float4(x * inv, y * inv, z * inv, 0.0f);
    float rc = fmaxf(r, 1e-6f);
    float r6 = r2 * r2 * r2;
    float r7 = r6 * r;
    float r8 = r6 * r2;
    float env = (r < 1.0f) ? (1.0f - 28.0f * r6 + 48.0f * r7 - 21.0f * r8) : 0.0f;
    float sc = 1.41421356237309515f * env / rc;
#pragma unroll
    for (int j = 0; j < 8; ++j)
        d[4 + j] = sc * sinf((float)(j + 1) * 3.14159265358979323846f * rc);
    d[12] = 0.f; d[13] = 0.f; d[14] = 0.f; d[15] = 0.f;

    if (p < N_EDGES / 16) {
        int target = p * 16;
        int lo = 0, hi = N_NODES - 1;
        while (lo < hi) {
            int mid = (lo + hi + 1) >> 1;
            if (row_start[mid] <= target) lo = mid; else hi = mid - 1;
        }
        grp_row[p] = lo;
    }
}

// ---------------------------------------------------------------------------
// Merged prep: weight pack (blocks<448) + zero_bnd for interaction 0
// (all 2048 blocks). init_s removed: s is never read before node-i0 writes it
// (gather<1> reads embed_s directly; node-i0 has no skip).
// ---------------------------------------------------------------------------
__global__ __launch_bounds__(256) void prep_kernel(
    const float* __restrict__ Wls, const float* __restrict__ Wlv,
    const float* __restrict__ Wps, const float* __restrict__ Wpv,
    const float* __restrict__ skip_s, const float* __restrict__ skip_v,
    short* __restrict__ packW,
    const int* __restrict__ row_start,
    float* __restrict__ agg_s, float* __restrict__ agg_v)
{
    int idx = blockIdx.x * 256 + threadIdx.x;
    if (blockIdx.x < 448 && idx < 28 * 4096) {
        int m = idx >> 12, e = idx & 4095;
        int t = e >> 10, h = (e >> 9) & 1, l = (e >> 3) & 63, j = e & 7;
        int fi = h * 32 + ((l >> 4) << 3) + j;
        int fo = t * 16 + (l & 15);
        const float* src;
        if      (m < 2)  src = Wls    + m * 4096;
        else if (m < 4)  src = Wlv    + (m - 2) * 4096;
        else if (m < 6)  src = Wps    + (m - 4) * 4096;
        else if (m < 8)  src = Wpv    + (m - 6) * 4096;
        else if (m < 18) src = skip_s + (m - 8) * 4096;
        else             src = skip_v + (m - 18) * 4096;
        packW[idx] = cvt2(src[fi * 64 + fo], 0.f).x;
    }
    const int wid = threadIdx.x >> 6;
    const int f = threadIdx.x & 63;
    const int base = (blockIdx.x * 4 + wid) * 4;
#pragma unroll
    for (int t = 0; t < 4; ++t) {
        int i = base + t;
        int beg = row_start[i], end = row_start[i + 1];
        bool need = (end == beg) || (end > (((beg >> 4) + 1) << 4));
        if (need) {
            agg_s[(size_t)i * 64 + f] = 0.f;
            agg_v[((size_t)i * 3 + 0) * 64 + f] = 0.f;
            agg_v[((size_t)i * 3 + 1) * 64 + f] = 0.f;
            agg_v[((size_t)i * 3 + 2) * 64 + f] = 0.f;
        }
    }
}

// ---------------------------------------------------------------------------
// Dual-chain edge-balanced gather (rolled loop, 1 wave/block).
// VZERO (interaction 0): s_in[sr] == embed_s[species[sender]] bit-exactly;
// read the 2.5KB L1-resident table instead — zero random traffic.
// ---------------------------------------------------------------------------
template<int VZERO>
__global__ __launch_bounds__(64) void gather_kernel(
    const float* __restrict__ edata, const int* __restrict__ srk,
    const int* __restrict__ row_start, const int* __restrict__ grp_row,
    const float* __restrict__ embed_s,
    const float* __restrict__ s_in, const float* __restrict__ v_in,
    const float* __restrict__ Wr_i,
    float* __restrict__ agg_s, float* __restrict__ agg_v)
{
    const int f = threadIdx.x & 63;
    const int w = blockIdx.x;
    const int pA0 = w * 32;
    const int pB0 = pA0 + 16;

    float wr[5][8];
#pragma unroll
    for (int j = 0; j < 8; ++j)
#pragma unroll
        for (int p = 0; p < 5; ++p)
            wr[p][j] = (VZERO && (p == 1 || p == 3 || p == 4))
                       ? 0.f : Wr_i[j * 320 + p * 64 + f];

    int rA = grp_row[2 * w], rB = grp_row[2 * w + 1];
    int begA = row_start[rA], endA = row_start[rA + 1];
    int begB = row_start[rB], endB = row_start[rB + 1];
    float aA0 = 0.f, aA1 = 0.f, aA2 = 0.f, aA3 = 0.f;
    float aB0 = 0.f, aB1 = 0.f, aB2 = 0.f, aB3 = 0.f;

    int svA_c = srk[pA0],     svB_c = srk[pB0];
    int svA_n = srk[pA0 + 1], svB_n = srk[pB0 + 1];
    int srA_c = svA_c & 0xFFFF, srB_c = svB_c & 0xFFFF;
    float ssA, ssB;
    if (VZERO) {
        ssA = embed_s[(svA_c >> 16) * 64 + f];
        ssB = embed_s[(svB_c >> 16) * 64 + f];
    } else {
        ssA = s_in[(size_t)srA_c * 64 + f];
        ssB = s_in[(size_t)srB_c * 64 + f];
    }
    float vA0 = 0.f, vA1 = 0.f, vA2 = 0.f, vB0 = 0.f, vB1 = 0.f, vB2 = 0.f;
    if (!VZERO) {
        vA0 = v_in[((size_t)srA_c * 3 + 0) * 64 + f];
        vA1 = v_in[((size_t)srA_c * 3 + 1) * 64 + f];
        vA2 = v_in[((size_t)srA_c * 3 + 2) * 64 + f];
        vB0 = v_in[((size_t)srB_c * 3 + 0) * 64 + f];
        vB1 = v_in[((size_t)srB_c * 3 + 1) * 64 + f];
        vB2 = v_in[((size_t)srB_c * 3 + 2) * 64 + f];
    }

    for (int k = 0; k < 16; ++k) {
        int pA = pA0 + k, pB = pB0 + k;
        int svA_n2 = (k + 2 < 16) ? srk[pA + 2] : svA_n;
        int svB_n2 = (k + 2 < 16) ? srk[pB + 2] : svB_n;
        int srA_n = svA_n & 0xFFFF, srB_n = svB_n & 0xFFFF;
        float ssA_n, ssB_n;
        if (VZERO) {
            ssA_n = embed_s[(svA_n >> 16) * 64 + f];
            ssB_n = embed_s[(svB_n >> 16) * 64 + f];
        } else {
            ssA_n = s_in[(size_t)srA_n * 64 + f];
            ssB_n = s_in[(size_t)srB_n * 64 + f];
        }
        float vA0n = 0.f, vA1n = 0.f, vA2n = 0.f;
        float vB0n = 0.f, vB1n = 0.f, vB2n = 0.f;
        if (!VZERO) {
            vA0n = v_in[((size_t)srA_n * 3 + 0) * 64 + f];
            vA1n = v_in[((size_t)srA_n * 3 + 1) * 64 + f];
            vA2n = v_in[((size_t)srA_n * 3 + 2) * 64 + f];
            vB0n = v_in[((size_t)srB_n * 3 + 0) * 64 + f];
            vB1n = v_in[((size_t)srB_n * 3 + 1) * 64 + f];
            vB2n = v_in[((size_t)srB_n * 3 + 2) * 64 + f];
        }
        const float* dA = edata + (size_t)pA * 16;
        const float* dB = edata + (size_t)pB * 16;
        float4 yA = *(const float4*)dA;
        float4 qA0 = *(const float4*)(dA + 4);
        float4 qA1 = *(const float4*)(dA + 8);
        float4 yB = *(const float4*)dB;
        float4 qB0 = *(const float4*)(dB + 4);
        float4 qB1 = *(const float4*)(dB + 8);

        float rbA[8] = {qA0.x, qA0.y, qA0.z, qA0.w, qA1.x, qA1.y, qA1.z, qA1.w};
        float rbB[8] = {qB0.x, qB0.y, qB0.z, qB0.w, qB1.x, qB1.y, qB1.z, qB1.w};
        float wA0 = 0.f, wA1 = 0.f, wA2 = 0.f, wA3 = 0.f, wA4 = 0.f;
        float wB0 = 0.f, wB1 = 0.f, wB2 = 0.f, wB3 = 0.f, wB4 = 0.f;
#pragma unroll
        for (int j = 0; j < 8; ++j) {
            wA0 = fmaf(rbA[j], wr[0][j], wA0);  wB0 = fmaf(rbB[j], wr[0][j], wB0);
            if (!VZERO) { wA1 = fmaf(rbA[j], wr[1][j], wA1);  wB1 = fmaf(rbB[j], wr[1][j], wB1); }
            wA2 = fmaf(rbA[j], wr[2][j], wA2);  wB2 = fmaf(rbB[j], wr[2][j], wB2);
            if (!VZERO) { wA3 = fmaf(rbA[j], wr[3][j], wA3);  wB3 = fmaf(rbB[j], wr[3][j], wB3); }
            if (!VZERO) { wA4 = fmaf(rbA[j], wr[4][j], wA4);  wB4 = fmaf(rbB[j], wr[4][j], wB4); }
        }
        if (VZERO) {
            aA0 += wA0 * ssA;
            float wsA = wA2 * ssA;
            aA1 += wsA * yA.x; aA2 += wsA * yA.y; aA3 += wsA * yA.z;
            aB0 += wB0 * ssB;
            float wsB = wB2 * ssB;
            aB1 += wsB * yB.x; aB2 += wsB * yB.y; aB3 += wsB * yB.z;
        } else {
            float dotA = vA0 * yA.x + vA1 * yA.y + vA2 * yA.z;
            aA0 += wA0 * ssA + wA1 * dotA;
            float cA0 = vA1 * yA.z - vA2 * yA.y;
            float cA1 = vA2 * yA.x - vA0 * yA.z;
            float cA2 = vA0 * yA.y - vA1 * yA.x;
            float wsA = wA2 * ssA;
            aA1 += wsA * yA.x + wA3 * vA0 + wA4 * cA0;
            aA2 += wsA * yA.y + wA3 * vA1 + wA4 * cA1;
            aA3 += wsA * yA.z + wA3 * vA2 + wA4 * cA2;
            float dotB = vB0 * yB.x + vB1 * yB.y + vB2 * yB.z;
            aB0 += wB0 * ssB + wB1 * dotB;
            float cB0 = vB1 * yB.z - vB2 * yB.y;
            float cB1 = vB2 * yB.x - vB0 * yB.z;
            float cB2 = vB0 * yB.y - vB1 * yB.x;
            float wsB = wB2 * ssB;
            aB1 += wsB * yB.x + wB3 * vB0 + wB4 * cB0;
            aB2 += wsB * yB.y + wB3 * vB1 + wB4 * cB1;
            aB3 += wsB * yB.z + wB3 * vB2 + wB4 * cB2;
        }

        if (pA + 1 == endA || k == 15) {
            bool interior = (begA >= pA0) && (endA <= pA0 + 16);
            if (interior) {
                agg_s[(size_t)rA * 64 + f] = aA0;
                agg_v[((size_t)rA * 3 + 0) * 64 + f] = aA1;
                agg_v[((size_t)rA * 3 + 1) * 64 + f] = aA2;
                agg_v[((size_t)rA * 3 + 2) * 64 + f] = aA3;
            } else {
                unsafeAtomicAdd(&agg_s[(size_t)rA * 64 + f], aA0);
                unsafeAtomicAdd(&agg_v[((size_t)rA * 3 + 0) * 64 + f], aA1);
                unsafeAtomicAdd(&agg_v[((size_t)rA * 3 + 1) * 64 + f], aA2);
                unsafeAtomicAdd(&agg_v[((size_t)rA * 3 + 2) * 64 + f], aA3);
            }
            aA0 = aA1 = aA2 = aA3 = 0.f;
            if (pA + 1 == endA && k < 15) {
                begA = endA; ++rA; endA = row_start[rA + 1];
                while (endA == begA) { ++rA; endA = row_start[rA + 1]; }
            }
        }
        if (pB + 1 == endB || k == 15) {
            bool interior = (begB >= pB0) && (endB <= pB0 + 16);
            if (interior) {
                agg_s[(size_t)rB * 64 + f] = aB0;
                agg_v[((size_t)rB * 3 + 0) * 64 + f] = aB1;
                agg_v[((size_t)rB * 3 + 1) * 64 + f] = aB2;
                agg_v[((size_t)rB * 3 + 2) * 64 + f] = aB3;
            } else {
                unsafeAtomicAdd(&agg_s[(size_t)rB * 64 + f], aB0);
                unsafeAtomicAdd(&agg_v[((size_t)rB * 3 + 0) * 64 + f], aB1);
                unsafeAtomicAdd(&agg_v[((size_t)rB * 3 + 1) * 64 + f], aB2);
                unsafeAtomicAdd(&agg_v[((size_t)rB * 3 + 2) * 64 + f], aB3);
            }
            aB0 = aB1 = aB2 = aB3 = 0.f;
            if (pB + 1 == endB && k < 15) {
                begB = endB; ++rB; endB = row_start[rB + 1];
                while (endB == begB) { ++rB; endB = row_start[rB + 1]; }
            }
        }
        ssA = ssA_n; vA0 = vA0n; vA1 = vA1n; vA2 = vA2n;
        ssB = ssB_n; vB0 = vB0n; vB1 = vB1n; vB2 = vB2n;
        srA_c = srA_n; srB_c = srB_n;
        svA_n = svA_n2; svB_n = svB_n2;
    }
}

// ---------------------------------------------------------------------------
// MFMA node kernel with fused readout and (it==0) fused zeroing of its own
// agg rows for the next interaction. wave = 16 sorted nodes.
// ---------------------------------------------------------------------------
__global__ __launch_bounds__(256) void node_mfma_kernel(
    const float* __restrict__ agg_s, const float* __restrict__ agg_v,
    float* s, float* v,
    const short* __restrict__ packW, int it,
    const float* __restrict__ pw_i,
    const int* __restrict__ spec_srt,
    const int* __restrict__ row_start, const int* __restrict__ sidx,
    const float* __restrict__ Wread0, const float* __restrict__ Wr1a,
    const float* __restrict__ Wr1b,
    float* __restrict__ out,
    int has_skip)
{
    const int l = threadIdx.x & 63;
    const int wid = threadIdx.x >> 6;
    const int cl = l & 15;
    const int q = l >> 4;
    const int i16 = (blockIdx.x * 4 + wid) * 16;
    __shared__ float xls_all[4][16 * 65];
    float* xls = xls_all[wid];

    const short* pWls = packW + (size_t)(0 + it) * 4096;
    const short* pWlv = packW + (size_t)(2 + it) * 4096;
    const short* pWps = packW + (size_t)(4 + it) * 4096;
    const short* pWpv = packW + (size_t)(6 + it) * 4096;
    const short* pSkS = packW + (size_t)8 * 4096;
    const short* pSkV = packW + (size_t)18 * 4096;
    const short8 z8 = {0, 0, 0, 0, 0, 0, 0, 0};

    const float* ars = agg_s + (size_t)(i16 + cl) * 64;
    short8 As[2] = { loadArow(ars, 0, q), loadArow(ars, 1, q) };
    short8 Av[3][2];
#pragma unroll
    for (int k = 0; k < 3; ++k) {
        const float* r = agg_v + ((size_t)(i16 + cl) * 3 + k) * 64;
        Av[k][0] = loadArow(r, 0, q);
        Av[k][1] = loadArow(r, 1, q);
    }

    f32x4 sD[4];
#pragma unroll
    for (int t = 0; t < 4; ++t) {
        f32x4 acc = {0.f, 0.f, 0.f, 0.f};
        acc = MFMA16(As[0], loadB(pWls, t, 0, l), acc);
        acc = MFMA16(As[1], loadB(pWls, t, 1, l), acc);
        sD[t] = acc;
    }

    f32x4 vD[3][4];
#pragma unroll
    for (int k = 0; k < 3; ++k)
#pragma unroll
        for (int t = 0; t < 4; ++t) vD[k][t] = (f32x4){0.f, 0.f, 0.f, 0.f};
#pragma unroll
    for (int t = 0; t < 4; ++t)
#pragma unroll
        for (int h = 0; h < 2; ++h) {
            short8 b = loadB(pWlv, t, h, l);
#pragma unroll
            for (int k = 0; k < 3; ++k) vD[k][t] = MFMA16(Av[k][h], b, vD[k][t]);
        }

    int z0 = spec_srt[i16], z1 = spec_srt[i16 + 15];
    float psD[4][4], pvsD[4][4];
    if (z0 == z1) {
        const float* pb = pw_i + z0 * 576 + cl;
        float pc[9][4];
#pragma unroll
        for (int c = 0; c < 9; ++c)
#pragma unroll
            for (int t = 0; t < 4; ++t) pc[c][t] = pb[c * 64 + t * 16];
#pragma unroll
        for (int t = 0; t < 4; ++t)
#pragma unroll
            for (int r = 0; r < 4; ++r) {
                float x = sD[t][r] * EPS_C;
                float w0 = vD[0][t][r] * EPS_C;
                float w1 = vD[1][t][r] * EPS_C;
                float w2 = vD[2][t][r] * EPS_C;
                vD[0][t][r] = w0; vD[1][t][r] = w1; vD[2][t][r] = w2;
                float vv = w0 * w0 + w1 * w1 + w2 * w2;
                float x2 = x * x;
                psD[t][r] = pc[0][t] * x + pc[1][t] * x2 + pc[2][t] * vv
                          + pc[3][t] * x2 * x + pc[4][t] * x * vv;
                pvsD[t][r] = pc[5][t] + pc[6][t] * x + pc[7][t] * x2 + pc[8][t] * vv;
            }
    } else {
#pragma unroll
        for (int r = 0; r < 4; ++r) {
            int z = spec_srt[i16 + q * 4 + r];
            const float* pb = pw_i + z * 576 + cl;
#pragma unroll
            for (int t = 0; t < 4; ++t) {
                float p0 = pb[t*16], p1 = pb[64+t*16], p2 = pb[128+t*16];
                float p3 = pb[192+t*16], p4 = pb[256+t*16], p5 = pb[320+t*16];
                float p6 = pb[384+t*16], p7 = pb[448+t*16], p8 = pb[512+t*16];
                float x = sD[t][r] * EPS_C;
                float w0 = vD[0][t][r] * EPS_C;
                float w1 = vD[1][t][r] * EPS_C;
                float w2 = vD[2][t][r] * EPS_C;
                vD[0][t][r] = w0; vD[1][t][r] = w1; vD[2][t][r] = w2;
                float vv = w0 * w0 + w1 * w1 + w2 * w2;
                float x2 = x * x;
                psD[t][r] = p0 * x + p1 * x2 + p2 * vv + p3 * x2 * x + p4 * x * vv;
                pvsD[t][r] = p5 + p6 * x + p7 * x2 + p8 * vv;
            }
        }
    }

#pragma unroll
    for (int t = 0; t < 4; ++t)
#pragma unroll
        for (int r = 0; r < 4; ++r)
            xls[(q * 4 + r) * 65 + t * 16 + cl] = psD[t][r];
    short8 psA[2];
#pragma unroll
    for (int h = 0; h < 2; ++h) {
        const float* rp = xls + cl * 65 + h * 32 + q * 8;
        float t0 = rp[0], t1 = rp[1], t2 = rp[2], t3 = rp[3];
        float t4 = rp[4], t5 = rp[5], t6 = rp[6], t7 = rp[7];
        psA[h] = cvt8(make_float4(t0, t1, t2, t3), make_float4(t4, t5, t6, t7));
    }

    f32x4 snD[4];
#pragma unroll
    for (int t = 0; t < 4; ++t) {
        f32x4 acc = {0.f, 0.f, 0.f, 0.f};
        acc = MFMA16(psA[0], loadB(pWps, t, 0, l), acc);
        acc = MFMA16(psA[1], loadB(pWps, t, 1, l), acc);
        snD[t] = acc;
    }
    if (has_skip) {
        const float* srow = s + (size_t)(i16 + cl) * 64;
        short8 Ai0 = loadArow(srow, 0, q), Ai1 = loadArow(srow, 1, q);
        int myz = spec_srt[i16 + cl];
        for (int z = z0; z <= z1; ++z) {
            bool keep = (myz == z);
            short8 m0 = keep ? Ai0 : z8;
            short8 m1 = keep ? Ai1 : z8;
            const short* pz = pSkS + (size_t)z * 4096;
#pragma unroll
            for (int t = 0; t < 4; ++t) {
                snD[t] = MFMA16(m0, loadB(pz, t, 0, l), snD[t]);
                snD[t] = MFMA16(m1, loadB(pz, t, 1, l), snD[t]);
            }
        }
    }
#pragma unroll
    for (int t = 0; t < 4; ++t)
#pragma unroll
        for (int r = 0; r < 4; ++r)
            s[(size_t)(i16 + q * 4 + r) * 64 + t * 16 + cl] = snD[t][r];

    // ---- fused readout
    if (it == 0) {
        float w0c[4];
#pragma unroll
        for (int t = 0; t < 4; ++t) w0c[t] = Wread0[t * 16 + cl];
#pragma unroll
        for (int r = 0; r < 4; ++r) {
            float a = snD[0][r] * w0c[0] + snD[1][r] * w0c[1]
                    + snD[2][r] * w0c[2] + snD[3][r] * w0c[3];
            a += __shfl_down(a, 8);
            a += __shfl_down(a, 4);
            a += __shfl_down(a, 2);
            a += __shfl_down(a, 1);
            if (cl == 0) out[(size_t)sidx[i16 + q * 4 + r] * 2 + 0] = a;
        }
    } else {
#pragma unroll
        for (int t = 0; t < 4; ++t)
#pragma unroll
            for (int r = 0; r < 4; ++r)
                xls[(q * 4 + r) * 65 + t * 16 + cl] = snD[t][r];
        float acc4[4] = {0.f, 0.f, 0.f, 0.f};
        for (int g = 0; g < 64; ++g) {
            float wa = Wr1a[g * 16 + cl];
#pragma unroll
            for (int j = 0; j < 4; ++j)
                acc4[j] = fmaf(xls[(q + 4 * j) * 65 + g], wa, acc4[j]);
        }
        float wb = Wr1b[cl];
#pragma unroll
        for (int j = 0; j < 4; ++j) {
            float av = acc4[j];
            float rr = (av / (1.f + expf(-av))) * wb;
            rr += __shfl_down(rr, 8);
            rr += __shfl_down(rr, 4);
            rr += __shfl_down(rr, 2);
            rr += __shfl_down(rr, 1);
            if (cl == 0) out[(size_t)sidx[i16 + q + 4 * j] * 2 + 1] = rr;
        }
    }

    short8 pvA[3][2];
#pragma unroll
    for (int k = 0; k < 3; ++k) {
#pragma unroll
        for (int t = 0; t < 4; ++t)
#pragma unroll
            for (int r = 0; r < 4; ++r)
                xls[(q * 4 + r) * 65 + t * 16 + cl] = pvsD[t][r] * vD[k][t][r];
#pragma unroll
        for (int h = 0; h < 2; ++h) {
            const float* rp = xls + cl * 65 + h * 32 + q * 8;
            float t0 = rp[0], t1 = rp[1], t2 = rp[2], t3 = rp[3];
            float t4 = rp[4], t5 = rp[5], t6 = rp[6], t7 = rp[7];
            pvA[k][h] = cvt8(make_float4(t0, t1, t2, t3), make_float4(t4, t5, t6, t7));
        }
    }

    f32x4 vnD[3][4];
#pragma unroll
    for (int k = 0; k < 3; ++k)
#pragma unroll
        for (int t = 0; t < 4; ++t) vnD[k][t] = (f32x4){0.f, 0.f, 0.f, 0.f};
#pragma unroll
    for (int t = 0; t < 4; ++t)
#pragma unroll
        for (int h = 0; h < 2; ++h) {
            short8 b = loadB(pWpv, t, h, l);
#pragma unroll
            for (int k = 0; k < 3; ++k) vnD[k][t] = MFMA16(pvA[k][h], b, vnD[k][t]);
        }
    if (has_skip) {
        short8 Aiv[3][2];
#pragma unroll
        for (int k = 0; k < 3; ++k) {
            const float* r = v + ((size_t)(i16 + cl) * 3 + k) * 64;
            Aiv[k][0] = loadArow(r, 0, q);
            Aiv[k][1] = loadArow(r, 1, q);
        }
        int myz = spec_srt[i16 + cl];
        for (int z = z0; z <= z1; ++z) {
            bool keep = (myz == z);
            const short* pz = pSkV + (size_t)z * 4096;
#pragma unroll
            for (int t = 0; t < 4; ++t)
#pragma unroll
                for (int h = 0; h < 2; ++h) {
                    short8 b = loadB(pz, t, h, l);
#pragma unroll
                    for (int k = 0; k < 3; ++k) {
                        short8 a = keep ? Aiv[k][h] : z8;
                        vnD[k][t] = MFMA16(a, b, vnD[k][t]);
                    }
                }
        }
    }
#pragma unroll
    for (int k = 0; k < 3; ++k)
#pragma unroll
        for (int t = 0; t < 4; ++t)
#pragma unroll
            for (int r = 0; r < 4; ++r)
                v[((size_t)(i16 + q * 4 + r) * 3 + k) * 64 + t * 16 + cl] = vnD[k][t][r];

    // ---- it==0: zero this wave's own agg boundary rows for interaction 1.
    if (it == 0) {
        for (int rr = 0; rr < 16; ++rr) {
            int i = i16 + rr;
            int beg = row_start[i], end = row_start[i + 1];
            bool need = (end == beg) || (end > (((beg >> 4) + 1) << 4));
            if (need) {
                float* as = (float*)agg_s;
                float* av = (float*)agg_v;
                as[(size_t)i * 64 + l] = 0.f;
                av[((size_t)i * 3 + 0) * 64 + l] = 0.f;
                av[((size_t)i * 3 + 1) * 64 + l] = 0.f;
                av[((size_t)i * 3 + 2) * 64 + l] = 0.f;
            }
        }
    }
}

// ---------------------------------------------------------------------------
extern "C" void kernel_launch(void* const* d_in, const int* in_sizes, int n_in,
                              void* d_out, int out_size, void* d_ws, size_t ws_size,
                              hipStream_t stream)
{
    const float* vectors = (const float*)d_in[0];
    const float* embed_s = (const float*)d_in[1];
    const float* Wr      = (const float*)d_in[2];   // [2,8,320]
    const float* Wls     = (const float*)d_in[3];   // [2,64,64]
    const float* Wlv     = (const float*)d_in[4];
    const float* skip_s  = (const float*)d_in[5];   // [10,64,64]
    const float* skip_v  = (const float*)d_in[6];
    const float* pw      = (const float*)d_in[7];   // [2,10,9,64]
    const float* Wps     = (const float*)d_in[8];
    const float* Wpv     = (const float*)d_in[9];
    const float* Wread0  = (const float*)d_in[10];  // [64,1]
    const float* Wr1a    = (const float*)d_in[11];  // [64,16]
    const float* Wr1b    = (const float*)d_in[12];  // [16,1]
    const int* senders   = (const int*)d_in[13];
    const int* receivers = (const int*)d_in[14];
    const int* species   = (const int*)d_in[15];
    float* out = (float*)d_out;

    float* ws = (float*)d_ws;
    float* edata = ws; ws += (size_t)N_EDGES * 16;  // 16 MB (slot-ordered)
    float* s     = ws; ws += (size_t)N_NODES * 64;  // 8 MB
    float* v     = ws; ws += (size_t)N_NODES * 192; // 24 MB
    float* agg_s = ws; ws += (size_t)N_NODES * 64;  // 8 MB
    float* agg_v = ws; ws += (size_t)N_NODES * 192; // 24 MB
    int* counts    = (int*)ws; ws += N_NODES;
    int* row_start = (int*)ws; ws += N_NODES + 4;
    int* cursor    = (int*)ws; ws += N_NODES;
    int* edge_ids  = (int*)ws; ws += N_EDGES;
    int* srk       = (int*)ws; ws += N_EDGES;
    int* grp_row   = (int*)ws; ws += N_EDGES / 16;
    int* sidx      = (int*)ws; ws += N_NODES;
    int* rank      = (int*)ws; ws += N_NODES;
    int* spec_srt  = (int*)ws; ws += N_NODES;
    int* lrank_arr = (int*)ws; ws += N_NODES;
    int* counts_blk = (int*)ws; ws += 128 * NSPEC;
    int* off_blk    = (int*)ws; ws += 128 * NSPEC;
    short* packW   = (short*)ws;                    // 224 KB

    // species counting sort (sort1 also zeroes CSR counts)
    sort1_kernel<<<N_NODES / 256, 256, 0, stream>>>(
        species, counts_blk, lrank_arr, counts);
    sort2_kernel<<<1, 640, 0, stream>>>(counts_blk, off_blk);
    sort3_kernel<<<N_NODES / 256, 256, 0, stream>>>(
        species, lrank_arr, off_blk, sidx, rank, spec_srt);

    // receiver CSR in sorted space
    hist_kernel<<<N_EDGES / 256, 256, 0, stream>>>(receivers, rank, counts);
    scan_kernel<<<1, 1024, 0, stream>>>(counts, row_start, cursor);
    scatter_kernel<<<N_EDGES / 256, 256, 0, stream>>>(receivers, rank, cursor, edge_ids);

    // edge features + packed sender rank/species + grp_row (one pass)
    edge_pre_kernel<<<N_EDGES / 256, 256, 0, stream>>>(
        vectors, edge_ids, senders, rank, species, row_start, edata, srk, grp_row);

    // merged prep: weight pack + zero boundary agg rows (i0). No init_s.
    prep_kernel<<<2048, 256, 0, stream>>>(
        Wls, Wlv, Wps, Wpv, skip_s, skip_v, packW, row_start, agg_s, agg_v);

    // interaction 0 (gather reads embed table; node fuses read0 + re-zeroing)
    gather_kernel<1><<<N_EDGES / 32, 64, 0, stream>>>(
        edata, srk, row_start, grp_row, embed_s, s, v, Wr, agg_s, agg_v);
    node_mfma_kernel<<<N_NODES / 64, 256, 0, stream>>>(
        agg_s, agg_v, s, v, packW, 0, pw, spec_srt,
        row_start, sidx, Wread0, Wr1a, Wr1b, out, 0);

    // interaction 1 (node fuses read1)
    gather_kernel<0><<<N_EDGES / 32, 64, 0, stream>>>(
        edata, srk, row_start, grp_row, embed_s, s, v, Wr + 2560, agg_s, agg_v);
    node_mfma_kernel<<<N_NODES / 64, 256, 0, stream>>>(
        agg_s, agg_v, s, v, packW, 1, pw + 5760, spec_srt,
        row_start, sidx, Wread0, Wr1a, Wr1b, out, 1);
}

// Round 18
// 298.254 us; speedup vs baseline: 1.2506x; 1.0050x over previous
//
#include <hip/hip_runtime.h>
#include <hip/hip_bf16.h>
#include <math.h>

#define N_NODES 32768
#define N_EDGES 262144
#define EPS_C 0.24253562503633297f   // 1/sqrt(17)
#define NSPEC 10

typedef __attribute__((ext_vector_type(8))) short short8;   // 8 bf16
typedef __attribute__((ext_vector_type(4))) float f32x4;    // 4 fp32 acc

#define MFMA16(a, b, c) __builtin_amdgcn_mfma_f32_16x16x32_bf16(a, b, c, 0, 0, 0)

__device__ __forceinline__ short2 cvt2(float a, float b) {
    union { __hip_bfloat162 h; short2 s; } u;
    u.h = __float22bfloat162_rn(make_float2(a, b));
    return u.s;
}
__device__ __forceinline__ unsigned short f2bf(float a) {
    return (unsigned short)cvt2(a, 0.f).x;
}
__device__ __forceinline__ float bf2f(unsigned short u) {
    return __uint_as_float(((unsigned)u) << 16);
}
__device__ __forceinline__ short8 cvt8(float4 a, float4 b) {
    short2 p0 = cvt2(a.x, a.y), p1 = cvt2(a.z, a.w);
    short2 p2 = cvt2(b.x, b.y), p3 = cvt2(b.z, b.w);
    short8 r;
    r[0] = p0.x; r[1] = p0.y; r[2] = p1.x; r[3] = p1.y;
    r[4] = p2.x; r[5] = p2.y; r[6] = p3.x; r[7] = p3.y;
    return r;
}
__device__ __forceinline__ short8 loadArow(const float* rowp, int h, int q) {
    const float* p = rowp + h * 32 + q * 8;
    return cvt8(*(const float4*)p, *(const float4*)(p + 4));
}
__device__ __forceinline__ short8 loadB(const short* P, int t, int h, int l) {
    return *(const short8*)(P + (((t * 2 + h) * 64 + l) << 3));
}

// ---------------------------------------------------------------------------
// Species counting sort — contention-free, deterministic. sort1 also zeroes
// the receiver-CSR counts array.
// ---------------------------------------------------------------------------
__global__ __launch_bounds__(256) void sort1_kernel(
    const int* __restrict__ species, int* __restrict__ counts_blk,
    int* __restrict__ lrank_arr, int* __restrict__ counts)
{
    __shared__ int wcnt[4][16];
    int n = blockIdx.x * 256 + threadIdx.x;
    counts[n] = 0;
    int sp = species[n];
    int lane = threadIdx.x & 63, wv = threadIdx.x >> 6;
    unsigned long long ltmask = (1ull << lane) - 1;
    int lrank_w = 0;
#pragma unroll
    for (int z = 0; z < NSPEC; ++z) {
        unsigned long long m = __ballot(sp == z);
        if (sp == z) lrank_w = __popcll(m & ltmask);
        if (lane == 0) wcnt[wv][z] = __popcll(m);
    }
    __syncthreads();
    int off = 0;
    for (int w = 0; w < wv; ++w) off += wcnt[w][sp];
    lrank_arr[n] = lrank_w + off;
    if (threadIdx.x < NSPEC)
        counts_blk[blockIdx.x * NSPEC + threadIdx.x] =
            wcnt[0][threadIdx.x] + wcnt[1][threadIdx.x] +
            wcnt[2][threadIdx.x] + wcnt[3][threadIdx.x];
}

// parallel block-offset scan: wave z shuffle-scans its 128 block counts
__global__ __launch_bounds__(640) void sort2_kernel(
    const int* __restrict__ counts_blk, int* __restrict__ off_blk)
{
    __shared__ int totals[16];
    int wv = threadIdx.x >> 6;        // 0..9 == species z
    int lane = threadIdx.x & 63;
    int c0 = counts_blk[lane * NSPEC + wv];
    int c1 = counts_blk[(64 + lane) * NSPEC + wv];
    int s0 = c0;
#pragma unroll
    for (int off = 1; off < 64; off <<= 1) {
        int y = __shfl_up(s0, off);
        if (lane >= off) s0 += y;
    }
    int tot0 = __shfl(s0, 63);
    int s1 = c1;
#pragma unroll
    for (int off = 1; off < 64; off <<= 1) {
        int y = __shfl_up(s1, off);
        if (lane >= off) s1 += y;
    }
    s1 += tot0;
    if (lane == 63) totals[wv] = s1;
    __syncthreads();
    int base = 0;
    for (int q = 0; q < wv; ++q) base += totals[q];
    off_blk[lane * NSPEC + wv] = base + s0 - c0;
    off_blk[(64 + lane) * NSPEC + wv] = base + s1 - c1;
}

__global__ __launch_bounds__(256) void sort3_kernel(
    const int* __restrict__ species, const int* __restrict__ lrank_arr,
    const int* __restrict__ off_blk,
    int* __restrict__ sidx, int* __restrict__ rank, int* __restrict__ spec_srt)
{
    int n = blockIdx.x * 256 + threadIdx.x;
    int sp = species[n];
    int slot = off_blk[blockIdx.x * NSPEC + sp] + lrank_arr[n];
    sidx[slot] = n;
    rank[n] = slot;
    spec_srt[slot] = sp;
}

// ---------------------------------------------------------------------------
// Receiver CSR in SORTED space
// ---------------------------------------------------------------------------
__global__ __launch_bounds__(256) void hist_kernel(
    const int* __restrict__ receivers, const int* __restrict__ rank,
    int* __restrict__ counts)
{
    int e = blockIdx.x * 256 + threadIdx.x;
    atomicAdd(&counts[rank[receivers[e]]], 1);
}

__global__ __launch_bounds__(1024) void scan_kernel(
    const int* __restrict__ counts, int* __restrict__ row_start, int* __restrict__ cursor)
{
    __shared__ int wave_tot[16];
    int tid = threadIdx.x;
    int c[32];
    int sum = 0;
#pragma unroll
    for (int i = 0; i < 32; ++i) { c[i] = counts[tid * 32 + i]; sum += c[i]; }
    int lane = tid & 63, wv = tid >> 6;
    int x = sum;
#pragma unroll
    for (int off = 1; off < 64; off <<= 1) {
        int y = __shfl_up(x, off);
        if (lane >= off) x += y;
    }
    if (lane == 63) wave_tot[wv] = x;
    __syncthreads();
    if (wv == 0 && lane < 16) {
        int t = wave_tot[lane];
#pragma unroll
        for (int off = 1; off < 16; off <<= 1) {
            int y = __shfl_up(t, off);
            if (lane >= off) t += y;
        }
        wave_tot[lane] = t;
    }
    __syncthreads();
    int excl = x - sum + (wv ? wave_tot[wv - 1] : 0);
    int run = excl;
#pragma unroll
    for (int i = 0; i < 32; ++i) {
        row_start[tid * 32 + i] = run;
        cursor[tid * 32 + i] = run;
        run += c[i];
    }
    if (tid == 1023) row_start[32768] = run;
}

__global__ __launch_bounds__(256) void scatter_kernel(
    const int* __restrict__ receivers, const int* __restrict__ rank,
    int* __restrict__ cursor, int* __restrict__ edge_ids)
{
    int e = blockIdx.x * 256 + threadIdx.x;
    int slot = atomicAdd(&cursor[rank[receivers[e]]], 1);
    edge_ids[slot] = e;
}

// ---------------------------------------------------------------------------
// Edge precompute in slot order + fused sender-rank/species stream + grp_row.
// srk[p] = rank | (species << 16)
// ---------------------------------------------------------------------------
__global__ __launch_bounds__(256) void edge_pre_kernel(
    const float* __restrict__ vectors, const int* __restrict__ edge_ids,
    const int* __restrict__ senders, const int* __restrict__ rank,
    const int* __restrict__ species, const int* __restrict__ row_start,
    float* __restrict__ edata, int* __restrict__ srk, int* __restrict__ grp_row)
{
    int p = blockIdx.x * 256 + threadIdx.x;
    int e = edge_ids[p];
    int snd = senders[e];
    srk[p] = rank[snd] | (species[snd] << 16);
    float x = vectors[e * 3 + 0], y = vectors[e * 3 + 1], z = vectors[e * 3 + 2];
    float r2 = x * x + y * y + z * z + 1e-12f;
    float r = sqrtf(r2);
    float inv = 1.0f / r;
    float* d = edata + (size_t)p * 16;
    *(float4*)d = make_float4(x * inv, y * inv, z * inv, 0.0f);
    float rc = fmaxf(r, 1e-6f);
    float r6 = r2 * r2 * r2;
    float r7 = r6 * r;
    float r8 = r6 * r2;
    float env = (r < 1.0f) ? (1.0f - 28.0f * r6 + 48.0f * r7 - 21.0f * r8) : 0.0f;
    float sc = 1.41421356237309515f * env / rc;
#pragma unroll
    for (int j = 0; j < 8; ++j)
        d[4 + j] = sc * sinf((float)(j + 1) * 3.14159265358979323846f * rc);
    d[12] = 0.f; d[13] = 0.f; d[14] = 0.f; d[15] = 0.f;

    if (p < N_EDGES / 16) {
        int target = p * 16;
        int lo = 0, hi = N_NODES - 1;
        while (lo < hi) {
            int mid = (lo + hi + 1) >> 1;
            if (row_start[mid] <= target) lo = mid; else hi = mid - 1;
        }
        grp_row[p] = lo;
    }
}

// ---------------------------------------------------------------------------
// Merged prep: weight pack (blocks<448) + zero_bnd for interaction 0.
// ---------------------------------------------------------------------------
__global__ __launch_bounds__(256) void prep_kernel(
    const float* __restrict__ Wls, const float* __restrict__ Wlv,
    const float* __restrict__ Wps, const float* __restrict__ Wpv,
    const float* __restrict__ skip_s, const float* __restrict__ skip_v,
    short* __restrict__ packW,
    const int* __restrict__ row_start,
    float* __restrict__ agg_s, float* __restrict__ agg_v)
{
    int idx = blockIdx.x * 256 + threadIdx.x;
    if (blockIdx.x < 448 && idx < 28 * 4096) {
        int m = idx >> 12, e = idx & 4095;
        int t = e >> 10, h = (e >> 9) & 1, l = (e >> 3) & 63, j = e & 7;
        int fi = h * 32 + ((l >> 4) << 3) + j;
        int fo = t * 16 + (l & 15);
        const float* src;
        if      (m < 2)  src = Wls    + m * 4096;
        else if (m < 4)  src = Wlv    + (m - 2) * 4096;
        else if (m < 6)  src = Wps    + (m - 4) * 4096;
        else if (m < 8)  src = Wpv    + (m - 6) * 4096;
        else if (m < 18) src = skip_s + (m - 8) * 4096;
        else             src = skip_v + (m - 18) * 4096;
        packW[idx] = cvt2(src[fi * 64 + fo], 0.f).x;
    }
    const int wid = threadIdx.x >> 6;
    const int f = threadIdx.x & 63;
    const int base = (blockIdx.x * 4 + wid) * 4;
#pragma unroll
    for (int t = 0; t < 4; ++t) {
        int i = base + t;
        int beg = row_start[i], end = row_start[i + 1];
        bool need = (end == beg) || (end > (((beg >> 4) + 1) << 4));
        if (need) {
            agg_s[(size_t)i * 64 + f] = 0.f;
            agg_v[((size_t)i * 3 + 0) * 64 + f] = 0.f;
            agg_v[((size_t)i * 3 + 1) * 64 + f] = 0.f;
            agg_v[((size_t)i * 3 + 2) * 64 + f] = 0.f;
        }
    }
}

// ---------------------------------------------------------------------------
// Dual-chain edge-balanced gather (rolled loop, 1 wave/block).
// VZERO: s from 2.5KB embed table. !VZERO: s/v state is bf16 — half the
// random traffic (one 128B line per component per wave).
// ---------------------------------------------------------------------------
template<int VZERO>
__global__ __launch_bounds__(64) void gather_kernel(
    const float* __restrict__ edata, const int* __restrict__ srk,
    const int* __restrict__ row_start, const int* __restrict__ grp_row,
    const float* __restrict__ embed_s,
    const unsigned short* __restrict__ s_in, const unsigned short* __restrict__ v_in,
    const float* __restrict__ Wr_i,
    float* __restrict__ agg_s, float* __restrict__ agg_v)
{
    const int f = threadIdx.x & 63;
    const int w = blockIdx.x;
    const int pA0 = w * 32;
    const int pB0 = pA0 + 16;

    float wr[5][8];
#pragma unroll
    for (int j = 0; j < 8; ++j)
#pragma unroll
        for (int p = 0; p < 5; ++p)
            wr[p][j] = (VZERO && (p == 1 || p == 3 || p == 4))
                       ? 0.f : Wr_i[j * 320 + p * 64 + f];

    int rA = grp_row[2 * w], rB = grp_row[2 * w + 1];
    int begA = row_start[rA], endA = row_start[rA + 1];
    int begB = row_start[rB], endB = row_start[rB + 1];
    float aA0 = 0.f, aA1 = 0.f, aA2 = 0.f, aA3 = 0.f;
    float aB0 = 0.f, aB1 = 0.f, aB2 = 0.f, aB3 = 0.f;

    int svA_c = srk[pA0],     svB_c = srk[pB0];
    int svA_n = srk[pA0 + 1], svB_n = srk[pB0 + 1];
    int srA_c = svA_c & 0xFFFF, srB_c = svB_c & 0xFFFF;
    float ssA, ssB;
    if (VZERO) {
        ssA = embed_s[(svA_c >> 16) * 64 + f];
        ssB = embed_s[(svB_c >> 16) * 64 + f];
    } else {
        ssA = bf2f(s_in[(size_t)srA_c * 64 + f]);
        ssB = bf2f(s_in[(size_t)srB_c * 64 + f]);
    }
    float vA0 = 0.f, vA1 = 0.f, vA2 = 0.f, vB0 = 0.f, vB1 = 0.f, vB2 = 0.f;
    if (!VZERO) {
        vA0 = bf2f(v_in[((size_t)srA_c * 3 + 0) * 64 + f]);
        vA1 = bf2f(v_in[((size_t)srA_c * 3 + 1) * 64 + f]);
        vA2 = bf2f(v_in[((size_t)srA_c * 3 + 2) * 64 + f]);
        vB0 = bf2f(v_in[((size_t)srB_c * 3 + 0) * 64 + f]);
        vB1 = bf2f(v_in[((size_t)srB_c * 3 + 1) * 64 + f]);
        vB2 = bf2f(v_in[((size_t)srB_c * 3 + 2) * 64 + f]);
    }

    for (int k = 0; k < 16; ++k) {
        int pA = pA0 + k, pB = pB0 + k;
        int svA_n2 = (k + 2 < 16) ? srk[pA + 2] : svA_n;
        int svB_n2 = (k + 2 < 16) ? srk[pB + 2] : svB_n;
        int srA_n = svA_n & 0xFFFF, srB_n = svB_n & 0xFFFF;
        float ssA_n, ssB_n;
        if (VZERO) {
            ssA_n = embed_s[(svA_n >> 16) * 64 + f];
            ssB_n = embed_s[(svB_n >> 16) * 64 + f];
        } else {
            ssA_n = bf2f(s_in[(size_t)srA_n * 64 + f]);
            ssB_n = bf2f(s_in[(size_t)srB_n * 64 + f]);
        }
        float vA0n = 0.f, vA1n = 0.f, vA2n = 0.f;
        float vB0n = 0.f, vB1n = 0.f, vB2n = 0.f;
        if (!VZERO) {
            vA0n = bf2f(v_in[((size_t)srA_n * 3 + 0) * 64 + f]);
            vA1n = bf2f(v_in[((size_t)srA_n * 3 + 1) * 64 + f]);
            vA2n = bf2f(v_in[((size_t)srA_n * 3 + 2) * 64 + f]);
            vB0n = bf2f(v_in[((size_t)srB_n * 3 + 0) * 64 + f]);
            vB1n = bf2f(v_in[((size_t)srB_n * 3 + 1) * 64 + f]);
            vB2n = bf2f(v_in[((size_t)srB_n * 3 + 2) * 64 + f]);
        }
        const float* dA = edata + (size_t)pA * 16;
        const float* dB = edata + (size_t)pB * 16;
        float4 yA = *(const float4*)dA;
        float4 qA0 = *(const float4*)(dA + 4);
        float4 qA1 = *(const float4*)(dA + 8);
        float4 yB = *(const float4*)dB;
        float4 qB0 = *(const float4*)(dB + 4);
        float4 qB1 = *(const float4*)(dB + 8);

        float rbA[8] = {qA0.x, qA0.y, qA0.z, qA0.w, qA1.x, qA1.y, qA1.z, qA1.w};
        float rbB[8] = {qB0.x, qB0.y, qB0.z, qB0.w, qB1.x, qB1.y, qB1.z, qB1.w};
        float wA0 = 0.f, wA1 = 0.f, wA2 = 0.f, wA3 = 0.f, wA4 = 0.f;
        float wB0 = 0.f, wB1 = 0.f, wB2 = 0.f, wB3 = 0.f, wB4 = 0.f;
#pragma unroll
        for (int j = 0; j < 8; ++j) {
            wA0 = fmaf(rbA[j], wr[0][j], wA0);  wB0 = fmaf(rbB[j], wr[0][j], wB0);
            if (!VZERO) { wA1 = fmaf(rbA[j], wr[1][j], wA1);  wB1 = fmaf(rbB[j], wr[1][j], wB1); }
            wA2 = fmaf(rbA[j], wr[2][j], wA2);  wB2 = fmaf(rbB[j], wr[2][j], wB2);
            if (!VZERO) { wA3 = fmaf(rbA[j], wr[3][j], wA3);  wB3 = fmaf(rbB[j], wr[3][j], wB3); }
            if (!VZERO) { wA4 = fmaf(rbA[j], wr[4][j], wA4);  wB4 = fmaf(rbB[j], wr[4][j], wB4); }
        }
        if (VZERO) {
            aA0 += wA0 * ssA;
            float wsA = wA2 * ssA;
            aA1 += wsA * yA.x; aA2 += wsA * yA.y; aA3 += wsA * yA.z;
            aB0 += wB0 * ssB;
            float wsB = wB2 * ssB;
            aB1 += wsB * yB.x; aB2 += wsB * yB.y; aB3 += wsB * yB.z;
        } else {
            float dotA = vA0 * yA.x + vA1 * yA.y + vA2 * yA.z;
            aA0 += wA0 * ssA + wA1 * dotA;
            float cA0 = vA1 * yA.z - vA2 * yA.y;
            float cA1 = vA2 * yA.x - vA0 * yA.z;
            float cA2 = vA0 * yA.y - vA1 * yA.x;
            float wsA = wA2 * ssA;
            aA1 += wsA * yA.x + wA3 * vA0 + wA4 * cA0;
            aA2 += wsA * yA.y + wA3 * vA1 + wA4 * cA1;
            aA3 += wsA * yA.z + wA3 * vA2 + wA4 * cA2;
            float dotB = vB0 * yB.x + vB1 * yB.y + vB2 * yB.z;
            aB0 += wB0 * ssB + wB1 * dotB;
            float cB0 = vB1 * yB.z - vB2 * yB.y;
            float cB1 = vB2 * yB.x - vB0 * yB.z;
            float cB2 = vB0 * yB.y - vB1 * yB.x;
            float wsB = wB2 * ssB;
            aB1 += wsB * yB.x + wB3 * vB0 + wB4 * cB0;
            aB2 += wsB * yB.y + wB3 * vB1 + wB4 * cB1;
            aB3 += wsB * yB.z + wB3 * vB2 + wB4 * cB2;
        }

        if (pA + 1 == endA || k == 15) {
            bool interior = (begA >= pA0) && (endA <= pA0 + 16);
            if (interior) {
                agg_s[(size_t)rA * 64 + f] = aA0;
                agg_v[((size_t)rA * 3 + 0) * 64 + f] = aA1;
                agg_v[((size_t)rA * 3 + 1) * 64 + f] = aA2;
                agg_v[((size_t)rA * 3 + 2) * 64 + f] = aA3;
            } else {
                unsafeAtomicAdd(&agg_s[(size_t)rA * 64 + f], aA0);
                unsafeAtomicAdd(&agg_v[((size_t)rA * 3 + 0) * 64 + f], aA1);
                unsafeAtomicAdd(&agg_v[((size_t)rA * 3 + 1) * 64 + f], aA2);
                unsafeAtomicAdd(&agg_v[((size_t)rA * 3 + 2) * 64 + f], aA3);
            }
            aA0 = aA1 = aA2 = aA3 = 0.f;
            if (pA + 1 == endA && k < 15) {
                begA = endA; ++rA; endA = row_start[rA + 1];
                while (endA == begA) { ++rA; endA = row_start[rA + 1]; }
            }
        }
        if (pB + 1 == endB || k == 15) {
            bool interior = (begB >= pB0) && (endB <= pB0 + 16);
            if (interior) {
                agg_s[(size_t)rB * 64 + f] = aB0;
                agg_v[((size_t)rB * 3 + 0) * 64 + f] = aB1;
                agg_v[((size_t)rB * 3 + 1) * 64 + f] = aB2;
                agg_v[((size_t)rB * 3 + 2) * 64 + f] = aB3;
            } else {
                unsafeAtomicAdd(&agg_s[(size_t)rB * 64 + f], aB0);
                unsafeAtomicAdd(&agg_v[((size_t)rB * 3 + 0) * 64 + f], aB1);
                unsafeAtomicAdd(&agg_v[((size_t)rB * 3 + 1) * 64 + f], aB2);
                unsafeAtomicAdd(&agg_v[((size_t)rB * 3 + 2) * 64 + f], aB3);
            }
            aB0 = aB1 = aB2 = aB3 = 0.f;
            if (pB + 1 == endB && k < 15) {
                begB = endB; ++rB; endB = row_start[rB + 1];
                while (endB == begB) { ++rB; endB = row_start[rB + 1]; }
            }
        }
        ssA = ssA_n; vA0 = vA0n; vA1 = vA1n; vA2 = vA2n;
        ssB = ssB_n; vB0 = vB0n; vB1 = vB1n; vB2 = vB2n;
        srA_c = srA_n; srB_c = srB_n;
        svA_n = svA_n2; svB_n = svB_n2;
    }
}

// ---------------------------------------------------------------------------
// MFMA node kernel, bf16 s/v state: skip A-fragments are direct short8 loads
// (bit-exact vs fp32 path); s/v stores are RNE-bf16. Fused readout uses
// pre-rounded fp32 registers. wave = 16 sorted nodes.
// ---------------------------------------------------------------------------
__global__ __launch_bounds__(256) void node_mfma_kernel(
    const float* __restrict__ agg_s, const float* __restrict__ agg_v,
    unsigned short* s, unsigned short* v,
    const short* __restrict__ packW, int it,
    const float* __restrict__ pw_i,
    const int* __restrict__ spec_srt,
    const int* __restrict__ row_start, const int* __restrict__ sidx,
    const float* __restrict__ Wread0, const float* __restrict__ Wr1a,
    const float* __restrict__ Wr1b,
    float* __restrict__ out,
    int has_skip)
{
    const int l = threadIdx.x & 63;
    const int wid = threadIdx.x >> 6;
    const int cl = l & 15;
    const int q = l >> 4;
    const int i16 = (blockIdx.x * 4 + wid) * 16;
    __shared__ float xls_all[4][16 * 65];
    float* xls = xls_all[wid];

    const short* pWls = packW + (size_t)(0 + it) * 4096;
    const short* pWlv = packW + (size_t)(2 + it) * 4096;
    const short* pWps = packW + (size_t)(4 + it) * 4096;
    const short* pWpv = packW + (size_t)(6 + it) * 4096;
    const short* pSkS = packW + (size_t)8 * 4096;
    const short* pSkV = packW + (size_t)18 * 4096;
    const short8 z8 = {0, 0, 0, 0, 0, 0, 0, 0};

    const float* ars = agg_s + (size_t)(i16 + cl) * 64;
    short8 As[2] = { loadArow(ars, 0, q), loadArow(ars, 1, q) };
    short8 Av[3][2];
#pragma unroll
    for (int k = 0; k < 3; ++k) {
        const float* r = agg_v + ((size_t)(i16 + cl) * 3 + k) * 64;
        Av[k][0] = loadArow(r, 0, q);
        Av[k][1] = loadArow(r, 1, q);
    }

    f32x4 sD[4];
#pragma unroll
    for (int t = 0; t < 4; ++t) {
        f32x4 acc = {0.f, 0.f, 0.f, 0.f};
        acc = MFMA16(As[0], loadB(pWls, t, 0, l), acc);
        acc = MFMA16(As[1], loadB(pWls, t, 1, l), acc);
        sD[t] = acc;
    }

    f32x4 vD[3][4];
#pragma unroll
    for (int k = 0; k < 3; ++k)
#pragma unroll
        for (int t = 0; t < 4; ++t) vD[k][t] = (f32x4){0.f, 0.f, 0.f, 0.f};
#pragma unroll
    for (int t = 0; t < 4; ++t)
#pragma unroll
        for (int h = 0; h < 2; ++h) {
            short8 b = loadB(pWlv, t, h, l);
#pragma unroll
            for (int k = 0; k < 3; ++k) vD[k][t] = MFMA16(Av[k][h], b, vD[k][t]);
        }

    int z0 = spec_srt[i16], z1 = spec_srt[i16 + 15];
    float psD[4][4], pvsD[4][4];
    if (z0 == z1) {
        const float* pb = pw_i + z0 * 576 + cl;
        float pc[9][4];
#pragma unroll
        for (int c = 0; c < 9; ++c)
#pragma unroll
            for (int t = 0; t < 4; ++t) pc[c][t] = pb[c * 64 + t * 16];
#pragma unroll
        for (int t = 0; t < 4; ++t)
#pragma unroll
            for (int r = 0; r < 4; ++r) {
                float x = sD[t][r] * EPS_C;
                float w0 = vD[0][t][r] * EPS_C;
                float w1 = vD[1][t][r] * EPS_C;
                float w2 = vD[2][t][r] * EPS_C;
                vD[0][t][r] = w0; vD[1][t][r] = w1; vD[2][t][r] = w2;
                float vv = w0 * w0 + w1 * w1 + w2 * w2;
                float x2 = x * x;
                psD[t][r] = pc[0][t] * x + pc[1][t] * x2 + pc[2][t] * vv
                          + pc[3][t] * x2 * x + pc[4][t] * x * vv;
                pvsD[t][r] = pc[5][t] + pc[6][t] * x + pc[7][t] * x2 + pc[8][t] * vv;
            }
    } else {
#pragma unroll
        for (int r = 0; r < 4; ++r) {
            int z = spec_srt[i16 + q * 4 + r];
            const float* pb = pw_i + z * 576 + cl;
#pragma unroll
            for (int t = 0; t < 4; ++t) {
                float p0 = pb[t*16], p1 = pb[64+t*16], p2 = pb[128+t*16];
                float p3 = pb[192+t*16], p4 = pb[256+t*16], p5 = pb[320+t*16];
                float p6 = pb[384+t*16], p7 = pb[448+t*16], p8 = pb[512+t*16];
                float x = sD[t][r] * EPS_C;
                float w0 = vD[0][t][r] * EPS_C;
                float w1 = vD[1][t][r] * EPS_C;
                float w2 = vD[2][t][r] * EPS_C;
                vD[0][t][r] = w0; vD[1][t][r] = w1; vD[2][t][r] = w2;
                float vv = w0 * w0 + w1 * w1 + w2 * w2;
                float x2 = x * x;
                psD[t][r] = p0 * x + p1 * x2 + p2 * vv + p3 * x2 * x + p4 * x * vv;
                pvsD[t][r] = p5 + p6 * x + p7 * x2 + p8 * vv;
            }
        }
    }

#pragma unroll
    for (int t = 0; t < 4; ++t)
#pragma unroll
        for (int r = 0; r < 4; ++r)
            xls[(q * 4 + r) * 65 + t * 16 + cl] = psD[t][r];
    short8 psA[2];
#pragma unroll
    for (int h = 0; h < 2; ++h) {
        const float* rp = xls + cl * 65 + h * 32 + q * 8;
        float t0 = rp[0], t1 = rp[1], t2 = rp[2], t3 = rp[3];
        float t4 = rp[4], t5 = rp[5], t6 = rp[6], t7 = rp[7];
        psA[h] = cvt8(make_float4(t0, t1, t2, t3), make_float4(t4, t5, t6, t7));
    }

    f32x4 snD[4];
#pragma unroll
    for (int t = 0; t < 4; ++t) {
        f32x4 acc = {0.f, 0.f, 0.f, 0.f};
        acc = MFMA16(psA[0], loadB(pWps, t, 0, l), acc);
        acc = MFMA16(psA[1], loadB(pWps, t, 1, l), acc);
        snD[t] = acc;
    }
    if (has_skip) {
        const unsigned short* srow = s + (size_t)(i16 + cl) * 64;
        short8 Ai0 = *(const short8*)(srow + q * 8);
        short8 Ai1 = *(const short8*)(srow + 32 + q * 8);
        int myz = spec_srt[i16 + cl];
        for (int z = z0; z <= z1; ++z) {
            bool keep = (myz == z);
            short8 m0 = keep ? Ai0 : z8;
            short8 m1 = keep ? Ai1 : z8;
            const short* pz = pSkS + (size_t)z * 4096;
#pragma unroll
            for (int t = 0; t < 4; ++t) {
                snD[t] = MFMA16(m0, loadB(pz, t, 0, l), snD[t]);
                snD[t] = MFMA16(m1, loadB(pz, t, 1, l), snD[t]);
            }
        }
    }
#pragma unroll
    for (int t = 0; t < 4; ++t)
#pragma unroll
        for (int r = 0; r < 4; ++r)
            s[(size_t)(i16 + q * 4 + r) * 64 + t * 16 + cl] = f2bf(snD[t][r]);

    // ---- fused readout (pre-rounded fp32 registers)
    if (it == 0) {
        float w0c[4];
#pragma unroll
        for (int t = 0; t < 4; ++t) w0c[t] = Wread0[t * 16 + cl];
#pragma unroll
        for (int r = 0; r < 4; ++r) {
            float a = snD[0][r] * w0c[0] + snD[1][r] * w0c[1]
                    + snD[2][r] * w0c[2] + snD[3][r] * w0c[3];
            a += __shfl_down(a, 8);
            a += __shfl_down(a, 4);
            a += __shfl_down(a, 2);
            a += __shfl_down(a, 1);
            if (cl == 0) out[(size_t)sidx[i16 + q * 4 + r] * 2 + 0] = a;
        }
    } else {
#pragma unroll
        for (int t = 0; t < 4; ++t)
#pragma unroll
            for (int r = 0; r < 4; ++r)
                xls[(q * 4 + r) * 65 + t * 16 + cl] = snD[t][r];
        float acc4[4] = {0.f, 0.f, 0.f, 0.f};
        for (int g = 0; g < 64; ++g) {
            float wa = Wr1a[g * 16 + cl];
#pragma unroll
            for (int j = 0; j < 4; ++j)
                acc4[j] = fmaf(xls[(q + 4 * j) * 65 + g], wa, acc4[j]);
        }
        float wb = Wr1b[cl];
#pragma unroll
        for (int j = 0; j < 4; ++j) {
            float av = acc4[j];
            float rr = (av / (1.f + expf(-av))) * wb;
            rr += __shfl_down(rr, 8);
            rr += __shfl_down(rr, 4);
            rr += __shfl_down(rr, 2);
            rr += __shfl_down(rr, 1);
            if (cl == 0) out[(size_t)sidx[i16 + q + 4 * j] * 2 + 1] = rr;
        }
    }

    short8 pvA[3][2];
#pragma unroll
    for (int k = 0; k < 3; ++k) {
#pragma unroll
        for (int t = 0; t < 4; ++t)
#pragma unroll
            for (int r = 0; r < 4; ++r)
                xls[(q * 4 + r) * 65 + t * 16 + cl] = pvsD[t][r] * vD[k][t][r];
#pragma unroll
        for (int h = 0; h < 2; ++h) {
            const float* rp = xls + cl * 65 + h * 32 + q * 8;
            float t0 = rp[0], t1 = rp[1], t2 = rp[2], t3 = rp[3];
            float t4 = rp[4], t5 = rp[5], t6 = rp[6], t7 = rp[7];
            pvA[k][h] = cvt8(make_float4(t0, t1, t2, t3), make_float4(t4, t5, t6, t7));
        }
    }

    f32x4 vnD[3][4];
#pragma unroll
    for (int k = 0; k < 3; ++k)
#pragma unroll
        for (int t = 0; t < 4; ++t) vnD[k][t] = (f32x4){0.f, 0.f, 0.f, 0.f};
#pragma unroll
    for (int t = 0; t < 4; ++t)
#pragma unroll
        for (int h = 0; h < 2; ++h) {
            short8 b = loadB(pWpv, t, h, l);
#pragma unroll
            for (int k = 0; k < 3; ++k) vnD[k][t] = MFMA16(pvA[k][h], b, vnD[k][t]);
        }
    if (has_skip) {
        short8 Aiv[3][2];
#pragma unroll
        for (int k = 0; k < 3; ++k) {
            const unsigned short* r = v + ((size_t)(i16 + cl) * 3 + k) * 64;
            Aiv[k][0] = *(const short8*)(r + q * 8);
            Aiv[k][1] = *(const short8*)(r + 32 + q * 8);
        }
        int myz = spec_srt[i16 + cl];
        for (int z = z0; z <= z1; ++z) {
            bool keep = (myz == z);
            const short* pz = pSkV + (size_t)z * 4096;
#pragma unroll
            for (int t = 0; t < 4; ++t)
#pragma unroll
                for (int h = 0; h < 2; ++h) {
                    short8 b = loadB(pz, t, h, l);
#pragma unroll
                    for (int k = 0; k < 3; ++k) {
                        short8 a = keep ? Aiv[k][h] : z8;
                        vnD[k][t] = MFMA16(a, b, vnD[k][t]);
                    }
                }
        }
    }
#pragma unroll
    for (int k = 0; k < 3; ++k)
#pragma unroll
        for (int t = 0; t < 4; ++t)
#pragma unroll
            for (int r = 0; r < 4; ++r)
                v[((size_t)(i16 + q * 4 + r) * 3 + k) * 64 + t * 16 + cl] = f2bf(vnD[k][t][r]);

    // ---- it==0: zero this wave's own agg boundary rows for interaction 1.
    if (it == 0) {
        for (int rr = 0; rr < 16; ++rr) {
            int i = i16 + rr;
            int beg = row_start[i], end = row_start[i + 1];
            bool need = (end == beg) || (end > (((beg >> 4) + 1) << 4));
            if (need) {
                float* as = (float*)agg_s;
                float* av = (float*)agg_v;
                as[(size_t)i * 64 + l] = 0.f;
                av[((size_t)i * 3 + 0) * 64 + l] = 0.f;
                av[((size_t)i * 3 + 1) * 64 + l] = 0.f;
                av[((size_t)i * 3 + 2) * 64 + l] = 0.f;
            }
        }
    }
}

// ---------------------------------------------------------------------------
extern "C" void kernel_launch(void* const* d_in, const int* in_sizes, int n_in,
                              void* d_out, int out_size, void* d_ws, size_t ws_size,
                              hipStream_t stream)
{
    const float* vectors = (const float*)d_in[0];
    const float* embed_s = (const float*)d_in[1];
    const float* Wr      = (const float*)d_in[2];   // [2,8,320]
    const float* Wls     = (const float*)d_in[3];   // [2,64,64]
    const float* Wlv     = (const float*)d_in[4];
    const float* skip_s  = (const float*)d_in[5];   // [10,64,64]
    const float* skip_v  = (const float*)d_in[6];
    const float* pw      = (const float*)d_in[7];   // [2,10,9,64]
    const float* Wps     = (const float*)d_in[8];
    const float* Wpv     = (const float*)d_in[9];
    const float* Wread0  = (const float*)d_in[10];  // [64,1]
    const float* Wr1a    = (const float*)d_in[11];  // [64,16]
    const float* Wr1b    = (const float*)d_in[12];  // [16,1]
    const int* senders   = (const int*)d_in[13];
    const int* receivers = (const int*)d_in[14];
    const int* species   = (const int*)d_in[15];
    float* out = (float*)d_out;

    float* ws = (float*)d_ws;
    float* edata = ws; ws += (size_t)N_EDGES * 16;  // 16 MB (slot-ordered)
    float* agg_s = ws; ws += (size_t)N_NODES * 64;  // 8 MB
    float* agg_v = ws; ws += (size_t)N_NODES * 192; // 24 MB
    unsigned short* s = (unsigned short*)ws; ws += (size_t)N_NODES * 32;  // 4 MB bf16
    unsigned short* v = (unsigned short*)ws; ws += (size_t)N_NODES * 96;  // 12 MB bf16
    int* counts    = (int*)ws; ws += N_NODES;
    int* row_start = (int*)ws; ws += N_NODES + 4;
    int* cursor    = (int*)ws; ws += N_NODES;
    int* edge_ids  = (int*)ws; ws += N_EDGES;
    int* srk       = (int*)ws; ws += N_EDGES;
    int* grp_row   = (int*)ws; ws += N_EDGES / 16;
    int* sidx      = (int*)ws; ws += N_NODES;
    int* rank      = (int*)ws; ws += N_NODES;
    int* spec_srt  = (int*)ws; ws += N_NODES;
    int* lrank_arr = (int*)ws; ws += N_NODES;
    int* counts_blk = (int*)ws; ws += 128 * NSPEC;
    int* off_blk    = (int*)ws; ws += 128 * NSPEC;
    short* packW   = (short*)ws;                    // 224 KB

    // species counting sort (sort1 also zeroes CSR counts)
    sort1_kernel<<<N_NODES / 256, 256, 0, stream>>>(
        species, counts_blk, lrank_arr, counts);
    sort2_kernel<<<1, 640, 0, stream>>>(counts_blk, off_blk);
    sort3_kernel<<<N_NODES / 256, 256, 0, stream>>>(
        species, lrank_arr, off_blk, sidx, rank, spec_srt);

    // receiver CSR in sorted space
    hist_kernel<<<N_EDGES / 256, 256, 0, stream>>>(receivers, rank, counts);
    scan_kernel<<<1, 1024, 0, stream>>>(counts, row_start, cursor);
    scatter_kernel<<<N_EDGES / 256, 256, 0, stream>>>(receivers, rank, cursor, edge_ids);

    // edge features + packed sender rank/species + grp_row (one pass)
    edge_pre_kernel<<<N_EDGES / 256, 256, 0, stream>>>(
        vectors, edge_ids, senders, rank, species, row_start, edata, srk, grp_row);

    // merged prep: weight pack + zero boundary agg rows (i0). No init_s.
    prep_kernel<<<2048, 256, 0, stream>>>(
        Wls, Wlv, Wps, Wpv, skip_s, skip_v, packW, row_start, agg_s, agg_v);

    // interaction 0 (gather reads embed table; node fuses read0 + re-zeroing)
    gather_kernel<1><<<N_EDGES / 32, 64, 0, stream>>>(
        edata, srk, row_start, grp_row, embed_s, s, v, Wr, agg_s, agg_v);
    node_mfma_kernel<<<N_NODES / 64, 256, 0, stream>>>(
        agg_s, agg_v, s, v, packW, 0, pw, spec_srt,
        row_start, sidx, Wread0, Wr1a, Wr1b, out, 0);

    // interaction 1 (bf16 s/v state halves random gather traffic)
    gather_kernel<0><<<N_EDGES / 32, 64, 0, stream>>>(
        edata, srk, row_start, grp_row, embed_s, s, v, Wr + 2560, agg_s, agg_v);
    node_mfma_kernel<<<N_NODES / 64, 256, 0, stream>>>(
        agg_s, agg_v, s, v, packW, 1, pw + 5760, spec_srt,
        row_start, sidx, Wread0, Wr1a, Wr1b, out, 1);
}